// Round 1
// baseline (664.732 us; speedup 1.0000x reference)
//
#include <hip/hip_runtime.h>
#include <hip/hip_bf16.h>
#include <math.h>

// Problem constants (fixed shapes from setup_inputs)
#define S_LEN 2048
#define NH 16
#define HD 64
#define DM 1024
#define NTOK 4096   // B*S
#define NBH 32      // B*NH

typedef __attribute__((ext_vector_type(8))) __bf16 bf16x8;
typedef __attribute__((ext_vector_type(8))) ushort ushort8;
typedef __attribute__((ext_vector_type(4))) float f32x4;

__device__ __forceinline__ ushort f2b(float x) {
  __hip_bfloat16 h = __float2bfloat16(x);
  return *reinterpret_cast<ushort*>(&h);
}

__device__ __forceinline__ void gload16(const void* g, void* l) {
  __builtin_amdgcn_global_load_lds((const __attribute__((address_space(1))) void*)g,
                                   (__attribute__((address_space(3))) void*)l, 16, 0, 0);
}

#define MFMA16(a, b, c) __builtin_amdgcn_mfma_f32_16x16x32_bf16((a), (b), (c), 0, 0, 0)

// ---------------------------------------------------------------- convert fp32 -> bf16
struct CvtArgs {
  const float* src[7];
  ushort* dst[7];
  int n[7];
};

__global__ void cvt_kernel(CvtArgs a) {
  int arr = blockIdx.y;
  long i = ((long)blockIdx.x * blockDim.x + threadIdx.x) * 8;
  if (i >= a.n[arr]) return;
  const float* s = a.src[arr];
  ushort* d = a.dst[arr];
  float4 v0 = *reinterpret_cast<const float4*>(s + i);
  float4 v1 = *reinterpret_cast<const float4*>(s + i + 4);
  ushort8 r;
  r[0] = f2b(v0.x); r[1] = f2b(v0.y); r[2] = f2b(v0.z); r[3] = f2b(v0.w);
  r[4] = f2b(v1.x); r[5] = f2b(v1.y); r[6] = f2b(v1.z); r[7] = f2b(v1.w);
  *reinterpret_cast<ushort8*>(d + i) = r;
}

// ---------------------------------------------------------------- GEMM  C = A[M,K] * W[N,K]^T
// act: 0 = raw -> bf16, 1 = softplus -> f32, 2 = pi*tanh -> f32, 3 = raw -> f32
__global__ __launch_bounds__(256) void gemm_bt(const ushort* __restrict__ A,
                                               const ushort* __restrict__ W,
                                               void* __restrict__ Cout,
                                               int M, int N, int K, int act) {
  __shared__ __align__(16) ushort Alds[128 * 32];
  __shared__ __align__(16) ushort Blds[128 * 32];
  const int t = threadIdx.x;
  const int lane = t & 63;
  const int wave = t >> 6;
  const int wm = wave >> 1, wn = wave & 1;   // 2x2 wave grid, 64x64 each
  const int l15 = lane & 15, g = lane >> 4;
  const int mbase = blockIdx.y * 128, nbase = blockIdx.x * 128;
  const int srow = t >> 2, scol = (t & 3) * 8;  // staging: 64 rows x 32 cols per issue
  const ushort* Ag = A + (size_t)(mbase + srow) * K + scol;
  const ushort* Wg = W + (size_t)(nbase + srow) * K + scol;
  ushort* Al = Alds + t * 8;
  ushort* Bl = Blds + t * 8;
  f32x4 acc[4][4] = {};
  for (int kt = 0; kt < K; kt += 32) {
    __syncthreads();
    gload16(Ag + kt, Al);
    gload16(Ag + kt + (size_t)64 * K, Al + 64 * 32);
    gload16(Wg + kt, Bl);
    gload16(Wg + kt + (size_t)64 * K, Bl + 64 * 32);
    asm volatile("s_waitcnt vmcnt(0)" ::: "memory");
    __syncthreads();
    bf16x8 af[4], bf[4];
#pragma unroll
    for (int i = 0; i < 4; i++)
      af[i] = *reinterpret_cast<const bf16x8*>(&Alds[(wm * 64 + i * 16 + l15) * 32 + g * 8]);
#pragma unroll
    for (int j = 0; j < 4; j++)
      bf[j] = *reinterpret_cast<const bf16x8*>(&Blds[(wn * 64 + j * 16 + l15) * 32 + g * 8]);
#pragma unroll
    for (int i = 0; i < 4; i++)
#pragma unroll
      for (int j = 0; j < 4; j++)
        acc[i][j] = MFMA16(af[i], bf[j], acc[i][j]);
  }
  const int row0 = mbase + wm * 64, col0 = nbase + wn * 64;
#pragma unroll
  for (int i = 0; i < 4; i++) {
#pragma unroll
    for (int j = 0; j < 4; j++) {
#pragma unroll
      for (int r = 0; r < 4; r++) {
        int row = row0 + i * 16 + g * 4 + r;   // D layout: row=(lane>>4)*4+r, col=lane&15
        int col = col0 + j * 16 + l15;
        float v = acc[i][j][r];
        size_t off = (size_t)row * N + col;
        if (act == 0) {
          ((ushort*)Cout)[off] = f2b(v);
        } else if (act == 1) {
          ((float*)Cout)[off] = fmaxf(v, 0.0f) + log1pf(expf(-fabsf(v)));
        } else if (act == 2) {
          ((float*)Cout)[off] = 3.14159265358979f * tanhf(v);
        } else {
          ((float*)Cout)[off] = v;
        }
      }
    }
  }
}

// ---------------------------------------------------------------- RMS-norm + cos/sin interleave
// One 64-lane wave per (b,s,h) row. qext/kext layout: [B,H,S,128] bf16, first 64 = cos part,
// next 64 = sin part. Score scale exp(sls[h])/8 folded into q.
__global__ void qkext_kernel(const float* __restrict__ qamp, const float* __restrict__ qphi,
                             const float* __restrict__ kamp, const float* __restrict__ kphi,
                             const float* __restrict__ sls,
                             ushort* __restrict__ qext, ushort* __restrict__ kext) {
  int wid = blockIdx.x * 4 + (threadIdx.x >> 6);
  int lane = threadIdx.x & 63;
  int h = wid & 15, bs = wid >> 4;
  int b = bs >> 11, s = bs & 2047;
  size_t xoff = (size_t)bs * DM + h * HD + lane;
  size_t eoff = ((size_t)(b * NH + h) * S_LEN + s) * 128 + lane;
  float scale = expf(sls[h]) * 0.125f;
  {
    float amp = qamp[xoff];
    float ss = amp * amp;
#pragma unroll
    for (int mk = 1; mk < 64; mk <<= 1) ss += __shfl_xor(ss, mk);
    float a = amp * rsqrtf(ss * (1.0f / 64.0f) + 1e-6f) * scale;
    float phi = qphi[xoff];
    float sn, cs;
    sincosf(phi, &sn, &cs);
    qext[eoff] = f2b(a * cs);
    qext[eoff + 64] = f2b(a * sn);
  }
  {
    float amp = kamp[xoff];
    float ss = amp * amp;
#pragma unroll
    for (int mk = 1; mk < 64; mk <<= 1) ss += __shfl_xor(ss, mk);
    float a = amp * rsqrtf(ss * (1.0f / 64.0f) + 1e-6f);
    float phi = kphi[xoff];
    float sn, cs;
    sincosf(phi, &sn, &cs);
    kext[eoff] = f2b(a * cs);
    kext[eoff + 64] = f2b(a * sn);
  }
}

// ---------------------------------------------------------------- V transpose: [B,S,H*64] -> [B,H,64,S]
__global__ void vt_kernel(const ushort* __restrict__ v, ushort* __restrict__ vT) {
  __shared__ __align__(16) ushort tile[64][80];
  int bh = blockIdx.y;
  int b = bh >> 4, h = bh & 15;
  int s0 = blockIdx.x * 64;
  int t = threadIdx.x;
  int r = t >> 2, cc = (t & 3) * 16;
  const ushort* src = v + (size_t)(b * S_LEN + s0 + r) * DM + h * HD + cc;
  *reinterpret_cast<ushort8*>(&tile[r][cc]) = *reinterpret_cast<const ushort8*>(src);
  *reinterpret_cast<ushort8*>(&tile[r][cc + 8]) = *reinterpret_cast<const ushort8*>(src + 8);
  __syncthreads();
  int d = t >> 2, sc = (t & 3) * 16;
  ushort8 o0, o1;
#pragma unroll
  for (int i = 0; i < 8; i++) o0[i] = tile[sc + i][d];
#pragma unroll
  for (int i = 0; i < 8; i++) o1[i] = tile[sc + 8 + i][d];
  ushort* dst = vT + ((size_t)bh * HD + d) * S_LEN + s0 + sc;
  *reinterpret_cast<ushort8*>(dst) = o0;
  *reinterpret_cast<ushort8*>(dst + 8) = o1;
}

// ---------------------------------------------------------------- causal flash attention
// grid (S/64, B*H); 4 waves/block; wave w owns Q rows [qb+16w, qb+16w+16).
// All waves loop kv = 0..qb (uniform trips); only diagonal tile needs element masking.
__global__ __launch_bounds__(256) void attn_kernel(const ushort* __restrict__ qext,
                                                   const ushort* __restrict__ kext,
                                                   const ushort* __restrict__ vT,
                                                   ushort* __restrict__ attnout) {
  __shared__ __align__(16) ushort Plds[4][1024];  // per-wave 16x64 bf16, XOR-swizzled
  const int bh = blockIdx.y;
  const int b = bh >> 4, h = bh & 15;
  const int qb = blockIdx.x * 64;
  const int wave = threadIdx.x >> 6, lane = threadIdx.x & 63;
  const int l15 = lane & 15, g = lane >> 4;
  const int qr = qb + wave * 16;
  const ushort* Qp = qext + ((size_t)bh * S_LEN + qr) * 128;
  const ushort* Kp = kext + (size_t)bh * S_LEN * 128;
  const ushort* Vp = vT + (size_t)bh * HD * S_LEN;
  bf16x8 aq[4];
#pragma unroll
  for (int kk = 0; kk < 4; kk++)
    aq[kk] = *reinterpret_cast<const bf16x8*>(&Qp[(size_t)l15 * 128 + kk * 32 + g * 8]);
  f32x4 o[4] = {};
  float m[4], ls[4];
#pragma unroll
  for (int r = 0; r < 4; r++) { m[r] = -1e30f; ls[r] = 0.0f; }
  char* myP = (char*)&Plds[wave][0];
  for (int kv = 0; kv <= qb; kv += 64) {
    f32x4 st[4] = {};
#pragma unroll
    for (int ct = 0; ct < 4; ct++) {
#pragma unroll
      for (int kk = 0; kk < 4; kk++) {
        bf16x8 bk = *reinterpret_cast<const bf16x8*>(
            &Kp[(size_t)(kv + ct * 16 + l15) * 128 + kk * 32 + g * 8]);
        st[ct] = MFMA16(aq[kk], bk, st[ct]);
      }
    }
    if (kv == qb) {  // diagonal tile: mask col > row
#pragma unroll
      for (int ct = 0; ct < 4; ct++)
#pragma unroll
        for (int r = 0; r < 4; r++) {
          int col = kv + ct * 16 + l15;
          int row = qr + g * 4 + r;
          if (col > row) st[ct][r] = -1e30f;
        }
    }
    // online softmax (rows live in the 16-lane group sharing g)
#pragma unroll
    for (int r = 0; r < 4; r++) {
      float pm = fmaxf(fmaxf(st[0][r], st[1][r]), fmaxf(st[2][r], st[3][r]));
      pm = fmaxf(pm, __shfl_xor(pm, 1));
      pm = fmaxf(pm, __shfl_xor(pm, 2));
      pm = fmaxf(pm, __shfl_xor(pm, 4));
      pm = fmaxf(pm, __shfl_xor(pm, 8));
      float mn = fmaxf(m[r], pm);
      float corr = __expf(m[r] - mn);
      m[r] = mn;
      float s0 = 0.f;
#pragma unroll
      for (int ct = 0; ct < 4; ct++) {
        float p = __expf(st[ct][r] - mn);
        st[ct][r] = p;
        s0 += p;
      }
      s0 += __shfl_xor(s0, 1);
      s0 += __shfl_xor(s0, 2);
      s0 += __shfl_xor(s0, 4);
      s0 += __shfl_xor(s0, 8);
      ls[r] = ls[r] * corr + s0;
#pragma unroll
      for (int ct = 0; ct < 4; ct++) o[ct][r] *= corr;
    }
    // P (D-layout) -> LDS, XOR swizzle byte ^= (row&7)<<4 (G4 fix for 128B rows)
#pragma unroll
    for (int ct = 0; ct < 4; ct++)
#pragma unroll
      for (int r = 0; r < 4; r++) {
        int row = g * 4 + r;
        int boff = (row * 128 + (ct * 16 + l15) * 2) ^ ((row & 7) << 4);
        *(ushort*)(myP + boff) = f2b(st[ct][r]);
      }
    // PV: A = P[16x64] from LDS (A-layout), B = vT (k-contiguous 16B loads)
#pragma unroll
    for (int ks = 0; ks < 2; ks++) {
      int boff = (l15 * 128 + ks * 64 + g * 16) ^ ((l15 & 7) << 4);
      bf16x8 ap = *reinterpret_cast<const bf16x8*>(myP + boff);
#pragma unroll
      for (int ct = 0; ct < 4; ct++) {
        bf16x8 bv = *reinterpret_cast<const bf16x8*>(
            &Vp[(size_t)(ct * 16 + l15) * S_LEN + kv + ks * 32 + g * 8]);
        o[ct] = MFMA16(ap, bv, o[ct]);
      }
    }
  }
  ushort* Op = attnout + (size_t)b * S_LEN * DM + h * HD;
#pragma unroll
  for (int ct = 0; ct < 4; ct++)
#pragma unroll
    for (int r = 0; r < 4; r++) {
      int q = qr + g * 4 + r;
      float v = o[ct][r] / ls[r];
      Op[(size_t)q * DM + ct * 16 + l15] = f2b(v);
    }
}

// ----------------------------------------------------------------
extern "C" void kernel_launch(void* const* d_in, const int* in_sizes, int n_in,
                              void* d_out, int out_size, void* d_ws, size_t ws_size,
                              hipStream_t stream) {
  const float* x   = (const float*)d_in[0];
  const float* Wqa = (const float*)d_in[1];
  const float* Wka = (const float*)d_in[2];
  const float* Wqp = (const float*)d_in[3];
  const float* Wkp = (const float*)d_in[4];
  const float* Wv  = (const float*)d_in[5];
  const float* Wo  = (const float*)d_in[6];
  const float* sls = (const float*)d_in[7];

  char* ws = (char*)d_ws;
  ushort* x_bf = (ushort*)ws; ws += (size_t)NTOK * DM * 2;
  ushort* w_bf[6];
  for (int i = 0; i < 6; i++) { w_bf[i] = (ushort*)ws; ws += (size_t)DM * DM * 2; }
  float* qamp = (float*)ws; ws += (size_t)NTOK * DM * 4;
  float* kamp = (float*)ws; ws += (size_t)NTOK * DM * 4;
  float* qphi = (float*)ws; ws += (size_t)NTOK * DM * 4;
  float* kphi = (float*)ws; ws += (size_t)NTOK * DM * 4;
  ushort* v_bf = (ushort*)ws; ws += (size_t)NTOK * DM * 2;
  ushort* qext = (ushort*)ws; ws += (size_t)NBH * S_LEN * 128 * 2;
  ushort* kext = (ushort*)ws; ws += (size_t)NBH * S_LEN * 128 * 2;
  ushort* vT   = (ushort*)ws; ws += (size_t)NBH * HD * S_LEN * 2;
  ushort* attn = (ushort*)ws; ws += (size_t)NTOK * DM * 2;

  // 1. fp32 -> bf16 conversions (x + 6 weights)
  CvtArgs ca;
  ca.src[0] = x; ca.dst[0] = x_bf; ca.n[0] = NTOK * DM;
  const float* wsrc[6] = {Wqa, Wka, Wqp, Wkp, Wv, Wo};
  for (int i = 0; i < 6; i++) { ca.src[i + 1] = wsrc[i]; ca.dst[i + 1] = w_bf[i]; ca.n[i + 1] = DM * DM; }
  dim3 cg((NTOK * DM / 8 + 255) / 256, 7);
  hipLaunchKernelGGL(cvt_kernel, cg, dim3(256), 0, stream, ca);

  // 2-6. projection GEMMs
  dim3 gg(DM / 128, NTOK / 128);
  hipLaunchKernelGGL(gemm_bt, gg, dim3(256), 0, stream, x_bf, w_bf[0], (void*)qamp, NTOK, DM, DM, 1);
  hipLaunchKernelGGL(gemm_bt, gg, dim3(256), 0, stream, x_bf, w_bf[1], (void*)kamp, NTOK, DM, DM, 1);
  hipLaunchKernelGGL(gemm_bt, gg, dim3(256), 0, stream, x_bf, w_bf[2], (void*)qphi, NTOK, DM, DM, 2);
  hipLaunchKernelGGL(gemm_bt, gg, dim3(256), 0, stream, x_bf, w_bf[3], (void*)kphi, NTOK, DM, DM, 2);
  hipLaunchKernelGGL(gemm_bt, gg, dim3(256), 0, stream, x_bf, w_bf[4], (void*)v_bf, NTOK, DM, DM, 0);

  // 7. RMS norm + phase -> qext/kext
  hipLaunchKernelGGL(qkext_kernel, dim3((NTOK * NH) / 4), dim3(256), 0, stream,
                     qamp, qphi, kamp, kphi, sls, qext, kext);

  // 8. V transpose
  hipLaunchKernelGGL(vt_kernel, dim3(S_LEN / 64, NBH), dim3(256), 0, stream, v_bf, vT);

  // 9. causal flash attention
  hipLaunchKernelGGL(attn_kernel, dim3(S_LEN / 64, NBH), dim3(256), 0, stream,
                     qext, kext, vT, attn);

  // 10. output projection -> fp32 d_out
  hipLaunchKernelGGL(gemm_bt, gg, dim3(256), 0, stream, attn, w_bf[5], d_out, NTOK, DM, DM, 3);
}

// Round 3
// 512.946 us; speedup vs baseline: 1.2959x; 1.2959x over previous
//
#include <hip/hip_runtime.h>
#include <hip/hip_bf16.h>
#include <math.h>

// Problem constants (fixed shapes from setup_inputs)
#define S_LEN 2048
#define NH 16
#define HD 64
#define DM 1024
#define NTOK 4096   // B*S
#define NBH 32      // B*NH

typedef __attribute__((ext_vector_type(8))) __bf16 bf16x8;
typedef __attribute__((ext_vector_type(8))) ushort ushort8;
typedef __attribute__((ext_vector_type(4))) ushort ushort4v;
typedef __attribute__((ext_vector_type(4))) float f32x4;
typedef __attribute__((ext_vector_type(16))) float f32x16;
typedef __attribute__((ext_vector_type(4))) uint u32x4;

__device__ __forceinline__ ushort f2b(float x) {
  __hip_bfloat16 h = __float2bfloat16(x);
  return *reinterpret_cast<ushort*>(&h);
}

__device__ __forceinline__ uint pk2(float lo, float hi) {
  return (uint)f2b(lo) | ((uint)f2b(hi) << 16);
}

__device__ __forceinline__ void gload16b(const void* g, void* l) {
  __builtin_amdgcn_global_load_lds((const __attribute__((address_space(1))) void*)g,
                                   (__attribute__((address_space(3))) void*)l, 16, 0, 0);
}

#define MFMA16(a, b, c) __builtin_amdgcn_mfma_f32_16x16x32_bf16((a), (b), (c), 0, 0, 0)
#define MFMA32(a, b, c) __builtin_amdgcn_mfma_f32_32x32x16_bf16((a), (b), (c), 0, 0, 0)

// ---------------------------------------------------------------- convert fp32 -> bf16
struct CvtArgs {
  const float* src[7];
  ushort* dst[7];
  int n[7];
};

__global__ void cvt_kernel(CvtArgs a) {
  int arr = blockIdx.y;
  long i = ((long)blockIdx.x * blockDim.x + threadIdx.x) * 8;
  if (i >= a.n[arr]) return;
  const float* s = a.src[arr];
  ushort* d = a.dst[arr];
  float4 v0 = *reinterpret_cast<const float4*>(s + i);
  float4 v1 = *reinterpret_cast<const float4*>(s + i + 4);
  ushort8 r;
  r[0] = f2b(v0.x); r[1] = f2b(v0.y); r[2] = f2b(v0.z); r[3] = f2b(v0.w);
  r[4] = f2b(v1.x); r[5] = f2b(v1.y); r[6] = f2b(v1.z); r[7] = f2b(v1.w);
  *reinterpret_cast<ushort8*>(d + i) = r;
}

// ---------------------------------------------------------------- GEMM  C = A[M,K] * W[N,K]^T
// act: 0 = raw -> bf16, 1 = softplus -> f32, 2 = pi*tanh -> f32, 3 = raw -> f32
__global__ __launch_bounds__(256) void gemm_bt(const ushort* __restrict__ A,
                                               const ushort* __restrict__ W,
                                               void* __restrict__ Cout,
                                               int M, int N, int K, int act) {
  __shared__ __align__(16) ushort Alds[128 * 32];
  __shared__ __align__(16) ushort Blds[128 * 32];
  const int t = threadIdx.x;
  const int lane = t & 63;
  const int wave = t >> 6;
  const int wm = wave >> 1, wn = wave & 1;   // 2x2 wave grid, 64x64 each
  const int l15 = lane & 15, g = lane >> 4;
  const int mbase = blockIdx.y * 128, nbase = blockIdx.x * 128;
  const int srow = t >> 2, scol = (t & 3) * 8;  // staging: 64 rows x 32 cols per issue
  const ushort* Ag = A + (size_t)(mbase + srow) * K + scol;
  const ushort* Wg = W + (size_t)(nbase + srow) * K + scol;
  ushort* Al = Alds + t * 8;
  ushort* Bl = Blds + t * 8;
  f32x4 acc[4][4] = {};
  for (int kt = 0; kt < K; kt += 32) {
    __syncthreads();
    gload16b(Ag + kt, Al);
    gload16b(Ag + kt + (size_t)64 * K, Al + 64 * 32);
    gload16b(Wg + kt, Bl);
    gload16b(Wg + kt + (size_t)64 * K, Bl + 64 * 32);
    asm volatile("s_waitcnt vmcnt(0)" ::: "memory");
    __syncthreads();
    bf16x8 af[4], bf[4];
#pragma unroll
    for (int i = 0; i < 4; i++)
      af[i] = *reinterpret_cast<const bf16x8*>(&Alds[(wm * 64 + i * 16 + l15) * 32 + g * 8]);
#pragma unroll
    for (int j = 0; j < 4; j++)
      bf[j] = *reinterpret_cast<const bf16x8*>(&Blds[(wn * 64 + j * 16 + l15) * 32 + g * 8]);
#pragma unroll
    for (int i = 0; i < 4; i++)
#pragma unroll
      for (int j = 0; j < 4; j++)
        acc[i][j] = MFMA16(af[i], bf[j], acc[i][j]);
  }
  const int row0 = mbase + wm * 64, col0 = nbase + wn * 64;
#pragma unroll
  for (int i = 0; i < 4; i++) {
#pragma unroll
    for (int j = 0; j < 4; j++) {
#pragma unroll
      for (int r = 0; r < 4; r++) {
        int row = row0 + i * 16 + g * 4 + r;   // D layout: row=(lane>>4)*4+r, col=lane&15
        int col = col0 + j * 16 + l15;
        float v = acc[i][j][r];
        size_t off = (size_t)row * N + col;
        if (act == 0) {
          ((ushort*)Cout)[off] = f2b(v);
        } else if (act == 1) {
          ((float*)Cout)[off] = fmaxf(v, 0.0f) + log1pf(expf(-fabsf(v)));
        } else if (act == 2) {
          ((float*)Cout)[off] = 3.14159265358979f * tanhf(v);
        } else {
          ((float*)Cout)[off] = v;
        }
      }
    }
  }
}

// ---------------------------------------------------------------- RMS-norm + cos/sin interleave
__global__ void qkext_kernel(const float* __restrict__ qamp, const float* __restrict__ qphi,
                             const float* __restrict__ kamp, const float* __restrict__ kphi,
                             const float* __restrict__ sls,
                             ushort* __restrict__ qext, ushort* __restrict__ kext) {
  int wid = blockIdx.x * 4 + (threadIdx.x >> 6);
  int lane = threadIdx.x & 63;
  int h = wid & 15, bs = wid >> 4;
  int b = bs >> 11, s = bs & 2047;
  size_t xoff = (size_t)bs * DM + h * HD + lane;
  size_t eoff = ((size_t)(b * NH + h) * S_LEN + s) * 128 + lane;
  float scale = expf(sls[h]) * 0.125f;
  {
    float amp = qamp[xoff];
    float ss = amp * amp;
#pragma unroll
    for (int mk = 1; mk < 64; mk <<= 1) ss += __shfl_xor(ss, mk);
    float a = amp * rsqrtf(ss * (1.0f / 64.0f) + 1e-6f) * scale;
    float phi = qphi[xoff];
    float sn, cs;
    sincosf(phi, &sn, &cs);
    qext[eoff] = f2b(a * cs);
    qext[eoff + 64] = f2b(a * sn);
  }
  {
    float amp = kamp[xoff];
    float ss = amp * amp;
#pragma unroll
    for (int mk = 1; mk < 64; mk <<= 1) ss += __shfl_xor(ss, mk);
    float a = amp * rsqrtf(ss * (1.0f / 64.0f) + 1e-6f);
    float phi = kphi[xoff];
    float sn, cs;
    sincosf(phi, &sn, &cs);
    kext[eoff] = f2b(a * cs);
    kext[eoff + 64] = f2b(a * sn);
  }
}

// ---------------------------------------------------------------- V transpose: [B,S,H*64] -> [B,H,64,S]
__global__ void vt_kernel(const ushort* __restrict__ v, ushort* __restrict__ vT) {
  __shared__ __align__(16) ushort tile[64][80];
  int bh = blockIdx.y;
  int b = bh >> 4, h = bh & 15;
  int s0 = blockIdx.x * 64;
  int t = threadIdx.x;
  int r = t >> 2, cc = (t & 3) * 16;
  const ushort* src = v + (size_t)(b * S_LEN + s0 + r) * DM + h * HD + cc;
  *reinterpret_cast<ushort8*>(&tile[r][cc]) = *reinterpret_cast<const ushort8*>(src);
  *reinterpret_cast<ushort8*>(&tile[r][cc + 8]) = *reinterpret_cast<const ushort8*>(src + 8);
  __syncthreads();
  int d = t >> 2, sc = (t & 3) * 16;
  ushort8 o0, o1;
#pragma unroll
  for (int i = 0; i < 8; i++) o0[i] = tile[sc + i][d];
#pragma unroll
  for (int i = 0; i < 8; i++) o1[i] = tile[sc + 8 + i][d];
  ushort* dst = vT + ((size_t)bh * HD + d) * S_LEN + s0 + sc;
  *reinterpret_cast<ushort8*>(dst) = o0;
  *reinterpret_cast<ushort8*>(dst + 8) = o1;
}

// ---------------------------------------------------------------- causal flash attention
// Swapped-QK 32x32 structure: 1 wave per 32 q-rows, no LDS, no barriers.
// st = mfma32(A=K, B=Q): lane holds P-row for q = lane&31 (16 kv per 32-tile, hi-split).
// PV: o = mfma32(A=V^T, B=P^T): output col = q = lane&31 -> rescale/normalize in-lane.
__global__ __launch_bounds__(256, 2) void attn_kernel(const ushort* __restrict__ qext,
                                                      const ushort* __restrict__ kext,
                                                      const ushort* __restrict__ vT,
                                                      ushort* __restrict__ attnout) {
  const int bh = blockIdx.y;
  const int b = bh >> 4, h = bh & 15;
  const int wave = threadIdx.x >> 6, lane = threadIdx.x & 63;
  const int l31 = lane & 31, hi = lane >> 5;
  const int qr0 = blockIdx.x * 128 + wave * 32;
  const int qa = qr0 + l31;  // this lane's q row
  const ushort* Qp = qext + (size_t)bh * S_LEN * 128;
  const ushort* Kp = kext + (size_t)bh * S_LEN * 128;
  const ushort* Vp = vT + (size_t)bh * HD * S_LEN;

  // Q B-frags, hoisted: frag s covers k = s*16 + hi*8 .. +8 for column q = l31
  bf16x8 qf[8];
#pragma unroll
  for (int s = 0; s < 8; s++)
    qf[s] = *reinterpret_cast<const bf16x8*>(&Qp[(size_t)qa * 128 + s * 16 + hi * 8]);

  f32x16 o0 = {}, o1 = {};
  float m = -1e30f, ls = 0.0f;
  const int ntiles = (qr0 + 95) >> 6;

  for (int t = 0; t < ntiles; ++t) {
    const int kb = t << 6;
    // ---- QK^T (swapped): st0 = kv[kb..kb+31], st1 = kv[kb+32..kb+63]
    f32x16 st0 = {}, st1 = {};
    const ushort* Kt = Kp + (size_t)(kb + l31) * 128 + hi * 8;
#pragma unroll
    for (int s = 0; s < 8; s++) {
      bf16x8 k0 = *reinterpret_cast<const bf16x8*>(Kt + s * 16);
      bf16x8 k1 = *reinterpret_cast<const bf16x8*>(Kt + (size_t)32 * 128 + s * 16);
      st0 = MFMA32(k0, qf[s], st0);
      st1 = MFMA32(k1, qf[s], st1);
    }
    // ---- causal mask (last tile only); kv = kb + crow(r,hi) (+32 for st1)
    if (t == ntiles - 1) {
#pragma unroll
      for (int r = 0; r < 16; r++) {
        int kv = kb + (r & 3) + 8 * (r >> 2) + 4 * hi;
        if (kv > qa) st0[r] = -1e30f;
        if (kv + 32 > qa) st1[r] = -1e30f;
      }
    }
    // ---- online softmax: full row = this lane's 32 values + partner lane (l^32)
    float pm = -1e30f;
#pragma unroll
    for (int r = 0; r < 16; r++) pm = fmaxf(pm, fmaxf(st0[r], st1[r]));
    pm = fmaxf(pm, __shfl_xor(pm, 32));
    float mn = fmaxf(m, pm);
    float corr = __expf(m - mn);
    m = mn;
    float ssum = 0.0f;
#pragma unroll
    for (int r = 0; r < 16; r++) {
      st0[r] = __expf(st0[r] - mn);
      st1[r] = __expf(st1[r] - mn);
      ssum += st0[r] + st1[r];
    }
    ssum += __shfl_xor(ssum, 32);
    ls = ls * corr + ssum;
#pragma unroll
    for (int r = 0; r < 16; r++) { o0[r] *= corr; o1[r] *= corr; }

    // ---- pack P -> bf16 B-frags pb[0..3] (k-steps of 16 kv each)
    u32x4 pb[4];
#pragma unroll
    for (int half = 0; half < 2; half++) {
      const f32x16& st = half ? st1 : st0;
      uint cA0 = pk2(st[0], st[1]),  cA1 = pk2(st[2], st[3]);
      uint cB0 = pk2(st[4], st[5]),  cB1 = pk2(st[6], st[7]);
      uint cC0 = pk2(st[8], st[9]),  cC1 = pk2(st[10], st[11]);
      uint cD0 = pk2(st[12], st[13]), cD1 = pk2(st[14], st[15]);
      uint xA0 = __shfl_xor(cA0, 32), xA1 = __shfl_xor(cA1, 32);
      uint xB0 = __shfl_xor(cB0, 32), xB1 = __shfl_xor(cB1, 32);
      uint xC0 = __shfl_xor(cC0, 32), xC1 = __shfl_xor(cC1, 32);
      uint xD0 = __shfl_xor(cD0, 32), xD1 = __shfl_xor(cD1, 32);
      u32x4 lo, hi4;
      lo[0] = cA0; lo[1] = cA1; lo[2] = xA0; lo[3] = xA1;      // hi==0: kv 0..7
      hi4[0] = xB0; hi4[1] = xB1; hi4[2] = cB0; hi4[3] = cB1;  // hi==1: kv 8..15
      pb[half * 2] = hi ? hi4 : lo;
      u32x4 lo2, hi2;
      lo2[0] = cC0; lo2[1] = cC1; lo2[2] = xC0; lo2[3] = xC1;  // hi==0: kv 16..23
      hi2[0] = xD0; hi2[1] = xD1; hi2[2] = cD0; hi2[3] = cD1;  // hi==1: kv 24..31
      pb[half * 2 + 1] = hi ? hi2 : lo2;
    }
    // ---- PV: A = V^T frags (hd rows), B = P^T frags
    const ushort* Vt = Vp + (size_t)l31 * S_LEN + kb + hi * 8;
#pragma unroll
    for (int ks = 0; ks < 4; ks++) {
      bf16x8 v0 = *reinterpret_cast<const bf16x8*>(Vt + ks * 16);
      bf16x8 v1 = *reinterpret_cast<const bf16x8*>(Vt + (size_t)32 * S_LEN + ks * 16);
      bf16x8 pbb = *reinterpret_cast<const bf16x8*>(&pb[ks]);
      o0 = MFMA32(v0, pbb, o0);
      o1 = MFMA32(v1, pbb, o1);
    }
  }

  // ---- normalize + write: lane owns q-row qa; o regs are hd = crow(r,hi) (+32 for o1)
  float inv = 1.0f / ls;
  ushort* Op = attnout + ((size_t)b * S_LEN + qa) * DM + h * HD;
#pragma unroll
  for (int g4 = 0; g4 < 4; g4++) {
    ushort4v w0, w1;
#pragma unroll
    for (int j = 0; j < 4; j++) {
      w0[j] = f2b(o0[4 * g4 + j] * inv);
      w1[j] = f2b(o1[4 * g4 + j] * inv);
    }
    *reinterpret_cast<ushort4v*>(Op + 8 * g4 + 4 * hi) = w0;
    *reinterpret_cast<ushort4v*>(Op + 32 + 8 * g4 + 4 * hi) = w1;
  }
}

// ----------------------------------------------------------------
extern "C" void kernel_launch(void* const* d_in, const int* in_sizes, int n_in,
                              void* d_out, int out_size, void* d_ws, size_t ws_size,
                              hipStream_t stream) {
  const float* x   = (const float*)d_in[0];
  const float* Wqa = (const float*)d_in[1];
  const float* Wka = (const float*)d_in[2];
  const float* Wqp = (const float*)d_in[3];
  const float* Wkp = (const float*)d_in[4];
  const float* Wv  = (const float*)d_in[5];
  const float* Wo  = (const float*)d_in[6];
  const float* sls = (const float*)d_in[7];

  char* ws = (char*)d_ws;
  ushort* x_bf = (ushort*)ws; ws += (size_t)NTOK * DM * 2;
  ushort* w_bf[6];
  for (int i = 0; i < 6; i++) { w_bf[i] = (ushort*)ws; ws += (size_t)DM * DM * 2; }
  float* qamp = (float*)ws; ws += (size_t)NTOK * DM * 4;
  float* kamp = (float*)ws; ws += (size_t)NTOK * DM * 4;
  float* qphi = (float*)ws; ws += (size_t)NTOK * DM * 4;
  float* kphi = (float*)ws; ws += (size_t)NTOK * DM * 4;
  ushort* v_bf = (ushort*)ws; ws += (size_t)NTOK * DM * 2;
  ushort* qext = (ushort*)ws; ws += (size_t)NBH * S_LEN * 128 * 2;
  ushort* kext = (ushort*)ws; ws += (size_t)NBH * S_LEN * 128 * 2;
  ushort* vT   = (ushort*)ws; ws += (size_t)NBH * HD * S_LEN * 2;
  ushort* attn = (ushort*)ws; ws += (size_t)NTOK * DM * 2;

  // 1. fp32 -> bf16 conversions (x + 6 weights)
  CvtArgs ca;
  ca.src[0] = x; ca.dst[0] = x_bf; ca.n[0] = NTOK * DM;
  const float* wsrc[6] = {Wqa, Wka, Wqp, Wkp, Wv, Wo};
  for (int i = 0; i < 6; i++) { ca.src[i + 1] = wsrc[i]; ca.dst[i + 1] = w_bf[i]; ca.n[i + 1] = DM * DM; }
  dim3 cg((NTOK * DM / 8 + 255) / 256, 7);
  hipLaunchKernelGGL(cvt_kernel, cg, dim3(256), 0, stream, ca);

  // 2-6. projection GEMMs
  dim3 gg(DM / 128, NTOK / 128);
  hipLaunchKernelGGL(gemm_bt, gg, dim3(256), 0, stream, x_bf, w_bf[0], (void*)qamp, NTOK, DM, DM, 1);
  hipLaunchKernelGGL(gemm_bt, gg, dim3(256), 0, stream, x_bf, w_bf[1], (void*)kamp, NTOK, DM, DM, 1);
  hipLaunchKernelGGL(gemm_bt, gg, dim3(256), 0, stream, x_bf, w_bf[2], (void*)qphi, NTOK, DM, DM, 2);
  hipLaunchKernelGGL(gemm_bt, gg, dim3(256), 0, stream, x_bf, w_bf[3], (void*)kphi, NTOK, DM, DM, 2);
  hipLaunchKernelGGL(gemm_bt, gg, dim3(256), 0, stream, x_bf, w_bf[4], (void*)v_bf, NTOK, DM, DM, 0);

  // 7. RMS norm + phase -> qext/kext
  hipLaunchKernelGGL(qkext_kernel, dim3((NTOK * NH) / 4), dim3(256), 0, stream,
                     qamp, qphi, kamp, kphi, sls, qext, kext);

  // 8. V transpose
  hipLaunchKernelGGL(vt_kernel, dim3(S_LEN / 64, NBH), dim3(256), 0, stream, v_bf, vT);

  // 9. causal flash attention (swapped-QK 32x32, 4 indep waves/block)
  hipLaunchKernelGGL(attn_kernel, dim3(S_LEN / 128, NBH), dim3(256), 0, stream,
                     qext, kext, vT, attn);

  // 10. output projection -> fp32 d_out
  hipLaunchKernelGGL(gemm_bt, gg, dim3(256), 0, stream, attn, w_bf[5], d_out, NTOK, DM, DM, 3);
}

// Round 4
// 343.488 us; speedup vs baseline: 1.9352x; 1.4933x over previous
//
#include <hip/hip_runtime.h>
#include <hip/hip_bf16.h>
#include <math.h>

// Problem constants (fixed shapes from setup_inputs)
#define S_LEN 2048
#define NH 16
#define HD 64
#define DM 1024
#define NTOK 4096   // B*S
#define NBH 32      // B*NH

typedef __attribute__((ext_vector_type(8))) __bf16 bf16x8;
typedef __attribute__((ext_vector_type(8))) ushort ushort8;
typedef __attribute__((ext_vector_type(4))) ushort ushort4v;
typedef __attribute__((ext_vector_type(4))) float f32x4;
typedef __attribute__((ext_vector_type(16))) float f32x16;
typedef __attribute__((ext_vector_type(4))) uint u32x4;

__device__ __forceinline__ ushort f2b(float x) {
  __hip_bfloat16 h = __float2bfloat16(x);
  return *reinterpret_cast<ushort*>(&h);
}

__device__ __forceinline__ uint pk2(float lo, float hi) {
  return (uint)f2b(lo) | ((uint)f2b(hi) << 16);
}

__device__ __forceinline__ void gload16b(const void* g, void* l) {
  __builtin_amdgcn_global_load_lds((const __attribute__((address_space(1))) void*)g,
                                   (__attribute__((address_space(3))) void*)l, 16, 0, 0);
}

#define MFMA16(a, b, c) __builtin_amdgcn_mfma_f32_16x16x32_bf16((a), (b), (c), 0, 0, 0)
#define MFMA32(a, b, c) __builtin_amdgcn_mfma_f32_32x32x16_bf16((a), (b), (c), 0, 0, 0)

// ---------------------------------------------------------------- convert fp32 -> bf16
struct CvtArgs {
  const float* src[7];
  ushort* dst[7];
  int n[7];
};

__global__ void cvt_kernel(CvtArgs a) {
  int arr = blockIdx.y;
  long i = ((long)blockIdx.x * blockDim.x + threadIdx.x) * 8;
  if (i >= a.n[arr]) return;
  const float* s = a.src[arr];
  ushort* d = a.dst[arr];
  float4 v0 = *reinterpret_cast<const float4*>(s + i);
  float4 v1 = *reinterpret_cast<const float4*>(s + i + 4);
  ushort8 r;
  r[0] = f2b(v0.x); r[1] = f2b(v0.y); r[2] = f2b(v0.z); r[3] = f2b(v0.w);
  r[4] = f2b(v1.x); r[5] = f2b(v1.y); r[6] = f2b(v1.z); r[7] = f2b(v1.w);
  *reinterpret_cast<ushort8*>(d + i) = r;
}

// ---------------------------------------------------------------- GEMM core (shared by both kernels)
// C = A[M,K] * W[N,K]^T; act: 0 raw->bf16, 1 softplus->f32, 2 pi*tanh->f32, 3 raw->f32
__device__ __forceinline__ void gemm_body(const ushort* __restrict__ A,
                                          const ushort* __restrict__ W,
                                          void* __restrict__ Cout,
                                          int M, int N, int K, int act,
                                          int bx, int by,
                                          ushort* Alds, ushort* Blds) {
  const int t = threadIdx.x;
  const int lane = t & 63;
  const int wave = t >> 6;
  const int wm = wave >> 1, wn = wave & 1;   // 2x2 wave grid, 64x64 each
  const int l15 = lane & 15, g = lane >> 4;
  const int mbase = by * 128, nbase = bx * 128;
  const int srow = t >> 2, scol = (t & 3) * 8;  // staging: 64 rows x 32 cols per issue
  const ushort* Ag = A + (size_t)(mbase + srow) * K + scol;
  const ushort* Wg = W + (size_t)(nbase + srow) * K + scol;
  ushort* Al = Alds + t * 8;
  ushort* Bl = Blds + t * 8;
  f32x4 acc[4][4] = {};
  for (int kt = 0; kt < K; kt += 32) {
    __syncthreads();
    gload16b(Ag + kt, Al);
    gload16b(Ag + kt + (size_t)64 * K, Al + 64 * 32);
    gload16b(Wg + kt, Bl);
    gload16b(Wg + kt + (size_t)64 * K, Bl + 64 * 32);
    asm volatile("s_waitcnt vmcnt(0)" ::: "memory");
    __syncthreads();
    bf16x8 af[4], bfr[4];
#pragma unroll
    for (int i = 0; i < 4; i++)
      af[i] = *reinterpret_cast<const bf16x8*>(&Alds[(wm * 64 + i * 16 + l15) * 32 + g * 8]);
#pragma unroll
    for (int j = 0; j < 4; j++)
      bfr[j] = *reinterpret_cast<const bf16x8*>(&Blds[(wn * 64 + j * 16 + l15) * 32 + g * 8]);
#pragma unroll
    for (int i = 0; i < 4; i++)
#pragma unroll
      for (int j = 0; j < 4; j++)
        acc[i][j] = MFMA16(af[i], bfr[j], acc[i][j]);
  }
  const int row0 = mbase + wm * 64, col0 = nbase + wn * 64;
#pragma unroll
  for (int i = 0; i < 4; i++) {
#pragma unroll
    for (int j = 0; j < 4; j++) {
#pragma unroll
      for (int r = 0; r < 4; r++) {
        int row = row0 + i * 16 + g * 4 + r;   // D layout: row=(lane>>4)*4+r, col=lane&15
        int col = col0 + j * 16 + l15;
        float v = acc[i][j][r];
        size_t off = (size_t)row * N + col;
        if (act == 0) {
          ((ushort*)Cout)[off] = f2b(v);
        } else if (act == 1) {
          ((float*)Cout)[off] = fmaxf(v, 0.0f) + log1pf(expf(-fabsf(v)));
        } else if (act == 2) {
          ((float*)Cout)[off] = 3.14159265358979f * tanhf(v);
        } else {
          ((float*)Cout)[off] = v;
        }
      }
    }
  }
}

// Single GEMM (used for the final Wo projection)
__global__ __launch_bounds__(256) void gemm_bt(const ushort* __restrict__ A,
                                               const ushort* __restrict__ W,
                                               void* __restrict__ Cout,
                                               int M, int N, int K, int act) {
  __shared__ __align__(16) ushort Alds[128 * 32];
  __shared__ __align__(16) ushort Blds[128 * 32];
  gemm_body(A, W, Cout, M, N, K, act, blockIdx.x, blockIdx.y, Alds, Blds);
}

// Batched projection GEMMs: blockIdx.z selects {W, out, act}; shared A.
struct ProjBatch {
  const ushort* W[5];
  void* out[5];
  int act[5];
};

__global__ __launch_bounds__(256) void gemm_proj(const ushort* __restrict__ A, ProjBatch pb,
                                                 int M, int N, int K) {
  __shared__ __align__(16) ushort Alds[128 * 32];
  __shared__ __align__(16) ushort Blds[128 * 32];
  int z = blockIdx.z;
  gemm_body(A, pb.W[z], pb.out[z], M, N, K, pb.act[z], blockIdx.x, blockIdx.y, Alds, Blds);
}

// ---------------------------------------------------------------- RMS-norm + cos/sin interleave
__global__ void qkext_kernel(const float* __restrict__ qamp, const float* __restrict__ qphi,
                             const float* __restrict__ kamp, const float* __restrict__ kphi,
                             const float* __restrict__ sls,
                             ushort* __restrict__ qext, ushort* __restrict__ kext) {
  int wid = blockIdx.x * 4 + (threadIdx.x >> 6);
  int lane = threadIdx.x & 63;
  int h = wid & 15, bs = wid >> 4;
  int b = bs >> 11, s = bs & 2047;
  size_t xoff = (size_t)bs * DM + h * HD + lane;
  size_t eoff = ((size_t)(b * NH + h) * S_LEN + s) * 128 + lane;
  float scale = expf(sls[h]) * 0.125f;
  {
    float amp = qamp[xoff];
    float ss = amp * amp;
#pragma unroll
    for (int mk = 1; mk < 64; mk <<= 1) ss += __shfl_xor(ss, mk);
    float a = amp * rsqrtf(ss * (1.0f / 64.0f) + 1e-6f) * scale;
    float phi = qphi[xoff];
    float sn, cs;
    sincosf(phi, &sn, &cs);
    qext[eoff] = f2b(a * cs);
    qext[eoff + 64] = f2b(a * sn);
  }
  {
    float amp = kamp[xoff];
    float ss = amp * amp;
#pragma unroll
    for (int mk = 1; mk < 64; mk <<= 1) ss += __shfl_xor(ss, mk);
    float a = amp * rsqrtf(ss * (1.0f / 64.0f) + 1e-6f);
    float phi = kphi[xoff];
    float sn, cs;
    sincosf(phi, &sn, &cs);
    kext[eoff] = f2b(a * cs);
    kext[eoff + 64] = f2b(a * sn);
  }
}

// ---------------------------------------------------------------- V transpose: [B,S,H*64] -> [B,H,64,S]
__global__ void vt_kernel(const ushort* __restrict__ v, ushort* __restrict__ vT) {
  __shared__ __align__(16) ushort tile[64][80];
  int bh = blockIdx.y;
  int b = bh >> 4, h = bh & 15;
  int s0 = blockIdx.x * 64;
  int t = threadIdx.x;
  int r = t >> 2, cc = (t & 3) * 16;
  const ushort* src = v + (size_t)(b * S_LEN + s0 + r) * DM + h * HD + cc;
  *reinterpret_cast<ushort8*>(&tile[r][cc]) = *reinterpret_cast<const ushort8*>(src);
  *reinterpret_cast<ushort8*>(&tile[r][cc + 8]) = *reinterpret_cast<const ushort8*>(src + 8);
  __syncthreads();
  int d = t >> 2, sc = (t & 3) * 16;
  ushort8 o0, o1;
#pragma unroll
  for (int i = 0; i < 8; i++) o0[i] = tile[sc + i][d];
#pragma unroll
  for (int i = 0; i < 8; i++) o1[i] = tile[sc + 8 + i][d];
  ushort* dst = vT + ((size_t)bh * HD + d) * S_LEN + s0 + sc;
  *reinterpret_cast<ushort8*>(dst) = o0;
  *reinterpret_cast<ushort8*>(dst + 8) = o1;
}

// ---------------------------------------------------------------- causal flash attention
// Swapped-QK 32x32, 4-way KV split: block = one 32-row q-tile; wave w takes kv tiles
// t = w, w+4, ... with private online-softmax state; LDS merge at the end.
__global__ __launch_bounds__(256, 4) void attn_kernel(const ushort* __restrict__ qext,
                                                      const ushort* __restrict__ kext,
                                                      const ushort* __restrict__ vT,
                                                      ushort* __restrict__ attnout) {
  __shared__ float cmb[3][64][34];
  const int bh = blockIdx.y;
  const int b = bh >> 4, h = bh & 15;
  const int wave = threadIdx.x >> 6, lane = threadIdx.x & 63;
  const int l31 = lane & 31, hi = lane >> 5;
  const int qr0 = blockIdx.x * 32;
  const int qa = qr0 + l31;  // this lane's q row
  const ushort* Qp = qext + (size_t)bh * S_LEN * 128;
  const ushort* Kp = kext + (size_t)bh * S_LEN * 128;
  const ushort* Vp = vT + (size_t)bh * HD * S_LEN;

  // Q B-frags, hoisted: frag s covers k = s*16 + hi*8 .. +8 for column q = l31
  bf16x8 qf[8];
#pragma unroll
  for (int s = 0; s < 8; s++)
    qf[s] = *reinterpret_cast<const bf16x8*>(&Qp[(size_t)qa * 128 + s * 16 + hi * 8]);

  f32x16 o0 = {}, o1 = {};
  float m = -1e30f, ls = 0.0f;
  const int ntiles = (qr0 + 95) >> 6;

  for (int t = wave; t < ntiles; t += 4) {
    const int kb = t << 6;
    // ---- QK^T (swapped): st0 = kv[kb..kb+31], st1 = kv[kb+32..kb+63]
    f32x16 st0 = {}, st1 = {};
    const ushort* Kt = Kp + (size_t)(kb + l31) * 128 + hi * 8;
#pragma unroll
    for (int s = 0; s < 8; s++) {
      bf16x8 k0 = *reinterpret_cast<const bf16x8*>(Kt + s * 16);
      bf16x8 k1 = *reinterpret_cast<const bf16x8*>(Kt + (size_t)32 * 128 + s * 16);
      st0 = MFMA32(k0, qf[s], st0);
      st1 = MFMA32(k1, qf[s], st1);
    }
    // ---- causal mask (last tile only); kv = kb + crow(r,hi) (+32 for st1)
    if (t == ntiles - 1) {
#pragma unroll
      for (int r = 0; r < 16; r++) {
        int kv = kb + (r & 3) + 8 * (r >> 2) + 4 * hi;
        if (kv > qa) st0[r] = -1e30f;
        if (kv + 32 > qa) st1[r] = -1e30f;
      }
    }
    // ---- online softmax with defer-max (T13): skip rescale if max grew < 8
    float pm = -1e30f;
#pragma unroll
    for (int r = 0; r < 16; r++) pm = fmaxf(pm, fmaxf(st0[r], st1[r]));
    pm = fmaxf(pm, __shfl_xor(pm, 32));
    if (!__all(pm <= m + 8.0f)) {
      float mn = fmaxf(m, pm);
      float corr = __expf(m - mn);
      m = mn;
      ls *= corr;
#pragma unroll
      for (int r = 0; r < 16; r++) { o0[r] *= corr; o1[r] *= corr; }
    }
    float ssum = 0.0f;
#pragma unroll
    for (int r = 0; r < 16; r++) {
      st0[r] = __expf(st0[r] - m);
      st1[r] = __expf(st1[r] - m);
      ssum += st0[r] + st1[r];
    }
    ssum += __shfl_xor(ssum, 32);
    ls += ssum;

    // ---- pack P -> bf16 B-frags pb[0..3] (k-steps of 16 kv each)
    u32x4 pb[4];
#pragma unroll
    for (int half = 0; half < 2; half++) {
      const f32x16& st = half ? st1 : st0;
      uint cA0 = pk2(st[0], st[1]),  cA1 = pk2(st[2], st[3]);
      uint cB0 = pk2(st[4], st[5]),  cB1 = pk2(st[6], st[7]);
      uint cC0 = pk2(st[8], st[9]),  cC1 = pk2(st[10], st[11]);
      uint cD0 = pk2(st[12], st[13]), cD1 = pk2(st[14], st[15]);
      uint xA0 = __shfl_xor(cA0, 32), xA1 = __shfl_xor(cA1, 32);
      uint xB0 = __shfl_xor(cB0, 32), xB1 = __shfl_xor(cB1, 32);
      uint xC0 = __shfl_xor(cC0, 32), xC1 = __shfl_xor(cC1, 32);
      uint xD0 = __shfl_xor(cD0, 32), xD1 = __shfl_xor(cD1, 32);
      u32x4 lo, hi4;
      lo[0] = cA0; lo[1] = cA1; lo[2] = xA0; lo[3] = xA1;      // hi==0: kv 0..7
      hi4[0] = xB0; hi4[1] = xB1; hi4[2] = cB0; hi4[3] = cB1;  // hi==1: kv 8..15
      pb[half * 2] = hi ? hi4 : lo;
      u32x4 lo2, hi2;
      lo2[0] = cC0; lo2[1] = cC1; lo2[2] = xC0; lo2[3] = xC1;  // hi==0: kv 16..23
      hi2[0] = xD0; hi2[1] = xD1; hi2[2] = cD0; hi2[3] = cD1;  // hi==1: kv 24..31
      pb[half * 2 + 1] = hi ? hi2 : lo2;
    }
    // ---- PV: A = V^T frags (hd rows), B = P^T frags
    const ushort* Vt = Vp + (size_t)l31 * S_LEN + kb + hi * 8;
#pragma unroll
    for (int ks = 0; ks < 4; ks++) {
      bf16x8 v0 = *reinterpret_cast<const bf16x8*>(Vt + ks * 16);
      bf16x8 v1 = *reinterpret_cast<const bf16x8*>(Vt + (size_t)32 * S_LEN + ks * 16);
      bf16x8 pbb = *reinterpret_cast<const bf16x8*>(&pb[ks]);
      o0 = MFMA32(v0, pbb, o0);
      o1 = MFMA32(v1, pbb, o1);
    }
  }

  // ---- cross-wave merge of the 4 partial online-softmax states
  if (wave) {
    float* c = &cmb[wave - 1][lane][0];
    c[0] = m; c[1] = ls;
#pragma unroll
    for (int r = 0; r < 16; r++) { c[2 + r] = o0[r]; c[18 + r] = o1[r]; }
  }
  __syncthreads();
  if (wave == 0) {
#pragma unroll
    for (int p = 0; p < 3; p++) {
      const float* c = &cmb[p][lane][0];
      float mp = c[0], lsp = c[1];
      float M = fmaxf(m, mp);
      float ca = __expf(m - M), cb = __expf(mp - M);
      m = M;
      ls = ls * ca + lsp * cb;
#pragma unroll
      for (int r = 0; r < 16; r++) {
        o0[r] = o0[r] * ca + c[2 + r] * cb;
        o1[r] = o1[r] * ca + c[18 + r] * cb;
      }
    }
    // ---- normalize + write: lane owns q-row qa; o regs are hd = crow(r,hi) (+32 for o1)
    float inv = 1.0f / ls;
    ushort* Op = attnout + ((size_t)b * S_LEN + qa) * DM + h * HD;
#pragma unroll
    for (int g4 = 0; g4 < 4; g4++) {
      ushort4v w0, w1;
#pragma unroll
      for (int j = 0; j < 4; j++) {
        w0[j] = f2b(o0[4 * g4 + j] * inv);
        w1[j] = f2b(o1[4 * g4 + j] * inv);
      }
      *reinterpret_cast<ushort4v*>(Op + 8 * g4 + 4 * hi) = w0;
      *reinterpret_cast<ushort4v*>(Op + 32 + 8 * g4 + 4 * hi) = w1;
    }
  }
}

// ----------------------------------------------------------------
extern "C" void kernel_launch(void* const* d_in, const int* in_sizes, int n_in,
                              void* d_out, int out_size, void* d_ws, size_t ws_size,
                              hipStream_t stream) {
  const float* x   = (const float*)d_in[0];
  const float* Wqa = (const float*)d_in[1];
  const float* Wka = (const float*)d_in[2];
  const float* Wqp = (const float*)d_in[3];
  const float* Wkp = (const float*)d_in[4];
  const float* Wv  = (const float*)d_in[5];
  const float* Wo  = (const float*)d_in[6];
  const float* sls = (const float*)d_in[7];

  char* ws = (char*)d_ws;
  ushort* x_bf = (ushort*)ws; ws += (size_t)NTOK * DM * 2;
  ushort* w_bf[6];
  for (int i = 0; i < 6; i++) { w_bf[i] = (ushort*)ws; ws += (size_t)DM * DM * 2; }
  float* qamp = (float*)ws; ws += (size_t)NTOK * DM * 4;
  float* kamp = (float*)ws; ws += (size_t)NTOK * DM * 4;
  float* qphi = (float*)ws; ws += (size_t)NTOK * DM * 4;
  float* kphi = (float*)ws; ws += (size_t)NTOK * DM * 4;
  ushort* v_bf = (ushort*)ws; ws += (size_t)NTOK * DM * 2;
  ushort* qext = (ushort*)ws; ws += (size_t)NBH * S_LEN * 128 * 2;
  ushort* kext = (ushort*)ws; ws += (size_t)NBH * S_LEN * 128 * 2;
  ushort* vT   = (ushort*)ws; ws += (size_t)NBH * HD * S_LEN * 2;
  ushort* attn = (ushort*)ws; ws += (size_t)NTOK * DM * 2;

  // 1. fp32 -> bf16 conversions (x + 6 weights)
  CvtArgs ca;
  ca.src[0] = x; ca.dst[0] = x_bf; ca.n[0] = NTOK * DM;
  const float* wsrc[6] = {Wqa, Wka, Wqp, Wkp, Wv, Wo};
  for (int i = 0; i < 6; i++) { ca.src[i + 1] = wsrc[i]; ca.dst[i + 1] = w_bf[i]; ca.n[i + 1] = DM * DM; }
  dim3 cg((NTOK * DM / 8 + 255) / 256, 7);
  hipLaunchKernelGGL(cvt_kernel, cg, dim3(256), 0, stream, ca);

  // 2. five projection GEMMs in ONE dispatch (grid.z picks weight/output/act)
  ProjBatch pbt;
  pbt.W[0] = w_bf[0]; pbt.out[0] = (void*)qamp; pbt.act[0] = 1;
  pbt.W[1] = w_bf[1]; pbt.out[1] = (void*)kamp; pbt.act[1] = 1;
  pbt.W[2] = w_bf[2]; pbt.out[2] = (void*)qphi; pbt.act[2] = 2;
  pbt.W[3] = w_bf[3]; pbt.out[3] = (void*)kphi; pbt.act[3] = 2;
  pbt.W[4] = w_bf[4]; pbt.out[4] = (void*)v_bf; pbt.act[4] = 0;
  dim3 gg5(DM / 128, NTOK / 128, 5);
  hipLaunchKernelGGL(gemm_proj, gg5, dim3(256), 0, stream, x_bf, pbt, NTOK, DM, DM);

  // 3. RMS norm + phase -> qext/kext
  hipLaunchKernelGGL(qkext_kernel, dim3((NTOK * NH) / 4), dim3(256), 0, stream,
                     qamp, qphi, kamp, kphi, sls, qext, kext);

  // 4. V transpose
  hipLaunchKernelGGL(vt_kernel, dim3(S_LEN / 64, NBH), dim3(256), 0, stream, v_bf, vT);

  // 5. causal flash attention (swapped-QK 32x32, 4-way KV split per 32-row q-tile)
  hipLaunchKernelGGL(attn_kernel, dim3(S_LEN / 32, NBH), dim3(256), 0, stream,
                     qext, kext, vT, attn);

  // 6. output projection -> fp32 d_out
  dim3 gg(DM / 128, NTOK / 128);
  hipLaunchKernelGGL(gemm_bt, gg, dim3(256), 0, stream, attn, w_bf[5], d_out, NTOK, DM, DM, 3);
}

// Round 6
// 238.307 us; speedup vs baseline: 2.7894x; 1.4414x over previous
//
#include <hip/hip_runtime.h>
#include <hip/hip_bf16.h>
#include <math.h>

// Problem constants (fixed shapes from setup_inputs)
#define S_LEN 2048
#define NH 16
#define HD 64
#define DM 1024
#define NTOK 4096   // B*S
#define NBH 32      // B*NH

typedef __attribute__((ext_vector_type(8))) __bf16 bf16x8;
typedef __attribute__((ext_vector_type(8))) ushort ushort8;
typedef __attribute__((ext_vector_type(4))) ushort ushort4v;
typedef __attribute__((ext_vector_type(4))) float f32x4;
typedef __attribute__((ext_vector_type(16))) float f32x16;
typedef __attribute__((ext_vector_type(4))) uint u32x4;

__device__ __forceinline__ ushort f2b(float x) {
  __hip_bfloat16 h = __float2bfloat16(x);
  return *reinterpret_cast<ushort*>(&h);
}

__device__ __forceinline__ uint pk2(float lo, float hi) {
  return (uint)f2b(lo) | ((uint)f2b(hi) << 16);
}

__device__ __forceinline__ void gload16b(const void* g, void* l) {
  __builtin_amdgcn_global_load_lds((const __attribute__((address_space(1))) void*)g,
                                   (__attribute__((address_space(3))) void*)l, 16, 0, 0);
}

#define MFMA16(a, b, c) __builtin_amdgcn_mfma_f32_16x16x32_bf16((a), (b), (c), 0, 0, 0)
#define MFMA32(a, b, c) __builtin_amdgcn_mfma_f32_32x32x16_bf16((a), (b), (c), 0, 0, 0)

// ---------------------------------------------------------------- convert fp32 -> bf16
struct CvtArgs {
  const float* src[7];
  ushort* dst[7];
  int n[7];
};

__global__ void cvt_kernel(CvtArgs a) {
  int arr = blockIdx.y;
  long i = ((long)blockIdx.x * blockDim.x + threadIdx.x) * 8;
  if (i >= a.n[arr]) return;
  const float* s = a.src[arr];
  ushort* d = a.dst[arr];
  float4 v0 = *reinterpret_cast<const float4*>(s + i);
  float4 v1 = *reinterpret_cast<const float4*>(s + i + 4);
  ushort8 r;
  r[0] = f2b(v0.x); r[1] = f2b(v0.y); r[2] = f2b(v0.z); r[3] = f2b(v0.w);
  r[4] = f2b(v1.x); r[5] = f2b(v1.y); r[6] = f2b(v1.z); r[7] = f2b(v1.w);
  *reinterpret_cast<ushort8*>(d + i) = r;
}

// ---------------------------------------------------------------- GEMM core
// C = A[M,K] * W[N,K]^T; act: 0 raw->bf16, 1 softplus->f32, 2 pi*tanh->f32, 3 raw->f32
__device__ __forceinline__ void gemm_body(const ushort* __restrict__ A,
                                          const ushort* __restrict__ W,
                                          void* __restrict__ Cout,
                                          int M, int N, int K, int act,
                                          int bx, int by,
                                          ushort* Alds, ushort* Blds) {
  const int t = threadIdx.x;
  const int lane = t & 63;
  const int wave = t >> 6;
  const int wm = wave >> 1, wn = wave & 1;   // 2x2 wave grid, 64x64 each
  const int l15 = lane & 15, g = lane >> 4;
  const int mbase = by * 128, nbase = bx * 128;
  const int srow = t >> 2, scol = (t & 3) * 8;  // staging: 64 rows x 32 cols per issue
  const ushort* Ag = A + (size_t)(mbase + srow) * K + scol;
  const ushort* Wg = W + (size_t)(nbase + srow) * K + scol;
  ushort* Al = Alds + t * 8;
  ushort* Bl = Blds + t * 8;
  f32x4 acc[4][4] = {};
  for (int kt = 0; kt < K; kt += 32) {
    __syncthreads();
    gload16b(Ag + kt, Al);
    gload16b(Ag + kt + (size_t)64 * K, Al + 64 * 32);
    gload16b(Wg + kt, Bl);
    gload16b(Wg + kt + (size_t)64 * K, Bl + 64 * 32);
    asm volatile("s_waitcnt vmcnt(0)" ::: "memory");
    __syncthreads();
    bf16x8 af[4], bfr[4];
#pragma unroll
    for (int i = 0; i < 4; i++)
      af[i] = *reinterpret_cast<const bf16x8*>(&Alds[(wm * 64 + i * 16 + l15) * 32 + g * 8]);
#pragma unroll
    for (int j = 0; j < 4; j++)
      bfr[j] = *reinterpret_cast<const bf16x8*>(&Blds[(wn * 64 + j * 16 + l15) * 32 + g * 8]);
#pragma unroll
    for (int i = 0; i < 4; i++)
#pragma unroll
      for (int j = 0; j < 4; j++)
        acc[i][j] = MFMA16(af[i], bfr[j], acc[i][j]);
  }
  const int row0 = mbase + wm * 64, col0 = nbase + wn * 64;
#pragma unroll
  for (int i = 0; i < 4; i++) {
#pragma unroll
    for (int j = 0; j < 4; j++) {
#pragma unroll
      for (int r = 0; r < 4; r++) {
        int row = row0 + i * 16 + g * 4 + r;   // D layout: row=(lane>>4)*4+r, col=lane&15
        int col = col0 + j * 16 + l15;
        float v = acc[i][j][r];
        size_t off = (size_t)row * N + col;
        if (act == 0) {
          ((ushort*)Cout)[off] = f2b(v);
        } else if (act == 1) {
          ((float*)Cout)[off] = fmaxf(v, 0.0f) + log1pf(expf(-fabsf(v)));
        } else if (act == 2) {
          ((float*)Cout)[off] = 3.14159265358979f * tanhf(v);
        } else {
          ((float*)Cout)[off] = v;
        }
      }
    }
  }
}

// Single GEMM (used for the final Wo projection)
__global__ __launch_bounds__(256) void gemm_bt(const ushort* __restrict__ A,
                                               const ushort* __restrict__ W,
                                               void* __restrict__ Cout,
                                               int M, int N, int K, int act) {
  __shared__ __align__(16) ushort Alds[128 * 32];
  __shared__ __align__(16) ushort Blds[128 * 32];
  gemm_body(A, W, Cout, M, N, K, act, blockIdx.x, blockIdx.y, Alds, Blds);
}

// Batched projection GEMMs: blockIdx.z selects {W, out, act}; shared A.
struct ProjBatch {
  const ushort* W[5];
  void* out[5];
  int act[5];
};

__global__ __launch_bounds__(256) void gemm_proj(const ushort* __restrict__ A, ProjBatch pb,
                                                 int M, int N, int K) {
  __shared__ __align__(16) ushort Alds[128 * 32];
  __shared__ __align__(16) ushort Blds[128 * 32];
  int z = blockIdx.z;
  gemm_body(A, pb.W[z], pb.out[z], M, N, K, pb.act[z], blockIdx.x, blockIdx.y, Alds, Blds);
}

// ---------------------------------------------------------------- RMS-norm + cos/sin interleave
__global__ void qkext_kernel(const float* __restrict__ qamp, const float* __restrict__ qphi,
                             const float* __restrict__ kamp, const float* __restrict__ kphi,
                             const float* __restrict__ sls,
                             ushort* __restrict__ qext, ushort* __restrict__ kext) {
  int wid = blockIdx.x * 4 + (threadIdx.x >> 6);
  int lane = threadIdx.x & 63;
  int h = wid & 15, bs = wid >> 4;
  int b = bs >> 11, s = bs & 2047;
  size_t xoff = (size_t)bs * DM + h * HD + lane;
  size_t eoff = ((size_t)(b * NH + h) * S_LEN + s) * 128 + lane;
  float scale = expf(sls[h]) * 0.125f;
  {
    float amp = qamp[xoff];
    float ss = amp * amp;
#pragma unroll
    for (int mk = 1; mk < 64; mk <<= 1) ss += __shfl_xor(ss, mk);
    float a = amp * rsqrtf(ss * (1.0f / 64.0f) + 1e-6f) * scale;
    float phi = qphi[xoff];
    float sn, cs;
    sincosf(phi, &sn, &cs);
    qext[eoff] = f2b(a * cs);
    qext[eoff + 64] = f2b(a * sn);
  }
  {
    float amp = kamp[xoff];
    float ss = amp * amp;
#pragma unroll
    for (int mk = 1; mk < 64; mk <<= 1) ss += __shfl_xor(ss, mk);
    float a = amp * rsqrtf(ss * (1.0f / 64.0f) + 1e-6f);
    float phi = kphi[xoff];
    float sn, cs;
    sincosf(phi, &sn, &cs);
    kext[eoff] = f2b(a * cs);
    kext[eoff + 64] = f2b(a * sn);
  }
}

// ---------------------------------------------------------------- V transpose: [B,S,H*64] -> [B,H,64,S]
__global__ void vt_kernel(const ushort* __restrict__ v, ushort* __restrict__ vT) {
  __shared__ __align__(16) ushort tile[64][80];
  int bh = blockIdx.y;
  int b = bh >> 4, h = bh & 15;
  int s0 = blockIdx.x * 64;
  int t = threadIdx.x;
  int r = t >> 2, cc = (t & 3) * 16;
  const ushort* src = v + (size_t)(b * S_LEN + s0 + r) * DM + h * HD + cc;
  *reinterpret_cast<ushort8*>(&tile[r][cc]) = *reinterpret_cast<const ushort8*>(src);
  *reinterpret_cast<ushort8*>(&tile[r][cc + 8]) = *reinterpret_cast<const ushort8*>(src + 8);
  __syncthreads();
  int d = t >> 2, sc = (t & 3) * 16;
  ushort8 o0, o1;
#pragma unroll
  for (int i = 0; i < 8; i++) o0[i] = tile[sc + i][d];
#pragma unroll
  for (int i = 0; i < 8; i++) o1[i] = tile[sc + 8 + i][d];
  ushort* dst = vT + ((size_t)bh * HD + d) * S_LEN + s0 + sc;
  *reinterpret_cast<ushort8*>(dst) = o0;
  *reinterpret_cast<ushort8*>(dst + 8) = o1;
}

// ---------------------------------------------------------------- causal flash attention
// Block = 128 q-rows (4 waves x 32-row swapped-QK). All waves share K/V tiles staged in
// LDS (global_load_lds, XOR-swizzled src), double-buffered with counted vmcnt(6) + raw
// s_barrier (T3-minimum pipeline). Per-wave private online softmax; no cross-wave merge.
__device__ __forceinline__ void stage_kv(const char* Kp, const char* Vp, int kb,
                                         char* buf, int wave, int lane) {
  // K tile: [64 kv][128 k] bf16 = 16KB, 16 chunks of 1KB; slot swizzle: slot ^= kv&7
#pragma unroll
  for (int c = 0; c < 4; c++) {
    int i = wave * 4 + c;
    int kvl = i * 4 + (lane >> 4);
    int slot = (lane & 15) ^ (kvl & 7);
    gload16b(Kp + (size_t)(kb + kvl) * 256 + slot * 16, buf + i * 1024);
  }
  // V tile: [64 hd][64 kv] bf16 = 8KB, 8 chunks of 1KB; slot swizzle: slot ^= hd&7
#pragma unroll
  for (int c = 0; c < 2; c++) {
    int i = wave * 2 + c;
    int hd = i * 8 + (lane >> 3);
    int slot = (lane & 7) ^ (hd & 7);
    gload16b(Vp + (size_t)hd * (S_LEN * 2) + (size_t)kb * 2 + slot * 16,
             buf + 16384 + i * 1024);
  }
}

__global__ __launch_bounds__(256, 2) void attn_kernel(const ushort* __restrict__ qext,
                                                      const ushort* __restrict__ kext,
                                                      const ushort* __restrict__ vT,
                                                      ushort* __restrict__ attnout) {
  __shared__ __align__(16) char lds[2][24576];  // [buf][16KB K + 8KB V]
  // flat grid 512; pairing swizzle: CU's 2 resident blocks get qt j and 15-j (uniform work)
  const int u = blockIdx.x;
  const int uh = u >> 8, v = u & 255;
  const int bh = v >> 3, j = v & 7;
  const int qt = uh ? (15 - j) : j;
  const int b = bh >> 4, h = bh & 15;
  const int wave = threadIdx.x >> 6, lane = threadIdx.x & 63;
  const int l31 = lane & 31, hi = lane >> 5;
  const int qb = qt * 128;
  const int qw = qb + wave * 32;        // this wave's q-row start
  const int qa = qw + l31;              // this lane's q row
  const char* Kp = (const char*)(kext + (size_t)bh * S_LEN * 128);
  const char* Vp = (const char*)(vT + (size_t)bh * HD * S_LEN);
  const ushort* Qp = qext + (size_t)bh * S_LEN * 128;
  const int nt = 2 * qt + 2;
  const int ksw = l31 & 7;

  // prologue: stage tile 0, then hoist Q frags
  stage_kv(Kp, Vp, 0, lds[0], wave, lane);
  bf16x8 qf[8];
#pragma unroll
  for (int s = 0; s < 8; s++)
    qf[s] = *reinterpret_cast<const bf16x8*>(&Qp[(size_t)qa * 128 + s * 16 + hi * 8]);

  f32x16 o0 = {}, o1 = {};
  float m = -1e30f, ls = 0.0f;

  for (int t = 0; t < nt; ++t) {
    const int cur = t & 1;
    const int kb = t << 6;
    if (t + 1 < nt) {
      stage_kv(Kp, Vp, (t + 1) << 6, lds[cur ^ 1], wave, lane);
      asm volatile("s_waitcnt vmcnt(6)" ::: "memory");  // buf[cur] writes complete
    } else {
      asm volatile("s_waitcnt vmcnt(0)" ::: "memory");
    }
    __builtin_amdgcn_s_barrier();  // all waves' stage of buf[cur] done

    const char* Kb = lds[cur];
    const char* Vb = lds[cur] + 16384;

    // ---- QK^T (swapped): st0 = kv[kb..kb+31], st1 = kv[kb+32..kb+63]
    f32x16 st0 = {}, st1 = {};
    __builtin_amdgcn_s_setprio(1);
#pragma unroll
    for (int s = 0; s < 8; s++) {
      int sl = ((s * 2 + hi) ^ ksw) << 4;
      bf16x8 k0 = *(const bf16x8*)(Kb + l31 * 256 + sl);
      bf16x8 k1 = *(const bf16x8*)(Kb + (32 + l31) * 256 + sl);
      st0 = MFMA32(k0, qf[s], st0);
      st1 = MFMA32(k1, qf[s], st1);
    }
    __builtin_amdgcn_s_setprio(0);

    // ---- causal mask; trigger whenever tile reaches past this wave's first row:
    // tile covers kv kb..kb+63, wave rows start at qw -> mask needed iff kb+63 > qw,
    // i.e. (64-aligned kb, 32-aligned qw) kb + 64 > qw.  [R5 bug: used kb+32 > qw,
    // missing the st1 diagonal for waves with qw ≡ 32 (mod 64)]
    if (kb + 64 > qw) {
#pragma unroll
      for (int r = 0; r < 16; r++) {
        int kv = kb + (r & 3) + 8 * (r >> 2) + 4 * hi;
        if (kv > qa) st0[r] = -1e30f;
        if (kv + 32 > qa) st1[r] = -1e30f;
      }
    }
    // ---- online softmax with defer-max (T13)
    float pm = -1e30f;
#pragma unroll
    for (int r = 0; r < 16; r++) pm = fmaxf(pm, fmaxf(st0[r], st1[r]));
    pm = fmaxf(pm, __shfl_xor(pm, 32));
    if (!__all(pm <= m + 8.0f)) {
      float mn = fmaxf(m, pm);
      float corr = __expf(m - mn);
      m = mn;
      ls *= corr;
#pragma unroll
      for (int r = 0; r < 16; r++) { o0[r] *= corr; o1[r] *= corr; }
    }
    float ssum = 0.0f;
#pragma unroll
    for (int r = 0; r < 16; r++) {
      st0[r] = __expf(st0[r] - m);
      st1[r] = __expf(st1[r] - m);
      ssum += st0[r] + st1[r];
    }
    ssum += __shfl_xor(ssum, 32);
    ls += ssum;

    // ---- pack P -> bf16 B-frags pb[0..3] (k-steps of 16 kv each)
    u32x4 pb[4];
#pragma unroll
    for (int half = 0; half < 2; half++) {
      const f32x16& st = half ? st1 : st0;
      uint cA0 = pk2(st[0], st[1]),  cA1 = pk2(st[2], st[3]);
      uint cB0 = pk2(st[4], st[5]),  cB1 = pk2(st[6], st[7]);
      uint cC0 = pk2(st[8], st[9]),  cC1 = pk2(st[10], st[11]);
      uint cD0 = pk2(st[12], st[13]), cD1 = pk2(st[14], st[15]);
      uint xA0 = __shfl_xor(cA0, 32), xA1 = __shfl_xor(cA1, 32);
      uint xB0 = __shfl_xor(cB0, 32), xB1 = __shfl_xor(cB1, 32);
      uint xC0 = __shfl_xor(cC0, 32), xC1 = __shfl_xor(cC1, 32);
      uint xD0 = __shfl_xor(cD0, 32), xD1 = __shfl_xor(cD1, 32);
      u32x4 lo, hi4;
      lo[0] = cA0; lo[1] = cA1; lo[2] = xA0; lo[3] = xA1;      // hi==0: kv 0..7
      hi4[0] = xB0; hi4[1] = xB1; hi4[2] = cB0; hi4[3] = cB1;  // hi==1: kv 8..15
      pb[half * 2] = hi ? hi4 : lo;
      u32x4 lo2, hi2;
      lo2[0] = cC0; lo2[1] = cC1; lo2[2] = xC0; lo2[3] = xC1;  // hi==0: kv 16..23
      hi2[0] = xD0; hi2[1] = xD1; hi2[2] = cD0; hi2[3] = cD1;  // hi==1: kv 24..31
      pb[half * 2 + 1] = hi ? hi2 : lo2;
    }
    // ---- PV: A = V^T frags from LDS, B = P^T frags
    __builtin_amdgcn_s_setprio(1);
#pragma unroll
    for (int ks = 0; ks < 4; ks++) {
      int sl = ((ks * 2 + hi) ^ ksw) << 4;
      bf16x8 v0 = *(const bf16x8*)(Vb + l31 * 128 + sl);
      bf16x8 v1 = *(const bf16x8*)(Vb + (32 + l31) * 128 + sl);
      bf16x8 pbb = *reinterpret_cast<const bf16x8*>(&pb[ks]);
      o0 = MFMA32(v0, pbb, o0);
      o1 = MFMA32(v1, pbb, o1);
    }
    __builtin_amdgcn_s_setprio(0);
    __builtin_amdgcn_s_barrier();  // all waves done reading buf[cur] before overwrite
  }

  // ---- normalize + write: lane owns q-row qa; o regs are hd = crow(r,hi) (+32 for o1)
  float inv = 1.0f / ls;
  ushort* Op = attnout + ((size_t)b * S_LEN + qa) * DM + h * HD;
#pragma unroll
  for (int g4 = 0; g4 < 4; g4++) {
    ushort4v w0, w1;
#pragma unroll
    for (int jj = 0; jj < 4; jj++) {
      w0[jj] = f2b(o0[4 * g4 + jj] * inv);
      w1[jj] = f2b(o1[4 * g4 + jj] * inv);
    }
    *reinterpret_cast<ushort4v*>(Op + 8 * g4 + 4 * hi) = w0;
    *reinterpret_cast<ushort4v*>(Op + 32 + 8 * g4 + 4 * hi) = w1;
  }
}

// ----------------------------------------------------------------
extern "C" void kernel_launch(void* const* d_in, const int* in_sizes, int n_in,
                              void* d_out, int out_size, void* d_ws, size_t ws_size,
                              hipStream_t stream) {
  const float* x   = (const float*)d_in[0];
  const float* Wqa = (const float*)d_in[1];
  const float* Wka = (const float*)d_in[2];
  const float* Wqp = (const float*)d_in[3];
  const float* Wkp = (const float*)d_in[4];
  const float* Wv  = (const float*)d_in[5];
  const float* Wo  = (const float*)d_in[6];
  const float* sls = (const float*)d_in[7];

  char* ws = (char*)d_ws;
  ushort* x_bf = (ushort*)ws; ws += (size_t)NTOK * DM * 2;
  ushort* w_bf[6];
  for (int i = 0; i < 6; i++) { w_bf[i] = (ushort*)ws; ws += (size_t)DM * DM * 2; }
  float* qamp = (float*)ws; ws += (size_t)NTOK * DM * 4;
  float* kamp = (float*)ws; ws += (size_t)NTOK * DM * 4;
  float* qphi = (float*)ws; ws += (size_t)NTOK * DM * 4;
  float* kphi = (float*)ws; ws += (size_t)NTOK * DM * 4;
  ushort* v_bf = (ushort*)ws; ws += (size_t)NTOK * DM * 2;
  ushort* qext = (ushort*)ws; ws += (size_t)NBH * S_LEN * 128 * 2;
  ushort* kext = (ushort*)ws; ws += (size_t)NBH * S_LEN * 128 * 2;
  ushort* vT   = (ushort*)ws; ws += (size_t)NBH * HD * S_LEN * 2;
  ushort* attn = (ushort*)ws; ws += (size_t)NTOK * DM * 2;

  // 1. fp32 -> bf16 conversions (x + 6 weights)
  CvtArgs ca;
  ca.src[0] = x; ca.dst[0] = x_bf; ca.n[0] = NTOK * DM;
  const float* wsrc[6] = {Wqa, Wka, Wqp, Wkp, Wv, Wo};
  for (int i = 0; i < 6; i++) { ca.src[i + 1] = wsrc[i]; ca.dst[i + 1] = w_bf[i]; ca.n[i + 1] = DM * DM; }
  dim3 cg((NTOK * DM / 8 + 255) / 256, 7);
  hipLaunchKernelGGL(cvt_kernel, cg, dim3(256), 0, stream, ca);

  // 2. five projection GEMMs in ONE dispatch (grid.z picks weight/output/act)
  ProjBatch pbt;
  pbt.W[0] = w_bf[0]; pbt.out[0] = (void*)qamp; pbt.act[0] = 1;
  pbt.W[1] = w_bf[1]; pbt.out[1] = (void*)kamp; pbt.act[1] = 1;
  pbt.W[2] = w_bf[2]; pbt.out[2] = (void*)qphi; pbt.act[2] = 2;
  pbt.W[3] = w_bf[3]; pbt.out[3] = (void*)kphi; pbt.act[3] = 2;
  pbt.W[4] = w_bf[4]; pbt.out[4] = (void*)v_bf; pbt.act[4] = 0;
  dim3 gg5(DM / 128, NTOK / 128, 5);
  hipLaunchKernelGGL(gemm_proj, gg5, dim3(256), 0, stream, x_bf, pbt, NTOK, DM, DM);

  // 3. RMS norm + phase -> qext/kext
  hipLaunchKernelGGL(qkext_kernel, dim3((NTOK * NH) / 4), dim3(256), 0, stream,
                     qamp, qphi, kamp, kphi, sls, qext, kext);

  // 4. V transpose
  hipLaunchKernelGGL(vt_kernel, dim3(S_LEN / 64, NBH), dim3(256), 0, stream, v_bf, vT);

  // 5. causal flash attention (128-row blocks, LDS-staged K/V, 2-phase pipeline)
  hipLaunchKernelGGL(attn_kernel, dim3(512), dim3(256), 0, stream,
                     qext, kext, vT, attn);

  // 6. output projection -> fp32 d_out
  dim3 gg(DM / 128, NTOK / 128);
  hipLaunchKernelGGL(gemm_bt, gg, dim3(256), 0, stream, attn, w_bf[5], d_out, NTOK, DM, DM, 3);
}

// Round 7
// 196.979 us; speedup vs baseline: 3.3746x; 1.2098x over previous
//
#include <hip/hip_runtime.h>
#include <hip/hip_bf16.h>
#include <math.h>

// Problem constants (fixed shapes from setup_inputs)
#define S_LEN 2048
#define NH 16
#define HD 64
#define DM 1024
#define NTOK 4096   // B*S
#define NBH 32      // B*NH

typedef __attribute__((ext_vector_type(8))) __bf16 bf16x8;
typedef __attribute__((ext_vector_type(8))) ushort ushort8;
typedef __attribute__((ext_vector_type(4))) ushort ushort4v;
typedef __attribute__((ext_vector_type(4))) float f32x4;
typedef __attribute__((ext_vector_type(16))) float f32x16;
typedef __attribute__((ext_vector_type(4))) uint u32x4;

__device__ __forceinline__ ushort f2b(float x) {
  __hip_bfloat16 h = __float2bfloat16(x);
  return *reinterpret_cast<ushort*>(&h);
}

__device__ __forceinline__ uint pk2(float lo, float hi) {
  return (uint)f2b(lo) | ((uint)f2b(hi) << 16);
}

__device__ __forceinline__ void gload16b(const void* g, void* l) {
  __builtin_amdgcn_global_load_lds((const __attribute__((address_space(1))) void*)g,
                                   (__attribute__((address_space(3))) void*)l, 16, 0, 0);
}

#define MFMA16(a, b, c) __builtin_amdgcn_mfma_f32_16x16x32_bf16((a), (b), (c), 0, 0, 0)
#define MFMA32(a, b, c) __builtin_amdgcn_mfma_f32_32x32x16_bf16((a), (b), (c), 0, 0, 0)

// ---------------------------------------------------------------- convert fp32 -> bf16
struct CvtArgs {
  const float* src[7];
  ushort* dst[7];
  int n[7];
};

__global__ void cvt_kernel(CvtArgs a) {
  int arr = blockIdx.y;
  long i = ((long)blockIdx.x * blockDim.x + threadIdx.x) * 8;
  if (i >= a.n[arr]) return;
  const float* s = a.src[arr];
  ushort* d = a.dst[arr];
  float4 v0 = *reinterpret_cast<const float4*>(s + i);
  float4 v1 = *reinterpret_cast<const float4*>(s + i + 4);
  ushort8 r;
  r[0] = f2b(v0.x); r[1] = f2b(v0.y); r[2] = f2b(v0.z); r[3] = f2b(v0.w);
  r[4] = f2b(v1.x); r[5] = f2b(v1.y); r[6] = f2b(v1.z); r[7] = f2b(v1.w);
  *reinterpret_cast<ushort8*>(d + i) = r;
}

// ---------------------------------------------------------------- GEMM core
// C = A[M,K] * W[N,K]^T; act: 0 raw->bf16, 1 softplus->f32, 2 pi*tanh->f32, 3 raw->f32
// Double-buffered LDS, counted vmcnt(4) + raw s_barrier (T3-minimum 2-phase pipeline).
// Epilogue uses fast hw transcendentals (v_exp/v_log/v_rcp) instead of libm.
__device__ __forceinline__ void gemm_body(const ushort* __restrict__ A,
                                          const ushort* __restrict__ W,
                                          void* __restrict__ Cout,
                                          int M, int N, int K, int act,
                                          int bx, int by,
                                          ushort* Alds, ushort* Blds) {
  const int t = threadIdx.x;
  const int lane = t & 63;
  const int wave = t >> 6;
  const int wm = wave >> 1, wn = wave & 1;   // 2x2 wave grid, 64x64 each
  const int l15 = lane & 15, g = lane >> 4;
  const int mbase = by * 128, nbase = bx * 128;
  const int srow = t >> 2, scol = (t & 3) * 8;  // staging: 64 rows x 32 cols per issue
  const ushort* Ag = A + (size_t)(mbase + srow) * K + scol;
  const ushort* Wg = W + (size_t)(nbase + srow) * K + scol;

  // stage one 128x32 A-tile + B-tile into buffer `buf` (4 gload16b / thread)
  auto stage = [&](int buf, int kt) {
    ushort* Al = Alds + buf * 4096 + t * 8;
    ushort* Bl = Blds + buf * 4096 + t * 8;
    gload16b(Ag + kt, Al);
    gload16b(Ag + kt + (size_t)64 * K, Al + 64 * 32);
    gload16b(Wg + kt, Bl);
    gload16b(Wg + kt + (size_t)64 * K, Bl + 64 * 32);
  };

  const int nk = K / 32;
  stage(0, 0);
  f32x4 acc[4][4] = {};
  for (int kt = 0; kt < nk; ++kt) {
    const int cur = kt & 1;
    if (kt + 1 < nk) {
      stage(cur ^ 1, (kt + 1) * 32);
      asm volatile("s_waitcnt vmcnt(4)" ::: "memory");  // buf[cur]'s 4 loads complete
    } else {
      asm volatile("s_waitcnt vmcnt(0)" ::: "memory");
    }
    __builtin_amdgcn_s_barrier();  // buf[cur] fully staged by all waves
    const ushort* Ab = Alds + cur * 4096;
    const ushort* Bb = Blds + cur * 4096;
    bf16x8 af[4], bfr[4];
#pragma unroll
    for (int i = 0; i < 4; i++)
      af[i] = *reinterpret_cast<const bf16x8*>(&Ab[(wm * 64 + i * 16 + l15) * 32 + g * 8]);
#pragma unroll
    for (int j = 0; j < 4; j++)
      bfr[j] = *reinterpret_cast<const bf16x8*>(&Bb[(wn * 64 + j * 16 + l15) * 32 + g * 8]);
    __builtin_amdgcn_s_setprio(1);
#pragma unroll
    for (int i = 0; i < 4; i++)
#pragma unroll
      for (int j = 0; j < 4; j++)
        acc[i][j] = MFMA16(af[i], bfr[j], acc[i][j]);
    __builtin_amdgcn_s_setprio(0);
    __builtin_amdgcn_s_barrier();  // all waves done reading buf[cur] before overwrite
  }
  const int row0 = mbase + wm * 64, col0 = nbase + wn * 64;
#pragma unroll
  for (int i = 0; i < 4; i++) {
#pragma unroll
    for (int j = 0; j < 4; j++) {
#pragma unroll
      for (int r = 0; r < 4; r++) {
        int row = row0 + i * 16 + g * 4 + r;   // D layout: row=(lane>>4)*4+r, col=lane&15
        int col = col0 + j * 16 + l15;
        float v = acc[i][j][r];
        size_t off = (size_t)row * N + col;
        if (act == 0) {
          ((ushort*)Cout)[off] = f2b(v);
        } else if (act == 1) {
          // softplus via hw exp/log: max(v,0) + log(1 + e^-|v|)
          float sp = fmaxf(v, 0.0f) + __logf(1.0f + __expf(-fabsf(v)));
          ((float*)Cout)[off] = sp;
        } else if (act == 2) {
          // pi * tanh(v) = pi * (1 - 2/(e^{2v}+1)); saturates correctly at +-inf
          float e = __expf(2.0f * v);
          float th = 1.0f - 2.0f * __builtin_amdgcn_rcpf(e + 1.0f);
          ((float*)Cout)[off] = 3.14159265358979f * th;
        } else {
          ((float*)Cout)[off] = v;
        }
      }
    }
  }
}

// Single GEMM (used for the final Wo projection)
__global__ __launch_bounds__(256) void gemm_bt(const ushort* __restrict__ A,
                                               const ushort* __restrict__ W,
                                               void* __restrict__ Cout,
                                               int M, int N, int K, int act) {
  __shared__ __align__(16) ushort Alds[2 * 4096];
  __shared__ __align__(16) ushort Blds[2 * 4096];
  gemm_body(A, W, Cout, M, N, K, act, blockIdx.x, blockIdx.y, Alds, Blds);
}

// Batched projection GEMMs: blockIdx.z selects {W, out, act}; shared A.
struct ProjBatch {
  const ushort* W[5];
  void* out[5];
  int act[5];
};

__global__ __launch_bounds__(256) void gemm_proj(const ushort* __restrict__ A, ProjBatch pb,
                                                 int M, int N, int K) {
  __shared__ __align__(16) ushort Alds[2 * 4096];
  __shared__ __align__(16) ushort Blds[2 * 4096];
  int z = blockIdx.z;
  gemm_body(A, pb.W[z], pb.out[z], M, N, K, pb.act[z], blockIdx.x, blockIdx.y, Alds, Blds);
}

// ---------------------------------------------------------------- RMS-norm + cos/sin interleave
__global__ void qkext_kernel(const float* __restrict__ qamp, const float* __restrict__ qphi,
                             const float* __restrict__ kamp, const float* __restrict__ kphi,
                             const float* __restrict__ sls,
                             ushort* __restrict__ qext, ushort* __restrict__ kext) {
  int wid = blockIdx.x * 4 + (threadIdx.x >> 6);
  int lane = threadIdx.x & 63;
  int h = wid & 15, bs = wid >> 4;
  int b = bs >> 11, s = bs & 2047;
  size_t xoff = (size_t)bs * DM + h * HD + lane;
  size_t eoff = ((size_t)(b * NH + h) * S_LEN + s) * 128 + lane;
  float scale = expf(sls[h]) * 0.125f;
  {
    float amp = qamp[xoff];
    float ss = amp * amp;
#pragma unroll
    for (int mk = 1; mk < 64; mk <<= 1) ss += __shfl_xor(ss, mk);
    float a = amp * rsqrtf(ss * (1.0f / 64.0f) + 1e-6f) * scale;
    float phi = qphi[xoff];
    float sn, cs;
    sincosf(phi, &sn, &cs);
    qext[eoff] = f2b(a * cs);
    qext[eoff + 64] = f2b(a * sn);
  }
  {
    float amp = kamp[xoff];
    float ss = amp * amp;
#pragma unroll
    for (int mk = 1; mk < 64; mk <<= 1) ss += __shfl_xor(ss, mk);
    float a = amp * rsqrtf(ss * (1.0f / 64.0f) + 1e-6f);
    float phi = kphi[xoff];
    float sn, cs;
    sincosf(phi, &sn, &cs);
    kext[eoff] = f2b(a * cs);
    kext[eoff + 64] = f2b(a * sn);
  }
}

// ---------------------------------------------------------------- V transpose: [B,S,H*64] -> [B,H,64,S]
__global__ void vt_kernel(const ushort* __restrict__ v, ushort* __restrict__ vT) {
  __shared__ __align__(16) ushort tile[64][80];
  int bh = blockIdx.y;
  int b = bh >> 4, h = bh & 15;
  int s0 = blockIdx.x * 64;
  int t = threadIdx.x;
  int r = t >> 2, cc = (t & 3) * 16;
  const ushort* src = v + (size_t)(b * S_LEN + s0 + r) * DM + h * HD + cc;
  *reinterpret_cast<ushort8*>(&tile[r][cc]) = *reinterpret_cast<const ushort8*>(src);
  *reinterpret_cast<ushort8*>(&tile[r][cc + 8]) = *reinterpret_cast<const ushort8*>(src + 8);
  __syncthreads();
  int d = t >> 2, sc = (t & 3) * 16;
  ushort8 o0, o1;
#pragma unroll
  for (int i = 0; i < 8; i++) o0[i] = tile[sc + i][d];
#pragma unroll
  for (int i = 0; i < 8; i++) o1[i] = tile[sc + 8 + i][d];
  ushort* dst = vT + ((size_t)bh * HD + d) * S_LEN + s0 + sc;
  *reinterpret_cast<ushort8*>(dst) = o0;
  *reinterpret_cast<ushort8*>(dst + 8) = o1;
}

// ---------------------------------------------------------------- causal flash attention
// Block = 128 q-rows (4 waves x 32-row swapped-QK). All waves share K/V tiles staged in
// LDS (global_load_lds, XOR-swizzled src), double-buffered with counted vmcnt(6) + raw
// s_barrier (T3-minimum pipeline). Per-wave private online softmax; no cross-wave merge.
__device__ __forceinline__ void stage_kv(const char* Kp, const char* Vp, int kb,
                                         char* buf, int wave, int lane) {
  // K tile: [64 kv][128 k] bf16 = 16KB, 16 chunks of 1KB; slot swizzle: slot ^= kv&7
#pragma unroll
  for (int c = 0; c < 4; c++) {
    int i = wave * 4 + c;
    int kvl = i * 4 + (lane >> 4);
    int slot = (lane & 15) ^ (kvl & 7);
    gload16b(Kp + (size_t)(kb + kvl) * 256 + slot * 16, buf + i * 1024);
  }
  // V tile: [64 hd][64 kv] bf16 = 8KB, 8 chunks of 1KB; slot swizzle: slot ^= hd&7
#pragma unroll
  for (int c = 0; c < 2; c++) {
    int i = wave * 2 + c;
    int hd = i * 8 + (lane >> 3);
    int slot = (lane & 7) ^ (hd & 7);
    gload16b(Vp + (size_t)hd * (S_LEN * 2) + (size_t)kb * 2 + slot * 16,
             buf + 16384 + i * 1024);
  }
}

__global__ __launch_bounds__(256, 2) void attn_kernel(const ushort* __restrict__ qext,
                                                      const ushort* __restrict__ kext,
                                                      const ushort* __restrict__ vT,
                                                      ushort* __restrict__ attnout) {
  __shared__ __align__(16) char lds[2][24576];  // [buf][16KB K + 8KB V]
  // flat grid 512; pairing swizzle: CU's 2 resident blocks get qt j and 15-j (uniform work)
  const int u = blockIdx.x;
  const int uh = u >> 8, v = u & 255;
  const int bh = v >> 3, j = v & 7;
  const int qt = uh ? (15 - j) : j;
  const int b = bh >> 4, h = bh & 15;
  const int wave = threadIdx.x >> 6, lane = threadIdx.x & 63;
  const int l31 = lane & 31, hi = lane >> 5;
  const int qb = qt * 128;
  const int qw = qb + wave * 32;        // this wave's q-row start
  const int qa = qw + l31;              // this lane's q row
  const char* Kp = (const char*)(kext + (size_t)bh * S_LEN * 128);
  const char* Vp = (const char*)(vT + (size_t)bh * HD * S_LEN);
  const ushort* Qp = qext + (size_t)bh * S_LEN * 128;
  const int nt = 2 * qt + 2;
  const int ksw = l31 & 7;

  // prologue: stage tile 0, then hoist Q frags
  stage_kv(Kp, Vp, 0, lds[0], wave, lane);
  bf16x8 qf[8];
#pragma unroll
  for (int s = 0; s < 8; s++)
    qf[s] = *reinterpret_cast<const bf16x8*>(&Qp[(size_t)qa * 128 + s * 16 + hi * 8]);

  f32x16 o0 = {}, o1 = {};
  float m = -1e30f, ls = 0.0f;

  for (int t = 0; t < nt; ++t) {
    const int cur = t & 1;
    const int kb = t << 6;
    if (t + 1 < nt) {
      stage_kv(Kp, Vp, (t + 1) << 6, lds[cur ^ 1], wave, lane);
      asm volatile("s_waitcnt vmcnt(6)" ::: "memory");  // buf[cur] writes complete
    } else {
      asm volatile("s_waitcnt vmcnt(0)" ::: "memory");
    }
    __builtin_amdgcn_s_barrier();  // all waves' stage of buf[cur] done

    const char* Kb = lds[cur];
    const char* Vb = lds[cur] + 16384;

    // ---- QK^T (swapped): st0 = kv[kb..kb+31], st1 = kv[kb+32..kb+63]
    f32x16 st0 = {}, st1 = {};
    __builtin_amdgcn_s_setprio(1);
#pragma unroll
    for (int s = 0; s < 8; s++) {
      int sl = ((s * 2 + hi) ^ ksw) << 4;
      bf16x8 k0 = *(const bf16x8*)(Kb + l31 * 256 + sl);
      bf16x8 k1 = *(const bf16x8*)(Kb + (32 + l31) * 256 + sl);
      st0 = MFMA32(k0, qf[s], st0);
      st1 = MFMA32(k1, qf[s], st1);
    }
    __builtin_amdgcn_s_setprio(0);

    // ---- causal mask; trigger whenever tile reaches past this wave's first row:
    // tile covers kv kb..kb+63, wave rows start at qw -> mask needed iff kb+64 > qw.
    if (kb + 64 > qw) {
#pragma unroll
      for (int r = 0; r < 16; r++) {
        int kv = kb + (r & 3) + 8 * (r >> 2) + 4 * hi;
        if (kv > qa) st0[r] = -1e30f;
        if (kv + 32 > qa) st1[r] = -1e30f;
      }
    }
    // ---- online softmax with defer-max (T13)
    float pm = -1e30f;
#pragma unroll
    for (int r = 0; r < 16; r++) pm = fmaxf(pm, fmaxf(st0[r], st1[r]));
    pm = fmaxf(pm, __shfl_xor(pm, 32));
    if (!__all(pm <= m + 8.0f)) {
      float mn = fmaxf(m, pm);
      float corr = __expf(m - mn);
      m = mn;
      ls *= corr;
#pragma unroll
      for (int r = 0; r < 16; r++) { o0[r] *= corr; o1[r] *= corr; }
    }
    float ssum = 0.0f;
#pragma unroll
    for (int r = 0; r < 16; r++) {
      st0[r] = __expf(st0[r] - m);
      st1[r] = __expf(st1[r] - m);
      ssum += st0[r] + st1[r];
    }
    ssum += __shfl_xor(ssum, 32);
    ls += ssum;

    // ---- pack P -> bf16 B-frags pb[0..3] (k-steps of 16 kv each)
    u32x4 pb[4];
#pragma unroll
    for (int half = 0; half < 2; half++) {
      const f32x16& st = half ? st1 : st0;
      uint cA0 = pk2(st[0], st[1]),  cA1 = pk2(st[2], st[3]);
      uint cB0 = pk2(st[4], st[5]),  cB1 = pk2(st[6], st[7]);
      uint cC0 = pk2(st[8], st[9]),  cC1 = pk2(st[10], st[11]);
      uint cD0 = pk2(st[12], st[13]), cD1 = pk2(st[14], st[15]);
      uint xA0 = __shfl_xor(cA0, 32), xA1 = __shfl_xor(cA1, 32);
      uint xB0 = __shfl_xor(cB0, 32), xB1 = __shfl_xor(cB1, 32);
      uint xC0 = __shfl_xor(cC0, 32), xC1 = __shfl_xor(cC1, 32);
      uint xD0 = __shfl_xor(cD0, 32), xD1 = __shfl_xor(cD1, 32);
      u32x4 lo, hi4;
      lo[0] = cA0; lo[1] = cA1; lo[2] = xA0; lo[3] = xA1;      // hi==0: kv 0..7
      hi4[0] = xB0; hi4[1] = xB1; hi4[2] = cB0; hi4[3] = cB1;  // hi==1: kv 8..15
      pb[half * 2] = hi ? hi4 : lo;
      u32x4 lo2, hi2;
      lo2[0] = cC0; lo2[1] = cC1; lo2[2] = xC0; lo2[3] = xC1;  // hi==0: kv 16..23
      hi2[0] = xD0; hi2[1] = xD1; hi2[2] = cD0; hi2[3] = cD1;  // hi==1: kv 24..31
      pb[half * 2 + 1] = hi ? hi2 : lo2;
    }
    // ---- PV: A = V^T frags from LDS, B = P^T frags
    __builtin_amdgcn_s_setprio(1);
#pragma unroll
    for (int ks = 0; ks < 4; ks++) {
      int sl = ((ks * 2 + hi) ^ ksw) << 4;
      bf16x8 v0 = *(const bf16x8*)(Vb + l31 * 128 + sl);
      bf16x8 v1 = *(const bf16x8*)(Vb + (32 + l31) * 128 + sl);
      bf16x8 pbb = *reinterpret_cast<const bf16x8*>(&pb[ks]);
      o0 = MFMA32(v0, pbb, o0);
      o1 = MFMA32(v1, pbb, o1);
    }
    __builtin_amdgcn_s_setprio(0);
    __builtin_amdgcn_s_barrier();  // all waves done reading buf[cur] before overwrite
  }

  // ---- normalize + write: lane owns q-row qa; o regs are hd = crow(r,hi) (+32 for o1)
  float inv = 1.0f / ls;
  ushort* Op = attnout + ((size_t)b * S_LEN + qa) * DM + h * HD;
#pragma unroll
  for (int g4 = 0; g4 < 4; g4++) {
    ushort4v w0, w1;
#pragma unroll
    for (int jj = 0; jj < 4; jj++) {
      w0[jj] = f2b(o0[4 * g4 + jj] * inv);
      w1[jj] = f2b(o1[4 * g4 + jj] * inv);
    }
    *reinterpret_cast<ushort4v*>(Op + 8 * g4 + 4 * hi) = w0;
    *reinterpret_cast<ushort4v*>(Op + 32 + 8 * g4 + 4 * hi) = w1;
  }
}

// ----------------------------------------------------------------
extern "C" void kernel_launch(void* const* d_in, const int* in_sizes, int n_in,
                              void* d_out, int out_size, void* d_ws, size_t ws_size,
                              hipStream_t stream) {
  const float* x   = (const float*)d_in[0];
  const float* Wqa = (const float*)d_in[1];
  const float* Wka = (const float*)d_in[2];
  const float* Wqp = (const float*)d_in[3];
  const float* Wkp = (const float*)d_in[4];
  const float* Wv  = (const float*)d_in[5];
  const float* Wo  = (const float*)d_in[6];
  const float* sls = (const float*)d_in[7];

  char* ws = (char*)d_ws;
  ushort* x_bf = (ushort*)ws; ws += (size_t)NTOK * DM * 2;
  ushort* w_bf[6];
  for (int i = 0; i < 6; i++) { w_bf[i] = (ushort*)ws; ws += (size_t)DM * DM * 2; }
  float* qamp = (float*)ws; ws += (size_t)NTOK * DM * 4;
  float* kamp = (float*)ws; ws += (size_t)NTOK * DM * 4;
  float* qphi = (float*)ws; ws += (size_t)NTOK * DM * 4;
  float* kphi = (float*)ws; ws += (size_t)NTOK * DM * 4;
  ushort* v_bf = (ushort*)ws; ws += (size_t)NTOK * DM * 2;
  ushort* qext = (ushort*)ws; ws += (size_t)NBH * S_LEN * 128 * 2;
  ushort* kext = (ushort*)ws; ws += (size_t)NBH * S_LEN * 128 * 2;
  ushort* vT   = (ushort*)ws; ws += (size_t)NBH * HD * S_LEN * 2;
  ushort* attn = (ushort*)ws; ws += (size_t)NTOK * DM * 2;

  // 1. fp32 -> bf16 conversions (x + 6 weights)
  CvtArgs ca;
  ca.src[0] = x; ca.dst[0] = x_bf; ca.n[0] = NTOK * DM;
  const float* wsrc[6] = {Wqa, Wka, Wqp, Wkp, Wv, Wo};
  for (int i = 0; i < 6; i++) { ca.src[i + 1] = wsrc[i]; ca.dst[i + 1] = w_bf[i]; ca.n[i + 1] = DM * DM; }
  dim3 cg((NTOK * DM / 8 + 255) / 256, 7);
  hipLaunchKernelGGL(cvt_kernel, cg, dim3(256), 0, stream, ca);

  // 2. five projection GEMMs in ONE dispatch (grid.z picks weight/output/act)
  ProjBatch pbt;
  pbt.W[0] = w_bf[0]; pbt.out[0] = (void*)qamp; pbt.act[0] = 1;
  pbt.W[1] = w_bf[1]; pbt.out[1] = (void*)kamp; pbt.act[1] = 1;
  pbt.W[2] = w_bf[2]; pbt.out[2] = (void*)qphi; pbt.act[2] = 2;
  pbt.W[3] = w_bf[3]; pbt.out[3] = (void*)kphi; pbt.act[3] = 2;
  pbt.W[4] = w_bf[4]; pbt.out[4] = (void*)v_bf; pbt.act[4] = 0;
  dim3 gg5(DM / 128, NTOK / 128, 5);
  hipLaunchKernelGGL(gemm_proj, gg5, dim3(256), 0, stream, x_bf, pbt, NTOK, DM, DM);

  // 3. RMS norm + phase -> qext/kext
  hipLaunchKernelGGL(qkext_kernel, dim3((NTOK * NH) / 4), dim3(256), 0, stream,
                     qamp, qphi, kamp, kphi, sls, qext, kext);

  // 4. V transpose
  hipLaunchKernelGGL(vt_kernel, dim3(S_LEN / 64, NBH), dim3(256), 0, stream, v_bf, vT);

  // 5. causal flash attention (128-row blocks, LDS-staged K/V, 2-phase pipeline)
  hipLaunchKernelGGL(attn_kernel, dim3(512), dim3(256), 0, stream,
                     qext, kext, vT, attn);

  // 6. output projection -> fp32 d_out
  dim3 gg(DM / 128, NTOK / 128);
  hipLaunchKernelGGL(gemm_bt, gg, dim3(256), 0, stream, attn, w_bf[5], d_out, NTOK, DM, DM, 3);
}

// Round 8
// 167.808 us; speedup vs baseline: 3.9613x; 1.1738x over previous
//
#include <hip/hip_runtime.h>
#include <hip/hip_bf16.h>
#include <math.h>

// Problem constants (fixed shapes from setup_inputs)
#define S_LEN 2048
#define NH 16
#define HD 64
#define DM 1024
#define NTOK 4096   // B*S
#define NBH 32      // B*NH

typedef __attribute__((ext_vector_type(8))) __bf16 bf16x8;
typedef __attribute__((ext_vector_type(8))) ushort ushort8;
typedef __attribute__((ext_vector_type(4))) ushort ushort4v;
typedef __attribute__((ext_vector_type(4))) float f32x4;
typedef __attribute__((ext_vector_type(16))) float f32x16;
typedef __attribute__((ext_vector_type(4))) uint u32x4;

__device__ __forceinline__ ushort f2b(float x) {
  __hip_bfloat16 h = __float2bfloat16(x);
  return *reinterpret_cast<ushort*>(&h);
}

__device__ __forceinline__ uint pk2(float lo, float hi) {
  return (uint)f2b(lo) | ((uint)f2b(hi) << 16);
}

__device__ __forceinline__ void gload16b(const void* g, void* l) {
  __builtin_amdgcn_global_load_lds((const __attribute__((address_space(1))) void*)g,
                                   (__attribute__((address_space(3))) void*)l, 16, 0, 0);
}

#define MFMA16(a, b, c) __builtin_amdgcn_mfma_f32_16x16x32_bf16((a), (b), (c), 0, 0, 0)
#define MFMA32(a, b, c) __builtin_amdgcn_mfma_f32_32x32x16_bf16((a), (b), (c), 0, 0, 0)

// ---------------------------------------------------------------- convert fp32 -> bf16
struct CvtArgs {
  const float* src[7];
  ushort* dst[7];
  int n[7];
};

__global__ void cvt_kernel(CvtArgs a) {
  int arr = blockIdx.y;
  long i = ((long)blockIdx.x * blockDim.x + threadIdx.x) * 8;
  if (i >= a.n[arr]) return;
  const float* s = a.src[arr];
  ushort* d = a.dst[arr];
  float4 v0 = *reinterpret_cast<const float4*>(s + i);
  float4 v1 = *reinterpret_cast<const float4*>(s + i + 4);
  ushort8 r;
  r[0] = f2b(v0.x); r[1] = f2b(v0.y); r[2] = f2b(v0.z); r[3] = f2b(v0.w);
  r[4] = f2b(v1.x); r[5] = f2b(v1.y); r[6] = f2b(v1.z); r[7] = f2b(v1.w);
  *reinterpret_cast<ushort8*>(d + i) = r;
}

// ---------------------------------------------------------------- fused QK projection
// z=0: q (amp=A@Wqa^T, phi=A@Wqp^T), z=1: k, z=2: v (plain GEMM -> bf16).
// Dual path: both products accumulated per tile; epilogue does softplus + RMS-norm over
// the head dim (one wave quadrant = 64 tokens x one head's 64 dims; row lives across
// 16 lanes x 4 j-regs -> 4 shfl_xor reduce) + pi*tanh -> sincos, writes ext directly.
__global__ __launch_bounds__(256, 2) void qkproj_kernel(
    const ushort* __restrict__ A,
    const ushort* __restrict__ Wqa, const ushort* __restrict__ Wqp,
    const ushort* __restrict__ Wka, const ushort* __restrict__ Wkp,
    const ushort* __restrict__ Wv, const float* __restrict__ sls,
    ushort* __restrict__ qext, ushort* __restrict__ kext, ushort* __restrict__ v_bf) {
  __shared__ __align__(16) ushort Alds[2][4096];
  __shared__ __align__(16) ushort B0lds[2][4096];
  __shared__ __align__(16) ushort B1lds[2][4096];
  const int z = blockIdx.z;
  const int t = threadIdx.x;
  const int lane = t & 63;
  const int wave = t >> 6;
  const int wm = wave >> 1, wn = wave & 1;
  const int l15 = lane & 15, g = lane >> 4;
  const int mbase = blockIdx.y * 128, nbase = blockIdx.x * 128;
  const int K = DM, N = DM;
  const int srow = t >> 2, scol = (t & 3) * 8;
  const ushort* Ag = A + (size_t)(mbase + srow) * K + scol;
  const ushort* Wa = (z == 0) ? Wqa : (z == 1) ? Wka : Wv;
  const ushort* Wp = (z == 0) ? Wqp : Wkp;  // unused for z==2
  const ushort* Wag = Wa + (size_t)(nbase + srow) * K + scol;
  const ushort* Wpg = (z < 2) ? (Wp + (size_t)(nbase + srow) * K + scol) : Wag;

  const int nk = K / 32;
  f32x4 accA[4][4] = {};

  if (z < 2) {
    // ---------------- dual GEMM ----------------
    f32x4 accP[4][4] = {};
    auto stage = [&](int buf, int kt) {
      gload16b(Ag + kt, &Alds[buf][t * 8]);
      gload16b(Ag + kt + (size_t)64 * K, &Alds[buf][t * 8 + 64 * 32]);
      gload16b(Wag + kt, &B0lds[buf][t * 8]);
      gload16b(Wag + kt + (size_t)64 * K, &B0lds[buf][t * 8 + 64 * 32]);
      gload16b(Wpg + kt, &B1lds[buf][t * 8]);
      gload16b(Wpg + kt + (size_t)64 * K, &B1lds[buf][t * 8 + 64 * 32]);
    };
    stage(0, 0);
    for (int kt = 0; kt < nk; ++kt) {
      const int cur = kt & 1;
      if (kt + 1 < nk) {
        stage(cur ^ 1, (kt + 1) * 32);
        asm volatile("s_waitcnt vmcnt(6)" ::: "memory");
      } else {
        asm volatile("s_waitcnt vmcnt(0)" ::: "memory");
      }
      __builtin_amdgcn_s_barrier();
      bf16x8 af[4], ba[4], bp[4];
#pragma unroll
      for (int i = 0; i < 4; i++)
        af[i] = *reinterpret_cast<const bf16x8*>(&Alds[cur][(wm * 64 + i * 16 + l15) * 32 + g * 8]);
#pragma unroll
      for (int j = 0; j < 4; j++) {
        ba[j] = *reinterpret_cast<const bf16x8*>(&B0lds[cur][(wn * 64 + j * 16 + l15) * 32 + g * 8]);
        bp[j] = *reinterpret_cast<const bf16x8*>(&B1lds[cur][(wn * 64 + j * 16 + l15) * 32 + g * 8]);
      }
      __builtin_amdgcn_s_setprio(1);
#pragma unroll
      for (int i = 0; i < 4; i++)
#pragma unroll
        for (int j = 0; j < 4; j++) {
          accA[i][j] = MFMA16(af[i], ba[j], accA[i][j]);
          accP[i][j] = MFMA16(af[i], bp[j], accP[i][j]);
        }
      __builtin_amdgcn_s_setprio(0);
      __builtin_amdgcn_s_barrier();
    }
    // ---------------- fused epilogue ----------------
    const int row0 = mbase + wm * 64;
    const int h = (nbase >> 6) + wn;              // head index (nbase + wn*64)/64
    const float scale = (z == 0) ? __expf(sls[h]) * 0.125f : 1.0f;
    ushort* ext = (z == 0) ? qext : kext;
#pragma unroll
    for (int i = 0; i < 4; i++) {
#pragma unroll
      for (int r = 0; r < 4; r++) {
        // softplus amplitudes for this token row (4 j-regs/lane)
        float sp[4];
        float ss = 0.0f;
#pragma unroll
        for (int j = 0; j < 4; j++) {
          float v = accA[i][j][r];
          sp[j] = fmaxf(v, 0.0f) + __logf(1.0f + __expf(-fabsf(v)));
          ss += sp[j] * sp[j];
        }
        // reduce sum-of-squares across the 16 lanes holding this row
        ss += __shfl_xor(ss, 1);
        ss += __shfl_xor(ss, 2);
        ss += __shfl_xor(ss, 4);
        ss += __shfl_xor(ss, 8);
        float rn = rsqrtf(ss * (1.0f / 64.0f) + 1e-6f) * scale;
        const int token = row0 + i * 16 + g * 4 + r;
        const int bb = token >> 11, sidx = token & 2047;
        ushort* base = ext + (((size_t)(bb * NH + h) * S_LEN + sidx) << 7);
#pragma unroll
        for (int j = 0; j < 4; j++) {
          float e = __expf(2.0f * accP[i][j][r]);
          float th = 1.0f - 2.0f * __builtin_amdgcn_rcpf(e + 1.0f);
          float phi = 3.14159265358979f * th;
          float sn = __sinf(phi), cs = __cosf(phi);
          float a = sp[j] * rn;
          int d = j * 16 + l15;
          base[d] = f2b(a * cs);
          base[64 + d] = f2b(a * sn);
        }
      }
    }
  } else {
    // ---------------- plain V GEMM -> bf16 ----------------
    auto stage = [&](int buf, int kt) {
      gload16b(Ag + kt, &Alds[buf][t * 8]);
      gload16b(Ag + kt + (size_t)64 * K, &Alds[buf][t * 8 + 64 * 32]);
      gload16b(Wag + kt, &B0lds[buf][t * 8]);
      gload16b(Wag + kt + (size_t)64 * K, &B0lds[buf][t * 8 + 64 * 32]);
    };
    stage(0, 0);
    for (int kt = 0; kt < nk; ++kt) {
      const int cur = kt & 1;
      if (kt + 1 < nk) {
        stage(cur ^ 1, (kt + 1) * 32);
        asm volatile("s_waitcnt vmcnt(4)" ::: "memory");
      } else {
        asm volatile("s_waitcnt vmcnt(0)" ::: "memory");
      }
      __builtin_amdgcn_s_barrier();
      bf16x8 af[4], ba[4];
#pragma unroll
      for (int i = 0; i < 4; i++)
        af[i] = *reinterpret_cast<const bf16x8*>(&Alds[cur][(wm * 64 + i * 16 + l15) * 32 + g * 8]);
#pragma unroll
      for (int j = 0; j < 4; j++)
        ba[j] = *reinterpret_cast<const bf16x8*>(&B0lds[cur][(wn * 64 + j * 16 + l15) * 32 + g * 8]);
      __builtin_amdgcn_s_setprio(1);
#pragma unroll
      for (int i = 0; i < 4; i++)
#pragma unroll
        for (int j = 0; j < 4; j++)
          accA[i][j] = MFMA16(af[i], ba[j], accA[i][j]);
      __builtin_amdgcn_s_setprio(0);
      __builtin_amdgcn_s_barrier();
    }
    const int row0 = mbase + wm * 64, col0 = nbase + wn * 64;
#pragma unroll
    for (int i = 0; i < 4; i++)
#pragma unroll
      for (int j = 0; j < 4; j++)
#pragma unroll
        for (int r = 0; r < 4; r++) {
          int row = row0 + i * 16 + g * 4 + r;
          int col = col0 + j * 16 + l15;
          v_bf[(size_t)row * N + col] = f2b(accA[i][j][r]);
        }
  }
}

// ---------------------------------------------------------------- GEMM (Wo projection)
// C = A[M,K] * W[N,K]^T -> fp32; double-buffered, counted vmcnt(4), fast epilogue.
__global__ __launch_bounds__(256) void gemm_bt(const ushort* __restrict__ A,
                                               const ushort* __restrict__ W,
                                               float* __restrict__ Cout,
                                               int M, int N, int K) {
  __shared__ __align__(16) ushort Alds[2 * 4096];
  __shared__ __align__(16) ushort Blds[2 * 4096];
  const int t = threadIdx.x;
  const int lane = t & 63;
  const int wave = t >> 6;
  const int wm = wave >> 1, wn = wave & 1;
  const int l15 = lane & 15, g = lane >> 4;
  const int mbase = blockIdx.y * 128, nbase = blockIdx.x * 128;
  const int srow = t >> 2, scol = (t & 3) * 8;
  const ushort* Ag = A + (size_t)(mbase + srow) * K + scol;
  const ushort* Wg = W + (size_t)(nbase + srow) * K + scol;
  auto stage = [&](int buf, int kt) {
    ushort* Al = Alds + buf * 4096 + t * 8;
    ushort* Bl = Blds + buf * 4096 + t * 8;
    gload16b(Ag + kt, Al);
    gload16b(Ag + kt + (size_t)64 * K, Al + 64 * 32);
    gload16b(Wg + kt, Bl);
    gload16b(Wg + kt + (size_t)64 * K, Bl + 64 * 32);
  };
  const int nk = K / 32;
  stage(0, 0);
  f32x4 acc[4][4] = {};
  for (int kt = 0; kt < nk; ++kt) {
    const int cur = kt & 1;
    if (kt + 1 < nk) {
      stage(cur ^ 1, (kt + 1) * 32);
      asm volatile("s_waitcnt vmcnt(4)" ::: "memory");
    } else {
      asm volatile("s_waitcnt vmcnt(0)" ::: "memory");
    }
    __builtin_amdgcn_s_barrier();
    const ushort* Ab = Alds + cur * 4096;
    const ushort* Bb = Blds + cur * 4096;
    bf16x8 af[4], bfr[4];
#pragma unroll
    for (int i = 0; i < 4; i++)
      af[i] = *reinterpret_cast<const bf16x8*>(&Ab[(wm * 64 + i * 16 + l15) * 32 + g * 8]);
#pragma unroll
    for (int j = 0; j < 4; j++)
      bfr[j] = *reinterpret_cast<const bf16x8*>(&Bb[(wn * 64 + j * 16 + l15) * 32 + g * 8]);
    __builtin_amdgcn_s_setprio(1);
#pragma unroll
    for (int i = 0; i < 4; i++)
#pragma unroll
      for (int j = 0; j < 4; j++)
        acc[i][j] = MFMA16(af[i], bfr[j], acc[i][j]);
    __builtin_amdgcn_s_setprio(0);
    __builtin_amdgcn_s_barrier();
  }
  const int row0 = mbase + wm * 64, col0 = nbase + wn * 64;
#pragma unroll
  for (int i = 0; i < 4; i++)
#pragma unroll
    for (int j = 0; j < 4; j++)
#pragma unroll
      for (int r = 0; r < 4; r++) {
        int row = row0 + i * 16 + g * 4 + r;
        int col = col0 + j * 16 + l15;
        Cout[(size_t)row * N + col] = acc[i][j][r];
      }
}

// ---------------------------------------------------------------- V transpose: [B,S,H*64] -> [B,H,64,S]
__global__ void vt_kernel(const ushort* __restrict__ v, ushort* __restrict__ vT) {
  __shared__ __align__(16) ushort tile[64][80];
  int bh = blockIdx.y;
  int b = bh >> 4, h = bh & 15;
  int s0 = blockIdx.x * 64;
  int t = threadIdx.x;
  int r = t >> 2, cc = (t & 3) * 16;
  const ushort* src = v + (size_t)(b * S_LEN + s0 + r) * DM + h * HD + cc;
  *reinterpret_cast<ushort8*>(&tile[r][cc]) = *reinterpret_cast<const ushort8*>(src);
  *reinterpret_cast<ushort8*>(&tile[r][cc + 8]) = *reinterpret_cast<const ushort8*>(src + 8);
  __syncthreads();
  int d = t >> 2, sc = (t & 3) * 16;
  ushort8 o0, o1;
#pragma unroll
  for (int i = 0; i < 8; i++) o0[i] = tile[sc + i][d];
#pragma unroll
  for (int i = 0; i < 8; i++) o1[i] = tile[sc + 8 + i][d];
  ushort* dst = vT + ((size_t)bh * HD + d) * S_LEN + s0 + sc;
  *reinterpret_cast<ushort8*>(dst) = o0;
  *reinterpret_cast<ushort8*>(dst + 8) = o1;
}

// ---------------------------------------------------------------- causal flash attention
// Block = 128 q-rows (4 waves x 32-row swapped-QK). K/V staged in LDS (global_load_lds,
// XOR-swizzled src), double-buffered, counted vmcnt(6) + raw s_barrier.
__device__ __forceinline__ void stage_kv(const char* Kp, const char* Vp, int kb,
                                         char* buf, int wave, int lane) {
#pragma unroll
  for (int c = 0; c < 4; c++) {
    int i = wave * 4 + c;
    int kvl = i * 4 + (lane >> 4);
    int slot = (lane & 15) ^ (kvl & 7);
    gload16b(Kp + (size_t)(kb + kvl) * 256 + slot * 16, buf + i * 1024);
  }
#pragma unroll
  for (int c = 0; c < 2; c++) {
    int i = wave * 2 + c;
    int hd = i * 8 + (lane >> 3);
    int slot = (lane & 7) ^ (hd & 7);
    gload16b(Vp + (size_t)hd * (S_LEN * 2) + (size_t)kb * 2 + slot * 16,
             buf + 16384 + i * 1024);
  }
}

__global__ __launch_bounds__(256, 2) void attn_kernel(const ushort* __restrict__ qext,
                                                      const ushort* __restrict__ kext,
                                                      const ushort* __restrict__ vT,
                                                      ushort* __restrict__ attnout) {
  __shared__ __align__(16) char lds[2][24576];
  const int u = blockIdx.x;
  const int uh = u >> 8, v = u & 255;
  const int bh = v >> 3, j = v & 7;
  const int qt = uh ? (15 - j) : j;
  const int b = bh >> 4, h = bh & 15;
  const int wave = threadIdx.x >> 6, lane = threadIdx.x & 63;
  const int l31 = lane & 31, hi = lane >> 5;
  const int qb = qt * 128;
  const int qw = qb + wave * 32;
  const int qa = qw + l31;
  const char* Kp = (const char*)(kext + (size_t)bh * S_LEN * 128);
  const char* Vp = (const char*)(vT + (size_t)bh * HD * S_LEN);
  const ushort* Qp = qext + (size_t)bh * S_LEN * 128;
  const int nt = 2 * qt + 2;
  const int ksw = l31 & 7;

  stage_kv(Kp, Vp, 0, lds[0], wave, lane);
  bf16x8 qf[8];
#pragma unroll
  for (int s = 0; s < 8; s++)
    qf[s] = *reinterpret_cast<const bf16x8*>(&Qp[(size_t)qa * 128 + s * 16 + hi * 8]);

  f32x16 o0 = {}, o1 = {};
  float m = -1e30f, ls = 0.0f;

  for (int t = 0; t < nt; ++t) {
    const int cur = t & 1;
    const int kb = t << 6;
    if (t + 1 < nt) {
      stage_kv(Kp, Vp, (t + 1) << 6, lds[cur ^ 1], wave, lane);
      asm volatile("s_waitcnt vmcnt(6)" ::: "memory");
    } else {
      asm volatile("s_waitcnt vmcnt(0)" ::: "memory");
    }
    __builtin_amdgcn_s_barrier();

    const char* Kb = lds[cur];
    const char* Vb = lds[cur] + 16384;

    f32x16 st0 = {}, st1 = {};
    __builtin_amdgcn_s_setprio(1);
#pragma unroll
    for (int s = 0; s < 8; s++) {
      int sl = ((s * 2 + hi) ^ ksw) << 4;
      bf16x8 k0 = *(const bf16x8*)(Kb + l31 * 256 + sl);
      bf16x8 k1 = *(const bf16x8*)(Kb + (32 + l31) * 256 + sl);
      st0 = MFMA32(k0, qf[s], st0);
      st1 = MFMA32(k1, qf[s], st1);
    }
    __builtin_amdgcn_s_setprio(0);

    if (kb + 64 > qw) {
#pragma unroll
      for (int r = 0; r < 16; r++) {
        int kv = kb + (r & 3) + 8 * (r >> 2) + 4 * hi;
        if (kv > qa) st0[r] = -1e30f;
        if (kv + 32 > qa) st1[r] = -1e30f;
      }
    }
    float pm = -1e30f;
#pragma unroll
    for (int r = 0; r < 16; r++) pm = fmaxf(pm, fmaxf(st0[r], st1[r]));
    pm = fmaxf(pm, __shfl_xor(pm, 32));
    if (!__all(pm <= m + 8.0f)) {
      float mn = fmaxf(m, pm);
      float corr = __expf(m - mn);
      m = mn;
      ls *= corr;
#pragma unroll
      for (int r = 0; r < 16; r++) { o0[r] *= corr; o1[r] *= corr; }
    }
    float ssum = 0.0f;
#pragma unroll
    for (int r = 0; r < 16; r++) {
      st0[r] = __expf(st0[r] - m);
      st1[r] = __expf(st1[r] - m);
      ssum += st0[r] + st1[r];
    }
    ssum += __shfl_xor(ssum, 32);
    ls += ssum;

    u32x4 pb[4];
#pragma unroll
    for (int half = 0; half < 2; half++) {
      const f32x16& st = half ? st1 : st0;
      uint cA0 = pk2(st[0], st[1]),  cA1 = pk2(st[2], st[3]);
      uint cB0 = pk2(st[4], st[5]),  cB1 = pk2(st[6], st[7]);
      uint cC0 = pk2(st[8], st[9]),  cC1 = pk2(st[10], st[11]);
      uint cD0 = pk2(st[12], st[13]), cD1 = pk2(st[14], st[15]);
      uint xA0 = __shfl_xor(cA0, 32), xA1 = __shfl_xor(cA1, 32);
      uint xB0 = __shfl_xor(cB0, 32), xB1 = __shfl_xor(cB1, 32);
      uint xC0 = __shfl_xor(cC0, 32), xC1 = __shfl_xor(cC1, 32);
      uint xD0 = __shfl_xor(cD0, 32), xD1 = __shfl_xor(cD1, 32);
      u32x4 lo, hi4;
      lo[0] = cA0; lo[1] = cA1; lo[2] = xA0; lo[3] = xA1;
      hi4[0] = xB0; hi4[1] = xB1; hi4[2] = cB0; hi4[3] = cB1;
      pb[half * 2] = hi ? hi4 : lo;
      u32x4 lo2, hi2;
      lo2[0] = cC0; lo2[1] = cC1; lo2[2] = xC0; lo2[3] = xC1;
      hi2[0] = xD0; hi2[1] = xD1; hi2[2] = cD0; hi2[3] = cD1;
      pb[half * 2 + 1] = hi ? hi2 : lo2;
    }
    __builtin_amdgcn_s_setprio(1);
#pragma unroll
    for (int ks = 0; ks < 4; ks++) {
      int sl = ((ks * 2 + hi) ^ ksw) << 4;
      bf16x8 v0 = *(const bf16x8*)(Vb + l31 * 128 + sl);
      bf16x8 v1 = *(const bf16x8*)(Vb + (32 + l31) * 128 + sl);
      bf16x8 pbb = *reinterpret_cast<const bf16x8*>(&pb[ks]);
      o0 = MFMA32(v0, pbb, o0);
      o1 = MFMA32(v1, pbb, o1);
    }
    __builtin_amdgcn_s_setprio(0);
    __builtin_amdgcn_s_barrier();
  }

  float inv = 1.0f / ls;
  ushort* Op = attnout + ((size_t)b * S_LEN + qa) * DM + h * HD;
#pragma unroll
  for (int g4 = 0; g4 < 4; g4++) {
    ushort4v w0, w1;
#pragma unroll
    for (int jj = 0; jj < 4; jj++) {
      w0[jj] = f2b(o0[4 * g4 + jj] * inv);
      w1[jj] = f2b(o1[4 * g4 + jj] * inv);
    }
    *reinterpret_cast<ushort4v*>(Op + 8 * g4 + 4 * hi) = w0;
    *reinterpret_cast<ushort4v*>(Op + 32 + 8 * g4 + 4 * hi) = w1;
  }
}

// ----------------------------------------------------------------
extern "C" void kernel_launch(void* const* d_in, const int* in_sizes, int n_in,
                              void* d_out, int out_size, void* d_ws, size_t ws_size,
                              hipStream_t stream) {
  const float* x   = (const float*)d_in[0];
  const float* Wqa = (const float*)d_in[1];
  const float* Wka = (const float*)d_in[2];
  const float* Wqp = (const float*)d_in[3];
  const float* Wkp = (const float*)d_in[4];
  const float* Wv  = (const float*)d_in[5];
  const float* Wo  = (const float*)d_in[6];
  const float* sls = (const float*)d_in[7];

  char* ws = (char*)d_ws;
  ushort* x_bf = (ushort*)ws; ws += (size_t)NTOK * DM * 2;
  ushort* w_bf[6];
  for (int i = 0; i < 6; i++) { w_bf[i] = (ushort*)ws; ws += (size_t)DM * DM * 2; }
  ushort* v_bf = (ushort*)ws; ws += (size_t)NTOK * DM * 2;
  ushort* qext = (ushort*)ws; ws += (size_t)NBH * S_LEN * 128 * 2;
  ushort* kext = (ushort*)ws; ws += (size_t)NBH * S_LEN * 128 * 2;
  ushort* vT   = (ushort*)ws; ws += (size_t)NBH * HD * S_LEN * 2;
  ushort* attn = (ushort*)ws; ws += (size_t)NTOK * DM * 2;

  // 1. fp32 -> bf16 conversions (x + 6 weights)
  CvtArgs ca;
  ca.src[0] = x; ca.dst[0] = x_bf; ca.n[0] = NTOK * DM;
  const float* wsrc[6] = {Wqa, Wka, Wqp, Wkp, Wv, Wo};
  for (int i = 0; i < 6; i++) { ca.src[i + 1] = wsrc[i]; ca.dst[i + 1] = w_bf[i]; ca.n[i + 1] = DM * DM; }
  dim3 cg((NTOK * DM / 8 + 255) / 256, 7);
  hipLaunchKernelGGL(cvt_kernel, cg, dim3(256), 0, stream, ca);

  // 2. fused projections: z=0 q (amp+phi+RMS+sincos), z=1 k, z=2 v
  dim3 gq(DM / 128, NTOK / 128, 3);
  hipLaunchKernelGGL(qkproj_kernel, gq, dim3(256), 0, stream,
                     x_bf, w_bf[0], w_bf[2], w_bf[1], w_bf[3], w_bf[4], sls,
                     qext, kext, v_bf);

  // 3. V transpose
  hipLaunchKernelGGL(vt_kernel, dim3(S_LEN / 64, NBH), dim3(256), 0, stream, v_bf, vT);

  // 4. causal flash attention (128-row blocks, LDS-staged K/V, 2-phase pipeline)
  hipLaunchKernelGGL(attn_kernel, dim3(512), dim3(256), 0, stream,
                     qext, kext, vT, attn);

  // 5. output projection -> fp32 d_out
  dim3 gg(DM / 128, NTOK / 128);
  hipLaunchKernelGGL(gemm_bt, gg, dim3(256), 0, stream, attn, w_bf[5], (float*)d_out,
                     NTOK, DM, DM);
}

// Round 9
// 164.329 us; speedup vs baseline: 4.0451x; 1.0212x over previous
//
#include <hip/hip_runtime.h>
#include <hip/hip_bf16.h>
#include <math.h>

// Problem constants (fixed shapes from setup_inputs)
#define S_LEN 2048
#define NH 16
#define HD 64
#define DM 1024
#define NTOK 4096   // B*S
#define NBH 32      // B*NH

typedef __attribute__((ext_vector_type(8))) __bf16 bf16x8;
typedef __attribute__((ext_vector_type(8))) ushort ushort8;
typedef __attribute__((ext_vector_type(4))) ushort ushort4v;
typedef __attribute__((ext_vector_type(4))) float f32x4;
typedef __attribute__((ext_vector_type(16))) float f32x16;
typedef __attribute__((ext_vector_type(4))) uint u32x4;

__device__ __forceinline__ ushort f2b(float x) {
  __hip_bfloat16 h = __float2bfloat16(x);
  return *reinterpret_cast<ushort*>(&h);
}

__device__ __forceinline__ uint pk2(float lo, float hi) {
  return (uint)f2b(lo) | ((uint)f2b(hi) << 16);
}

__device__ __forceinline__ void gload16b(const void* g, void* l) {
  __builtin_amdgcn_global_load_lds((const __attribute__((address_space(1))) void*)g,
                                   (__attribute__((address_space(3))) void*)l, 16, 0, 0);
}

#define MFMA16(a, b, c) __builtin_amdgcn_mfma_f32_16x16x32_bf16((a), (b), (c), 0, 0, 0)
#define MFMA32(a, b, c) __builtin_amdgcn_mfma_f32_32x32x16_bf16((a), (b), (c), 0, 0, 0)

// ---------------------------------------------------------------- convert fp32 -> bf16
struct CvtArgs {
  const float* src[7];
  ushort* dst[7];
  int n[7];
};

__global__ void cvt_kernel(CvtArgs a) {
  int arr = blockIdx.y;
  long i = ((long)blockIdx.x * blockDim.x + threadIdx.x) * 8;
  if (i >= a.n[arr]) return;
  const float* s = a.src[arr];
  ushort* d = a.dst[arr];
  float4 v0 = *reinterpret_cast<const float4*>(s + i);
  float4 v1 = *reinterpret_cast<const float4*>(s + i + 4);
  ushort8 r;
  r[0] = f2b(v0.x); r[1] = f2b(v0.y); r[2] = f2b(v0.z); r[3] = f2b(v0.w);
  r[4] = f2b(v1.x); r[5] = f2b(v1.y); r[6] = f2b(v1.z); r[7] = f2b(v1.w);
  *reinterpret_cast<ushort8*>(d + i) = r;
}

// ---------------------------------------------------------------- fused QK/V projection
// Flat 1-D grid of 768 blocks, backfill-ordered: u<512 -> dual GEMM (z=0 q / z=1 k:
// amp + phi products, fused softplus+RMS+pi*tanh+sincos epilogue -> q/k ext);
// u>=512 -> V GEMM whose epilogue writes vT[B,H,64,S] DIRECTLY (vt kernel eliminated:
// lane's 4 r-regs are 4 consecutive tokens at fixed head-dim = contiguous ushort4 in vT).
__global__ __launch_bounds__(256, 2) void qkproj_kernel(
    const ushort* __restrict__ A,
    const ushort* __restrict__ Wqa, const ushort* __restrict__ Wqp,
    const ushort* __restrict__ Wka, const ushort* __restrict__ Wkp,
    const ushort* __restrict__ Wv, const float* __restrict__ sls,
    ushort* __restrict__ qext, ushort* __restrict__ kext, ushort* __restrict__ vT) {
  __shared__ __align__(16) ushort Alds[2][4096];
  __shared__ __align__(16) ushort B0lds[2][4096];
  __shared__ __align__(16) ushort B1lds[2][4096];
  const int u = blockIdx.x;
  int z, bx, by;
  if (u < 512) { z = u >> 8; int v = u & 255; bx = v & 7; by = v >> 3; }
  else         { z = 2;      int v = u - 512; bx = v & 7; by = v >> 3; }
  const int t = threadIdx.x;
  const int lane = t & 63;
  const int wave = t >> 6;
  const int wm = wave >> 1, wn = wave & 1;
  const int l15 = lane & 15, g = lane >> 4;
  const int mbase = by * 128, nbase = bx * 128;
  const int K = DM;
  const int srow = t >> 2, scol = (t & 3) * 8;
  const ushort* Ag = A + (size_t)(mbase + srow) * K + scol;
  const ushort* Wa = (z == 0) ? Wqa : (z == 1) ? Wka : Wv;
  const ushort* Wp = (z == 0) ? Wqp : Wkp;  // unused for z==2
  const ushort* Wag = Wa + (size_t)(nbase + srow) * K + scol;
  const ushort* Wpg = (z < 2) ? (Wp + (size_t)(nbase + srow) * K + scol) : Wag;

  const int nk = K / 32;
  f32x4 accA[4][4] = {};

  if (z < 2) {
    // ---------------- dual GEMM ----------------
    f32x4 accP[4][4] = {};
    auto stage = [&](int buf, int kt) {
      gload16b(Ag + kt, &Alds[buf][t * 8]);
      gload16b(Ag + kt + (size_t)64 * K, &Alds[buf][t * 8 + 64 * 32]);
      gload16b(Wag + kt, &B0lds[buf][t * 8]);
      gload16b(Wag + kt + (size_t)64 * K, &B0lds[buf][t * 8 + 64 * 32]);
      gload16b(Wpg + kt, &B1lds[buf][t * 8]);
      gload16b(Wpg + kt + (size_t)64 * K, &B1lds[buf][t * 8 + 64 * 32]);
    };
    stage(0, 0);
    for (int kt = 0; kt < nk; ++kt) {
      const int cur = kt & 1;
      if (kt + 1 < nk) {
        stage(cur ^ 1, (kt + 1) * 32);
        asm volatile("s_waitcnt vmcnt(6)" ::: "memory");
      } else {
        asm volatile("s_waitcnt vmcnt(0)" ::: "memory");
      }
      __builtin_amdgcn_s_barrier();
      bf16x8 af[4], ba[4], bp[4];
#pragma unroll
      for (int i = 0; i < 4; i++)
        af[i] = *reinterpret_cast<const bf16x8*>(&Alds[cur][(wm * 64 + i * 16 + l15) * 32 + g * 8]);
#pragma unroll
      for (int j = 0; j < 4; j++) {
        ba[j] = *reinterpret_cast<const bf16x8*>(&B0lds[cur][(wn * 64 + j * 16 + l15) * 32 + g * 8]);
        bp[j] = *reinterpret_cast<const bf16x8*>(&B1lds[cur][(wn * 64 + j * 16 + l15) * 32 + g * 8]);
      }
      __builtin_amdgcn_s_setprio(1);
#pragma unroll
      for (int i = 0; i < 4; i++)
#pragma unroll
        for (int j = 0; j < 4; j++) {
          accA[i][j] = MFMA16(af[i], ba[j], accA[i][j]);
          accP[i][j] = MFMA16(af[i], bp[j], accP[i][j]);
        }
      __builtin_amdgcn_s_setprio(0);
      __builtin_amdgcn_s_barrier();
    }
    // ---------------- fused epilogue: softplus + RMS + pi*tanh -> sincos ----------------
    const int row0 = mbase + wm * 64;
    const int h = (nbase >> 6) + wn;              // head index
    const float scale = (z == 0) ? __expf(sls[h]) * 0.125f : 1.0f;
    ushort* ext = (z == 0) ? qext : kext;
#pragma unroll
    for (int i = 0; i < 4; i++) {
#pragma unroll
      for (int r = 0; r < 4; r++) {
        float sp[4];
        float ss = 0.0f;
#pragma unroll
        for (int j = 0; j < 4; j++) {
          float v = accA[i][j][r];
          sp[j] = fmaxf(v, 0.0f) + __logf(1.0f + __expf(-fabsf(v)));
          ss += sp[j] * sp[j];
        }
        ss += __shfl_xor(ss, 1);
        ss += __shfl_xor(ss, 2);
        ss += __shfl_xor(ss, 4);
        ss += __shfl_xor(ss, 8);
        float rn = rsqrtf(ss * (1.0f / 64.0f) + 1e-6f) * scale;
        const int token = row0 + i * 16 + g * 4 + r;
        const int bb = token >> 11, sidx = token & 2047;
        ushort* base = ext + (((size_t)(bb * NH + h) * S_LEN + sidx) << 7);
#pragma unroll
        for (int j = 0; j < 4; j++) {
          float e = __expf(2.0f * accP[i][j][r]);
          float th = 1.0f - 2.0f * __builtin_amdgcn_rcpf(e + 1.0f);
          float phi = 3.14159265358979f * th;
          float sn = __sinf(phi), cs = __cosf(phi);
          float a = sp[j] * rn;
          int d = j * 16 + l15;
          base[d] = f2b(a * cs);
          base[64 + d] = f2b(a * sn);
        }
      }
    }
  } else {
    // ---------------- V GEMM -> vT[B,H,64,S] directly ----------------
    auto stage = [&](int buf, int kt) {
      gload16b(Ag + kt, &Alds[buf][t * 8]);
      gload16b(Ag + kt + (size_t)64 * K, &Alds[buf][t * 8 + 64 * 32]);
      gload16b(Wag + kt, &B0lds[buf][t * 8]);
      gload16b(Wag + kt + (size_t)64 * K, &B0lds[buf][t * 8 + 64 * 32]);
    };
    stage(0, 0);
    for (int kt = 0; kt < nk; ++kt) {
      const int cur = kt & 1;
      if (kt + 1 < nk) {
        stage(cur ^ 1, (kt + 1) * 32);
        asm volatile("s_waitcnt vmcnt(4)" ::: "memory");
      } else {
        asm volatile("s_waitcnt vmcnt(0)" ::: "memory");
      }
      __builtin_amdgcn_s_barrier();
      bf16x8 af[4], ba[4];
#pragma unroll
      for (int i = 0; i < 4; i++)
        af[i] = *reinterpret_cast<const bf16x8*>(&Alds[cur][(wm * 64 + i * 16 + l15) * 32 + g * 8]);
#pragma unroll
      for (int j = 0; j < 4; j++)
        ba[j] = *reinterpret_cast<const bf16x8*>(&B0lds[cur][(wn * 64 + j * 16 + l15) * 32 + g * 8]);
      __builtin_amdgcn_s_setprio(1);
#pragma unroll
      for (int i = 0; i < 4; i++)
#pragma unroll
        for (int j = 0; j < 4; j++)
          accA[i][j] = MFMA16(af[i], ba[j], accA[i][j]);
      __builtin_amdgcn_s_setprio(0);
      __builtin_amdgcn_s_barrier();
    }
    const int row0 = mbase + wm * 64, col0 = nbase + wn * 64;
#pragma unroll
    for (int i = 0; i < 4; i++)
#pragma unroll
      for (int j = 0; j < 4; j++) {
        int col = col0 + j * 16 + l15;     // global value-dim
        int h = col >> 6, hd = col & 63;
        int t0 = row0 + i * 16 + g * 4;    // 4 consecutive tokens (r=0..3)
        int bb = t0 >> 11, s0 = t0 & 2047;
        ushort4v w;
#pragma unroll
        for (int r = 0; r < 4; r++) w[r] = f2b(accA[i][j][r]);
        *reinterpret_cast<ushort4v*>(
            &vT[(((size_t)(bb * NH + h) * HD + hd) << 11) + s0]) = w;
      }
  }
}

// ---------------------------------------------------------------- GEMM (Wo projection)
__global__ __launch_bounds__(256) void gemm_bt(const ushort* __restrict__ A,
                                               const ushort* __restrict__ W,
                                               float* __restrict__ Cout,
                                               int M, int N, int K) {
  __shared__ __align__(16) ushort Alds[2 * 4096];
  __shared__ __align__(16) ushort Blds[2 * 4096];
  const int t = threadIdx.x;
  const int lane = t & 63;
  const int wave = t >> 6;
  const int wm = wave >> 1, wn = wave & 1;
  const int l15 = lane & 15, g = lane >> 4;
  const int mbase = blockIdx.y * 128, nbase = blockIdx.x * 128;
  const int srow = t >> 2, scol = (t & 3) * 8;
  const ushort* Ag = A + (size_t)(mbase + srow) * K + scol;
  const ushort* Wg = W + (size_t)(nbase + srow) * K + scol;
  auto stage = [&](int buf, int kt) {
    ushort* Al = Alds + buf * 4096 + t * 8;
    ushort* Bl = Blds + buf * 4096 + t * 8;
    gload16b(Ag + kt, Al);
    gload16b(Ag + kt + (size_t)64 * K, Al + 64 * 32);
    gload16b(Wg + kt, Bl);
    gload16b(Wg + kt + (size_t)64 * K, Bl + 64 * 32);
  };
  const int nk = K / 32;
  stage(0, 0);
  f32x4 acc[4][4] = {};
  for (int kt = 0; kt < nk; ++kt) {
    const int cur = kt & 1;
    if (kt + 1 < nk) {
      stage(cur ^ 1, (kt + 1) * 32);
      asm volatile("s_waitcnt vmcnt(4)" ::: "memory");
    } else {
      asm volatile("s_waitcnt vmcnt(0)" ::: "memory");
    }
    __builtin_amdgcn_s_barrier();
    const ushort* Ab = Alds + cur * 4096;
    const ushort* Bb = Blds + cur * 4096;
    bf16x8 af[4], bfr[4];
#pragma unroll
    for (int i = 0; i < 4; i++)
      af[i] = *reinterpret_cast<const bf16x8*>(&Ab[(wm * 64 + i * 16 + l15) * 32 + g * 8]);
#pragma unroll
    for (int j = 0; j < 4; j++)
      bfr[j] = *reinterpret_cast<const bf16x8*>(&Bb[(wn * 64 + j * 16 + l15) * 32 + g * 8]);
    __builtin_amdgcn_s_setprio(1);
#pragma unroll
    for (int i = 0; i < 4; i++)
#pragma unroll
      for (int j = 0; j < 4; j++)
        acc[i][j] = MFMA16(af[i], bfr[j], acc[i][j]);
    __builtin_amdgcn_s_setprio(0);
    __builtin_amdgcn_s_barrier();
  }
  const int row0 = mbase + wm * 64, col0 = nbase + wn * 64;
#pragma unroll
  for (int i = 0; i < 4; i++)
#pragma unroll
    for (int j = 0; j < 4; j++)
#pragma unroll
      for (int r = 0; r < 4; r++) {
        int row = row0 + i * 16 + g * 4 + r;
        int col = col0 + j * 16 + l15;
        Cout[(size_t)row * N + col] = acc[i][j][r];
      }
}

// ---------------------------------------------------------------- causal flash attention
// Block = 128 q-rows (4 waves x 32-row swapped-QK). K/V staged in LDS (global_load_lds,
// XOR-swizzled src), double-buffered, counted vmcnt(6) + raw s_barrier.
__device__ __forceinline__ void stage_kv(const char* Kp, const char* Vp, int kb,
                                         char* buf, int wave, int lane) {
#pragma unroll
  for (int c = 0; c < 4; c++) {
    int i = wave * 4 + c;
    int kvl = i * 4 + (lane >> 4);
    int slot = (lane & 15) ^ (kvl & 7);
    gload16b(Kp + (size_t)(kb + kvl) * 256 + slot * 16, buf + i * 1024);
  }
#pragma unroll
  for (int c = 0; c < 2; c++) {
    int i = wave * 2 + c;
    int hd = i * 8 + (lane >> 3);
    int slot = (lane & 7) ^ (hd & 7);
    gload16b(Vp + (size_t)hd * (S_LEN * 2) + (size_t)kb * 2 + slot * 16,
             buf + 16384 + i * 1024);
  }
}

__global__ __launch_bounds__(256, 2) void attn_kernel(const ushort* __restrict__ qext,
                                                      const ushort* __restrict__ kext,
                                                      const ushort* __restrict__ vT,
                                                      ushort* __restrict__ attnout) {
  __shared__ __align__(16) char lds[2][24576];
  const int u = blockIdx.x;
  const int uh = u >> 8, v = u & 255;
  const int bh = v >> 3, j = v & 7;
  const int qt = uh ? (15 - j) : j;
  const int b = bh >> 4, h = bh & 15;
  const int wave = threadIdx.x >> 6, lane = threadIdx.x & 63;
  const int l31 = lane & 31, hi = lane >> 5;
  const int qb = qt * 128;
  const int qw = qb + wave * 32;
  const int qa = qw + l31;
  const char* Kp = (const char*)(kext + (size_t)bh * S_LEN * 128);
  const char* Vp = (const char*)(vT + (size_t)bh * HD * S_LEN);
  const ushort* Qp = qext + (size_t)bh * S_LEN * 128;
  const int nt = 2 * qt + 2;
  const int ksw = l31 & 7;

  stage_kv(Kp, Vp, 0, lds[0], wave, lane);
  bf16x8 qf[8];
#pragma unroll
  for (int s = 0; s < 8; s++)
    qf[s] = *reinterpret_cast<const bf16x8*>(&Qp[(size_t)qa * 128 + s * 16 + hi * 8]);

  f32x16 o0 = {}, o1 = {};
  float m = -1e30f, ls = 0.0f;

  for (int t = 0; t < nt; ++t) {
    const int cur = t & 1;
    const int kb = t << 6;
    if (t + 1 < nt) {
      stage_kv(Kp, Vp, (t + 1) << 6, lds[cur ^ 1], wave, lane);
      asm volatile("s_waitcnt vmcnt(6)" ::: "memory");
    } else {
      asm volatile("s_waitcnt vmcnt(0)" ::: "memory");
    }
    __builtin_amdgcn_s_barrier();

    const char* Kb = lds[cur];
    const char* Vb = lds[cur] + 16384;

    f32x16 st0 = {}, st1 = {};
    __builtin_amdgcn_s_setprio(1);
#pragma unroll
    for (int s = 0; s < 8; s++) {
      int sl = ((s * 2 + hi) ^ ksw) << 4;
      bf16x8 k0 = *(const bf16x8*)(Kb + l31 * 256 + sl);
      bf16x8 k1 = *(const bf16x8*)(Kb + (32 + l31) * 256 + sl);
      st0 = MFMA32(k0, qf[s], st0);
      st1 = MFMA32(k1, qf[s], st1);
    }
    __builtin_amdgcn_s_setprio(0);

    if (kb + 64 > qw) {
#pragma unroll
      for (int r = 0; r < 16; r++) {
        int kv = kb + (r & 3) + 8 * (r >> 2) + 4 * hi;
        if (kv > qa) st0[r] = -1e30f;
        if (kv + 32 > qa) st1[r] = -1e30f;
      }
    }
    float pm = -1e30f;
#pragma unroll
    for (int r = 0; r < 16; r++) pm = fmaxf(pm, fmaxf(st0[r], st1[r]));
    pm = fmaxf(pm, __shfl_xor(pm, 32));
    if (!__all(pm <= m + 8.0f)) {
      float mn = fmaxf(m, pm);
      float corr = __expf(m - mn);
      m = mn;
      ls *= corr;
#pragma unroll
      for (int r = 0; r < 16; r++) { o0[r] *= corr; o1[r] *= corr; }
    }
    float ssum = 0.0f;
#pragma unroll
    for (int r = 0; r < 16; r++) {
      st0[r] = __expf(st0[r] - m);
      st1[r] = __expf(st1[r] - m);
      ssum += st0[r] + st1[r];
    }
    ssum += __shfl_xor(ssum, 32);
    ls += ssum;

    u32x4 pb[4];
#pragma unroll
    for (int half = 0; half < 2; half++) {
      const f32x16& st = half ? st1 : st0;
      uint cA0 = pk2(st[0], st[1]),  cA1 = pk2(st[2], st[3]);
      uint cB0 = pk2(st[4], st[5]),  cB1 = pk2(st[6], st[7]);
      uint cC0 = pk2(st[8], st[9]),  cC1 = pk2(st[10], st[11]);
      uint cD0 = pk2(st[12], st[13]), cD1 = pk2(st[14], st[15]);
      uint xA0 = __shfl_xor(cA0, 32), xA1 = __shfl_xor(cA1, 32);
      uint xB0 = __shfl_xor(cB0, 32), xB1 = __shfl_xor(cB1, 32);
      uint xC0 = __shfl_xor(cC0, 32), xC1 = __shfl_xor(cC1, 32);
      uint xD0 = __shfl_xor(cD0, 32), xD1 = __shfl_xor(cD1, 32);
      u32x4 lo, hi4;
      lo[0] = cA0; lo[1] = cA1; lo[2] = xA0; lo[3] = xA1;
      hi4[0] = xB0; hi4[1] = xB1; hi4[2] = cB0; hi4[3] = cB1;
      pb[half * 2] = hi ? hi4 : lo;
      u32x4 lo2, hi2;
      lo2[0] = cC0; lo2[1] = cC1; lo2[2] = xC0; lo2[3] = xC1;
      hi2[0] = xD0; hi2[1] = xD1; hi2[2] = cD0; hi2[3] = cD1;
      pb[half * 2 + 1] = hi ? hi2 : lo2;
    }
    __builtin_amdgcn_s_setprio(1);
#pragma unroll
    for (int ks = 0; ks < 4; ks++) {
      int sl = ((ks * 2 + hi) ^ ksw) << 4;
      bf16x8 v0 = *(const bf16x8*)(Vb + l31 * 128 + sl);
      bf16x8 v1 = *(const bf16x8*)(Vb + (32 + l31) * 128 + sl);
      bf16x8 pbb = *reinterpret_cast<const bf16x8*>(&pb[ks]);
      o0 = MFMA32(v0, pbb, o0);
      o1 = MFMA32(v1, pbb, o1);
    }
    __builtin_amdgcn_s_setprio(0);
    __builtin_amdgcn_s_barrier();
  }

  float inv = 1.0f / ls;
  ushort* Op = attnout + ((size_t)b * S_LEN + qa) * DM + h * HD;
#pragma unroll
  for (int g4 = 0; g4 < 4; g4++) {
    ushort4v w0, w1;
#pragma unroll
    for (int jj = 0; jj < 4; jj++) {
      w0[jj] = f2b(o0[4 * g4 + jj] * inv);
      w1[jj] = f2b(o1[4 * g4 + jj] * inv);
    }
    *reinterpret_cast<ushort4v*>(Op + 8 * g4 + 4 * hi) = w0;
    *reinterpret_cast<ushort4v*>(Op + 32 + 8 * g4 + 4 * hi) = w1;
  }
}

// ----------------------------------------------------------------
extern "C" void kernel_launch(void* const* d_in, const int* in_sizes, int n_in,
                              void* d_out, int out_size, void* d_ws, size_t ws_size,
                              hipStream_t stream) {
  const float* x   = (const float*)d_in[0];
  const float* Wqa = (const float*)d_in[1];
  const float* Wka = (const float*)d_in[2];
  const float* Wqp = (const float*)d_in[3];
  const float* Wkp = (const float*)d_in[4];
  const float* Wv  = (const float*)d_in[5];
  const float* Wo  = (const float*)d_in[6];
  const float* sls = (const float*)d_in[7];

  char* ws = (char*)d_ws;
  ushort* x_bf = (ushort*)ws; ws += (size_t)NTOK * DM * 2;
  ushort* w_bf[6];
  for (int i = 0; i < 6; i++) { w_bf[i] = (ushort*)ws; ws += (size_t)DM * DM * 2; }
  ushort* qext = (ushort*)ws; ws += (size_t)NBH * S_LEN * 128 * 2;
  ushort* kext = (ushort*)ws; ws += (size_t)NBH * S_LEN * 128 * 2;
  ushort* vT   = (ushort*)ws; ws += (size_t)NBH * HD * S_LEN * 2;
  ushort* attn = (ushort*)ws; ws += (size_t)NTOK * DM * 2;

  // 1. fp32 -> bf16 conversions (x + 6 weights)
  CvtArgs ca;
  ca.src[0] = x; ca.dst[0] = x_bf; ca.n[0] = NTOK * DM;
  const float* wsrc[6] = {Wqa, Wka, Wqp, Wkp, Wv, Wo};
  for (int i = 0; i < 6; i++) { ca.src[i + 1] = wsrc[i]; ca.dst[i + 1] = w_bf[i]; ca.n[i + 1] = DM * DM; }
  dim3 cg((NTOK * DM / 8 + 255) / 256, 7);
  hipLaunchKernelGGL(cvt_kernel, cg, dim3(256), 0, stream, ca);

  // 2. fused projections, backfill-ordered flat grid:
  //    blocks [0,512): q/k dual GEMM + activation epilogue; [512,768): V GEMM -> vT
  hipLaunchKernelGGL(qkproj_kernel, dim3(768), dim3(256), 0, stream,
                     x_bf, w_bf[0], w_bf[2], w_bf[1], w_bf[3], w_bf[4], sls,
                     qext, kext, vT);

  // 3. causal flash attention (128-row blocks, LDS-staged K/V, 2-phase pipeline)
  hipLaunchKernelGGL(attn_kernel, dim3(512), dim3(256), 0, stream,
                     qext, kext, vT, attn);

  // 4. output projection -> fp32 d_out
  dim3 gg(DM / 128, NTOK / 128);
  hipLaunchKernelGGL(gemm_bt, gg, dim3(256), 0, stream, attn, w_bf[5], (float*)d_out,
                     NTOK, DM, DM);
}

// Round 10
// 157.684 us; speedup vs baseline: 4.2156x; 1.0421x over previous
//
#include <hip/hip_runtime.h>
#include <hip/hip_bf16.h>
#include <math.h>

// Problem constants (fixed shapes from setup_inputs)
#define S_LEN 2048
#define NH 16
#define HD 64
#define DM 1024
#define NTOK 4096   // B*S
#define NBH 32      // B*NH

typedef __attribute__((ext_vector_type(8))) __bf16 bf16x8;
typedef __attribute__((ext_vector_type(8))) ushort ushort8;
typedef __attribute__((ext_vector_type(4))) ushort ushort4v;
typedef __attribute__((ext_vector_type(4))) float f32x4;
typedef __attribute__((ext_vector_type(16))) float f32x16;
typedef __attribute__((ext_vector_type(4))) uint u32x4;

__device__ __forceinline__ ushort f2b(float x) {
  __hip_bfloat16 h = __float2bfloat16(x);
  return *reinterpret_cast<ushort*>(&h);
}

__device__ __forceinline__ uint pk2(float lo, float hi) {
  return (uint)f2b(lo) | ((uint)f2b(hi) << 16);
}

__device__ __forceinline__ void gload16b(const void* g, void* l) {
  __builtin_amdgcn_global_load_lds((const __attribute__((address_space(1))) void*)g,
                                   (__attribute__((address_space(3))) void*)l, 16, 0, 0);
}

#define MFMA16(a, b, c) __builtin_amdgcn_mfma_f32_16x16x32_bf16((a), (b), (c), 0, 0, 0)
#define MFMA32(a, b, c) __builtin_amdgcn_mfma_f32_32x32x16_bf16((a), (b), (c), 0, 0, 0)

// ---------------------------------------------------------------- convert fp32 -> bf16
struct CvtArgs {
  const float* src[7];
  ushort* dst[7];
  int n[7];
};

__global__ void cvt_kernel(CvtArgs a) {
  int arr = blockIdx.y;
  long i = ((long)blockIdx.x * blockDim.x + threadIdx.x) * 8;
  if (i >= a.n[arr]) return;
  const float* s = a.src[arr];
  ushort* d = a.dst[arr];
  float4 v0 = *reinterpret_cast<const float4*>(s + i);
  float4 v1 = *reinterpret_cast<const float4*>(s + i + 4);
  ushort8 r;
  r[0] = f2b(v0.x); r[1] = f2b(v0.y); r[2] = f2b(v0.z); r[3] = f2b(v0.w);
  r[4] = f2b(v1.x); r[5] = f2b(v1.y); r[6] = f2b(v1.z); r[7] = f2b(v1.w);
  *reinterpret_cast<ushort8*>(d + i) = r;
}

// ---------------------------------------------------------------- fused QK/V projection
// XCD-swizzled flat grid of 768 blocks: each XCD gets 64 dual-blocks (contiguous
// A-panels) + 32 V-blocks -> A stays L2-local, work balanced.
// LDS tiles [128][32] bf16 (64B rows): 16B slot s of row r holds GLOBAL slot
// s ^ ((r>>1)&3) (inverse-swizzled source, linear global_load_lds dest); frag reads
// use slot g ^ ((l15>>1)&3) -> bank-starts {0,16,4,20,8,24,12,28}: conflict-free.
__global__ __launch_bounds__(256, 2) void qkproj_kernel(
    const ushort* __restrict__ A,
    const ushort* __restrict__ Wqa, const ushort* __restrict__ Wqp,
    const ushort* __restrict__ Wka, const ushort* __restrict__ Wkp,
    const ushort* __restrict__ Wv, const float* __restrict__ sls,
    ushort* __restrict__ qext, ushort* __restrict__ kext, ushort* __restrict__ vT) {
  __shared__ __align__(16) ushort Alds[2][4096];
  __shared__ __align__(16) ushort B0lds[2][4096];
  __shared__ __align__(16) ushort B1lds[2][4096];
  // XCD-balanced bijective swizzle: xcd x gets duals [64x,64x+64) + Vs [512+32x, +32)
  const int d = blockIdx.x;
  const int xc = d & 7, c = d >> 3;  // c in 0..95
  const int u = (c < 64) ? (xc * 64 + c) : (512 + xc * 32 + (c - 64));
  int z, bx, by;
  if (u < 512) { z = u >> 8; int v = u & 255; bx = v & 7; by = v >> 3; }
  else         { z = 2;      int v = u - 512; bx = v & 7; by = v >> 3; }
  const int t = threadIdx.x;
  const int lane = t & 63;
  const int wave = t >> 6;
  const int wm = wave >> 1, wn = wave & 1;
  const int l15 = lane & 15, g = lane >> 4;
  const int mbase = by * 128, nbase = bx * 128;
  const int K = DM;
  const int srow = t >> 2;
  // inverse-swizzled source column: LDS slot (t&3) of row srow holds global slot
  // (t&3)^sx; rows srow and srow+64 share sx since 64>>1 == 0 (mod 4)
  const int sx = (srow >> 1) & 3;
  const int scol = (((t & 3) ^ sx)) * 8;
  const int xr = (l15 >> 1) & 3;  // read-side swizzle (row = 16*m + l15 -> (row>>1)&3)
  const ushort* Ag = A + (size_t)(mbase + srow) * K + scol;
  const ushort* Wa = (z == 0) ? Wqa : (z == 1) ? Wka : Wv;
  const ushort* Wp = (z == 0) ? Wqp : Wkp;  // unused for z==2
  const ushort* Wag = Wa + (size_t)(nbase + srow) * K + scol;
  const ushort* Wpg = (z < 2) ? (Wp + (size_t)(nbase + srow) * K + scol) : Wag;

  const int nk = K / 32;
  f32x4 accA[4][4] = {};

  if (z < 2) {
    // ---------------- dual GEMM ----------------
    f32x4 accP[4][4] = {};
    auto stage = [&](int buf, int kt) {
      gload16b(Ag + kt, &Alds[buf][t * 8]);
      gload16b(Ag + kt + (size_t)64 * K, &Alds[buf][t * 8 + 64 * 32]);
      gload16b(Wag + kt, &B0lds[buf][t * 8]);
      gload16b(Wag + kt + (size_t)64 * K, &B0lds[buf][t * 8 + 64 * 32]);
      gload16b(Wpg + kt, &B1lds[buf][t * 8]);
      gload16b(Wpg + kt + (size_t)64 * K, &B1lds[buf][t * 8 + 64 * 32]);
    };
    stage(0, 0);
    for (int kt = 0; kt < nk; ++kt) {
      const int cur = kt & 1;
      if (kt + 1 < nk) {
        stage(cur ^ 1, (kt + 1) * 32);
        asm volatile("s_waitcnt vmcnt(6)" ::: "memory");
      } else {
        asm volatile("s_waitcnt vmcnt(0)" ::: "memory");
      }
      __builtin_amdgcn_s_barrier();
      bf16x8 af[4], ba[4], bp[4];
#pragma unroll
      for (int i = 0; i < 4; i++)
        af[i] = *reinterpret_cast<const bf16x8*>(
            &Alds[cur][(wm * 64 + i * 16 + l15) * 32 + (g ^ xr) * 8]);
#pragma unroll
      for (int j = 0; j < 4; j++) {
        ba[j] = *reinterpret_cast<const bf16x8*>(
            &B0lds[cur][(wn * 64 + j * 16 + l15) * 32 + (g ^ xr) * 8]);
        bp[j] = *reinterpret_cast<const bf16x8*>(
            &B1lds[cur][(wn * 64 + j * 16 + l15) * 32 + (g ^ xr) * 8]);
      }
      __builtin_amdgcn_s_setprio(1);
#pragma unroll
      for (int i = 0; i < 4; i++)
#pragma unroll
        for (int j = 0; j < 4; j++) {
          accA[i][j] = MFMA16(af[i], ba[j], accA[i][j]);
          accP[i][j] = MFMA16(af[i], bp[j], accP[i][j]);
        }
      __builtin_amdgcn_s_setprio(0);
      __builtin_amdgcn_s_barrier();
    }
    // ---------------- fused epilogue: softplus + RMS + pi*tanh -> sincos ----------------
    const int row0 = mbase + wm * 64;
    const int h = (nbase >> 6) + wn;              // head index
    const float scale = (z == 0) ? __expf(sls[h]) * 0.125f : 1.0f;
    ushort* ext = (z == 0) ? qext : kext;
#pragma unroll
    for (int i = 0; i < 4; i++) {
#pragma unroll
      for (int r = 0; r < 4; r++) {
        float sp[4];
        float ss = 0.0f;
#pragma unroll
        for (int j = 0; j < 4; j++) {
          float v = accA[i][j][r];
          sp[j] = fmaxf(v, 0.0f) + __logf(1.0f + __expf(-fabsf(v)));
          ss += sp[j] * sp[j];
        }
        ss += __shfl_xor(ss, 1);
        ss += __shfl_xor(ss, 2);
        ss += __shfl_xor(ss, 4);
        ss += __shfl_xor(ss, 8);
        float rn = rsqrtf(ss * (1.0f / 64.0f) + 1e-6f) * scale;
        const int token = row0 + i * 16 + g * 4 + r;
        const int bb = token >> 11, sidx = token & 2047;
        ushort* base = ext + (((size_t)(bb * NH + h) * S_LEN + sidx) << 7);
#pragma unroll
        for (int j = 0; j < 4; j++) {
          float e = __expf(2.0f * accP[i][j][r]);
          float th = 1.0f - 2.0f * __builtin_amdgcn_rcpf(e + 1.0f);
          float phi = 3.14159265358979f * th;
          float sn = __sinf(phi), cs = __cosf(phi);
          float a = sp[j] * rn;
          int dd = j * 16 + l15;
          base[dd] = f2b(a * cs);
          base[64 + dd] = f2b(a * sn);
        }
      }
    }
  } else {
    // ---------------- V GEMM -> vT[B,H,64,S] directly ----------------
    auto stage = [&](int buf, int kt) {
      gload16b(Ag + kt, &Alds[buf][t * 8]);
      gload16b(Ag + kt + (size_t)64 * K, &Alds[buf][t * 8 + 64 * 32]);
      gload16b(Wag + kt, &B0lds[buf][t * 8]);
      gload16b(Wag + kt + (size_t)64 * K, &B0lds[buf][t * 8 + 64 * 32]);
    };
    stage(0, 0);
    for (int kt = 0; kt < nk; ++kt) {
      const int cur = kt & 1;
      if (kt + 1 < nk) {
        stage(cur ^ 1, (kt + 1) * 32);
        asm volatile("s_waitcnt vmcnt(4)" ::: "memory");
      } else {
        asm volatile("s_waitcnt vmcnt(0)" ::: "memory");
      }
      __builtin_amdgcn_s_barrier();
      bf16x8 af[4], ba[4];
#pragma unroll
      for (int i = 0; i < 4; i++)
        af[i] = *reinterpret_cast<const bf16x8*>(
            &Alds[cur][(wm * 64 + i * 16 + l15) * 32 + (g ^ xr) * 8]);
#pragma unroll
      for (int j = 0; j < 4; j++)
        ba[j] = *reinterpret_cast<const bf16x8*>(
            &B0lds[cur][(wn * 64 + j * 16 + l15) * 32 + (g ^ xr) * 8]);
      __builtin_amdgcn_s_setprio(1);
#pragma unroll
      for (int i = 0; i < 4; i++)
#pragma unroll
        for (int j = 0; j < 4; j++)
          accA[i][j] = MFMA16(af[i], ba[j], accA[i][j]);
      __builtin_amdgcn_s_setprio(0);
      __builtin_amdgcn_s_barrier();
    }
    const int row0 = mbase + wm * 64, col0 = nbase + wn * 64;
#pragma unroll
    for (int i = 0; i < 4; i++)
#pragma unroll
      for (int j = 0; j < 4; j++) {
        int col = col0 + j * 16 + l15;     // global value-dim
        int h = col >> 6, hd = col & 63;
        int t0 = row0 + i * 16 + g * 4;    // 4 consecutive tokens (r=0..3)
        int bb = t0 >> 11, s0 = t0 & 2047;
        ushort4v w;
#pragma unroll
        for (int r = 0; r < 4; r++) w[r] = f2b(accA[i][j][r]);
        *reinterpret_cast<ushort4v*>(
            &vT[(((size_t)(bb * NH + h) * HD + hd) << 11) + s0]) = w;
      }
  }
}

// ---------------------------------------------------------------- GEMM (Wo projection)
// Flat 256-block grid, XCD swizzle (A-panels XCD-local), swizzled LDS slots.
__global__ __launch_bounds__(256) void gemm_bt(const ushort* __restrict__ A,
                                               const ushort* __restrict__ W,
                                               float* __restrict__ Cout,
                                               int M, int N, int K) {
  __shared__ __align__(16) ushort Alds[2 * 4096];
  __shared__ __align__(16) ushort Blds[2 * 4096];
  const int d = blockIdx.x;
  const int u = (d & 7) * 32 + (d >> 3);   // 256 = 8*32, bijective
  const int bx = u & 7, by = u >> 3;
  const int t = threadIdx.x;
  const int lane = t & 63;
  const int wave = t >> 6;
  const int wm = wave >> 1, wn = wave & 1;
  const int l15 = lane & 15, g = lane >> 4;
  const int mbase = by * 128, nbase = bx * 128;
  const int srow = t >> 2;
  const int sx = (srow >> 1) & 3;
  const int scol = (((t & 3) ^ sx)) * 8;
  const int xr = (l15 >> 1) & 3;
  const ushort* Ag = A + (size_t)(mbase + srow) * K + scol;
  const ushort* Wg = W + (size_t)(nbase + srow) * K + scol;
  auto stage = [&](int buf, int kt) {
    ushort* Al = Alds + buf * 4096 + t * 8;
    ushort* Bl = Blds + buf * 4096 + t * 8;
    gload16b(Ag + kt, Al);
    gload16b(Ag + kt + (size_t)64 * K, Al + 64 * 32);
    gload16b(Wg + kt, Bl);
    gload16b(Wg + kt + (size_t)64 * K, Bl + 64 * 32);
  };
  const int nk = K / 32;
  stage(0, 0);
  f32x4 acc[4][4] = {};
  for (int kt = 0; kt < nk; ++kt) {
    const int cur = kt & 1;
    if (kt + 1 < nk) {
      stage(cur ^ 1, (kt + 1) * 32);
      asm volatile("s_waitcnt vmcnt(4)" ::: "memory");
    } else {
      asm volatile("s_waitcnt vmcnt(0)" ::: "memory");
    }
    __builtin_amdgcn_s_barrier();
    const ushort* Ab = Alds + cur * 4096;
    const ushort* Bb = Blds + cur * 4096;
    bf16x8 af[4], bfr[4];
#pragma unroll
    for (int i = 0; i < 4; i++)
      af[i] = *reinterpret_cast<const bf16x8*>(
          &Ab[(wm * 64 + i * 16 + l15) * 32 + (g ^ xr) * 8]);
#pragma unroll
    for (int j = 0; j < 4; j++)
      bfr[j] = *reinterpret_cast<const bf16x8*>(
          &Bb[(wn * 64 + j * 16 + l15) * 32 + (g ^ xr) * 8]);
    __builtin_amdgcn_s_setprio(1);
#pragma unroll
    for (int i = 0; i < 4; i++)
#pragma unroll
      for (int j = 0; j < 4; j++)
        acc[i][j] = MFMA16(af[i], bfr[j], acc[i][j]);
    __builtin_amdgcn_s_setprio(0);
    __builtin_amdgcn_s_barrier();
  }
  const int row0 = mbase + wm * 64, col0 = nbase + wn * 64;
#pragma unroll
  for (int i = 0; i < 4; i++)
#pragma unroll
    for (int j = 0; j < 4; j++)
#pragma unroll
      for (int r = 0; r < 4; r++) {
        int row = row0 + i * 16 + g * 4 + r;
        int col = col0 + j * 16 + l15;
        Cout[(size_t)row * N + col] = acc[i][j][r];
      }
}

// ---------------------------------------------------------------- causal flash attention
// Block = 128 q-rows (4 waves x 32-row swapped-QK). K/V staged in LDS (global_load_lds,
// XOR-swizzled src), double-buffered, counted vmcnt(6) + raw s_barrier.
__device__ __forceinline__ void stage_kv(const char* Kp, const char* Vp, int kb,
                                         char* buf, int wave, int lane) {
#pragma unroll
  for (int c = 0; c < 4; c++) {
    int i = wave * 4 + c;
    int kvl = i * 4 + (lane >> 4);
    int slot = (lane & 15) ^ (kvl & 7);
    gload16b(Kp + (size_t)(kb + kvl) * 256 + slot * 16, buf + i * 1024);
  }
#pragma unroll
  for (int c = 0; c < 2; c++) {
    int i = wave * 2 + c;
    int hd = i * 8 + (lane >> 3);
    int slot = (lane & 7) ^ (hd & 7);
    gload16b(Vp + (size_t)hd * (S_LEN * 2) + (size_t)kb * 2 + slot * 16,
             buf + 16384 + i * 1024);
  }
}

__global__ __launch_bounds__(256, 2) void attn_kernel(const ushort* __restrict__ qext,
                                                      const ushort* __restrict__ kext,
                                                      const ushort* __restrict__ vT,
                                                      ushort* __restrict__ attnout) {
  __shared__ __align__(16) char lds[2][24576];
  const int u = blockIdx.x;
  const int uh = u >> 8, v = u & 255;
  const int bh = v >> 3, j = v & 7;
  const int qt = uh ? (15 - j) : j;
  const int b = bh >> 4, h = bh & 15;
  const int wave = threadIdx.x >> 6, lane = threadIdx.x & 63;
  const int l31 = lane & 31, hi = lane >> 5;
  const int qb = qt * 128;
  const int qw = qb + wave * 32;
  const int qa = qw + l31;
  const char* Kp = (const char*)(kext + (size_t)bh * S_LEN * 128);
  const char* Vp = (const char*)(vT + (size_t)bh * HD * S_LEN);
  const ushort* Qp = qext + (size_t)bh * S_LEN * 128;
  const int nt = 2 * qt + 2;
  const int ksw = l31 & 7;

  stage_kv(Kp, Vp, 0, lds[0], wave, lane);
  bf16x8 qf[8];
#pragma unroll
  for (int s = 0; s < 8; s++)
    qf[s] = *reinterpret_cast<const bf16x8*>(&Qp[(size_t)qa * 128 + s * 16 + hi * 8]);

  f32x16 o0 = {}, o1 = {};
  float m = -1e30f, ls = 0.0f;

  for (int t = 0; t < nt; ++t) {
    const int cur = t & 1;
    const int kb = t << 6;
    if (t + 1 < nt) {
      stage_kv(Kp, Vp, (t + 1) << 6, lds[cur ^ 1], wave, lane);
      asm volatile("s_waitcnt vmcnt(6)" ::: "memory");
    } else {
      asm volatile("s_waitcnt vmcnt(0)" ::: "memory");
    }
    __builtin_amdgcn_s_barrier();

    const char* Kb = lds[cur];
    const char* Vb = lds[cur] + 16384;

    f32x16 st0 = {}, st1 = {};
    __builtin_amdgcn_s_setprio(1);
#pragma unroll
    for (int s = 0; s < 8; s++) {
      int sl = ((s * 2 + hi) ^ ksw) << 4;
      bf16x8 k0 = *(const bf16x8*)(Kb + l31 * 256 + sl);
      bf16x8 k1 = *(const bf16x8*)(Kb + (32 + l31) * 256 + sl);
      st0 = MFMA32(k0, qf[s], st0);
      st1 = MFMA32(k1, qf[s], st1);
    }
    __builtin_amdgcn_s_setprio(0);

    if (kb + 64 > qw) {
#pragma unroll
      for (int r = 0; r < 16; r++) {
        int kv = kb + (r & 3) + 8 * (r >> 2) + 4 * hi;
        if (kv > qa) st0[r] = -1e30f;
        if (kv + 32 > qa) st1[r] = -1e30f;
      }
    }
    float pm = -1e30f;
#pragma unroll
    for (int r = 0; r < 16; r++) pm = fmaxf(pm, fmaxf(st0[r], st1[r]));
    pm = fmaxf(pm, __shfl_xor(pm, 32));
    if (!__all(pm <= m + 8.0f)) {
      float mn = fmaxf(m, pm);
      float corr = __expf(m - mn);
      m = mn;
      ls *= corr;
#pragma unroll
      for (int r = 0; r < 16; r++) { o0[r] *= corr; o1[r] *= corr; }
    }
    float ssum = 0.0f;
#pragma unroll
    for (int r = 0; r < 16; r++) {
      st0[r] = __expf(st0[r] - m);
      st1[r] = __expf(st1[r] - m);
      ssum += st0[r] + st1[r];
    }
    ssum += __shfl_xor(ssum, 32);
    ls += ssum;

    u32x4 pb[4];
#pragma unroll
    for (int half = 0; half < 2; half++) {
      const f32x16& st = half ? st1 : st0;
      uint cA0 = pk2(st[0], st[1]),  cA1 = pk2(st[2], st[3]);
      uint cB0 = pk2(st[4], st[5]),  cB1 = pk2(st[6], st[7]);
      uint cC0 = pk2(st[8], st[9]),  cC1 = pk2(st[10], st[11]);
      uint cD0 = pk2(st[12], st[13]), cD1 = pk2(st[14], st[15]);
      uint xA0 = __shfl_xor(cA0, 32), xA1 = __shfl_xor(cA1, 32);
      uint xB0 = __shfl_xor(cB0, 32), xB1 = __shfl_xor(cB1, 32);
      uint xC0 = __shfl_xor(cC0, 32), xC1 = __shfl_xor(cC1, 32);
      uint xD0 = __shfl_xor(cD0, 32), xD1 = __shfl_xor(cD1, 32);
      u32x4 lo, hi4;
      lo[0] = cA0; lo[1] = cA1; lo[2] = xA0; lo[3] = xA1;
      hi4[0] = xB0; hi4[1] = xB1; hi4[2] = cB0; hi4[3] = cB1;
      pb[half * 2] = hi ? hi4 : lo;
      u32x4 lo2, hi2;
      lo2[0] = cC0; lo2[1] = cC1; lo2[2] = xC0; lo2[3] = xC1;
      hi2[0] = xD0; hi2[1] = xD1; hi2[2] = cD0; hi2[3] = cD1;
      pb[half * 2 + 1] = hi ? hi2 : lo2;
    }
    __builtin_amdgcn_s_setprio(1);
#pragma unroll
    for (int ks = 0; ks < 4; ks++) {
      int sl = ((ks * 2 + hi) ^ ksw) << 4;
      bf16x8 v0 = *(const bf16x8*)(Vb + l31 * 128 + sl);
      bf16x8 v1 = *(const bf16x8*)(Vb + (32 + l31) * 128 + sl);
      bf16x8 pbb = *reinterpret_cast<const bf16x8*>(&pb[ks]);
      o0 = MFMA32(v0, pbb, o0);
      o1 = MFMA32(v1, pbb, o1);
    }
    __builtin_amdgcn_s_setprio(0);
    __builtin_amdgcn_s_barrier();
  }

  float inv = 1.0f / ls;
  ushort* Op = attnout + ((size_t)b * S_LEN + qa) * DM + h * HD;
#pragma unroll
  for (int g4 = 0; g4 < 4; g4++) {
    ushort4v w0, w1;
#pragma unroll
    for (int jj = 0; jj < 4; jj++) {
      w0[jj] = f2b(o0[4 * g4 + jj] * inv);
      w1[jj] = f2b(o1[4 * g4 + jj] * inv);
    }
    *reinterpret_cast<ushort4v*>(Op + 8 * g4 + 4 * hi) = w0;
    *reinterpret_cast<ushort4v*>(Op + 32 + 8 * g4 + 4 * hi) = w1;
  }
}

// ----------------------------------------------------------------
extern "C" void kernel_launch(void* const* d_in, const int* in_sizes, int n_in,
                              void* d_out, int out_size, void* d_ws, size_t ws_size,
                              hipStream_t stream) {
  const float* x   = (const float*)d_in[0];
  const float* Wqa = (const float*)d_in[1];
  const float* Wka = (const float*)d_in[2];
  const float* Wqp = (const float*)d_in[3];
  const float* Wkp = (const float*)d_in[4];
  const float* Wv  = (const float*)d_in[5];
  const float* Wo  = (const float*)d_in[6];
  const float* sls = (const float*)d_in[7];

  char* ws = (char*)d_ws;
  ushort* x_bf = (ushort*)ws; ws += (size_t)NTOK * DM * 2;
  ushort* w_bf[6];
  for (int i = 0; i < 6; i++) { w_bf[i] = (ushort*)ws; ws += (size_t)DM * DM * 2; }
  ushort* qext = (ushort*)ws; ws += (size_t)NBH * S_LEN * 128 * 2;
  ushort* kext = (ushort*)ws; ws += (size_t)NBH * S_LEN * 128 * 2;
  ushort* vT   = (ushort*)ws; ws += (size_t)NBH * HD * S_LEN * 2;
  ushort* attn = (ushort*)ws; ws += (size_t)NTOK * DM * 2;

  // 1. fp32 -> bf16 conversions (x + 6 weights)
  CvtArgs ca;
  ca.src[0] = x; ca.dst[0] = x_bf; ca.n[0] = NTOK * DM;
  const float* wsrc[6] = {Wqa, Wka, Wqp, Wkp, Wv, Wo};
  for (int i = 0; i < 6; i++) { ca.src[i + 1] = wsrc[i]; ca.dst[i + 1] = w_bf[i]; ca.n[i + 1] = DM * DM; }
  dim3 cg((NTOK * DM / 8 + 255) / 256, 7);
  hipLaunchKernelGGL(cvt_kernel, cg, dim3(256), 0, stream, ca);

  // 2. fused projections, XCD-balanced swizzled flat grid (dual q/k + V->vT)
  hipLaunchKernelGGL(qkproj_kernel, dim3(768), dim3(256), 0, stream,
                     x_bf, w_bf[0], w_bf[2], w_bf[1], w_bf[3], w_bf[4], sls,
                     qext, kext, vT);

  // 3. causal flash attention (128-row blocks, LDS-staged K/V, 2-phase pipeline)
  hipLaunchKernelGGL(attn_kernel, dim3(512), dim3(256), 0, stream,
                     qext, kext, vT, attn);

  // 4. output projection -> fp32 d_out (XCD-swizzled flat grid)
  hipLaunchKernelGGL(gemm_bt, dim3(256), dim3(256), 0, stream, attn, w_bf[5],
                     (float*)d_out, NTOK, DM, DM);
}

// Round 11
// 156.822 us; speedup vs baseline: 4.2388x; 1.0055x over previous
//
#include <hip/hip_runtime.h>
#include <hip/hip_bf16.h>
#include <math.h>

// Problem constants (fixed shapes from setup_inputs)
#define S_LEN 2048
#define NH 16
#define HD 64
#define DM 1024
#define NTOK 4096   // B*S
#define NBH 32      // B*NH

typedef __attribute__((ext_vector_type(8))) __bf16 bf16x8;
typedef __attribute__((ext_vector_type(8))) ushort ushort8;
typedef __attribute__((ext_vector_type(4))) ushort ushort4v;
typedef __attribute__((ext_vector_type(4))) float f32x4;
typedef __attribute__((ext_vector_type(16))) float f32x16;
typedef __attribute__((ext_vector_type(4))) uint u32x4;

__device__ __forceinline__ ushort f2b(float x) {
  __hip_bfloat16 h = __float2bfloat16(x);
  return *reinterpret_cast<ushort*>(&h);
}

__device__ __forceinline__ uint pk2(float lo, float hi) {
  return (uint)f2b(lo) | ((uint)f2b(hi) << 16);
}

__device__ __forceinline__ void gload16b(const void* g, void* l) {
  __builtin_amdgcn_global_load_lds((const __attribute__((address_space(1))) void*)g,
                                   (__attribute__((address_space(3))) void*)l, 16, 0, 0);
}

#define MFMA16(a, b, c) __builtin_amdgcn_mfma_f32_16x16x32_bf16((a), (b), (c), 0, 0, 0)
#define MFMA32(a, b, c) __builtin_amdgcn_mfma_f32_32x32x16_bf16((a), (b), (c), 0, 0, 0)

// ---------------------------------------------------------------- convert fp32 -> bf16
struct CvtArgs {
  const float* src[7];
  ushort* dst[7];
  int n[7];
};

__global__ void cvt_kernel(CvtArgs a) {
  int arr = blockIdx.y;
  long i = ((long)blockIdx.x * blockDim.x + threadIdx.x) * 8;
  if (i >= a.n[arr]) return;
  const float* s = a.src[arr];
  ushort* d = a.dst[arr];
  float4 v0 = *reinterpret_cast<const float4*>(s + i);
  float4 v1 = *reinterpret_cast<const float4*>(s + i + 4);
  ushort8 r;
  r[0] = f2b(v0.x); r[1] = f2b(v0.y); r[2] = f2b(v0.z); r[3] = f2b(v0.w);
  r[4] = f2b(v1.x); r[5] = f2b(v1.y); r[6] = f2b(v1.z); r[7] = f2b(v1.w);
  *reinterpret_cast<ushort8*>(d + i) = r;
}

// ---------------------------------------------------------------- fused QK/V projection
// XCD-swizzled flat grid (A-panels XCD-local); conflict-free LDS slot swizzle
// (inverse-swizzled global source, swizzled read); TRIPLE-buffered staging ring:
// loads get 2 K-steps to land; counted vmcnt(12/6/0) (dual) / (8/4/0) (V).
__global__ __launch_bounds__(256, 2) void qkproj_kernel(
    const ushort* __restrict__ A,
    const ushort* __restrict__ Wqa, const ushort* __restrict__ Wqp,
    const ushort* __restrict__ Wka, const ushort* __restrict__ Wkp,
    const ushort* __restrict__ Wv, const float* __restrict__ sls,
    ushort* __restrict__ qext, ushort* __restrict__ kext, ushort* __restrict__ vT) {
  __shared__ __align__(16) ushort Alds[3][4096];
  __shared__ __align__(16) ushort B0lds[3][4096];
  __shared__ __align__(16) ushort B1lds[3][4096];
  // XCD-balanced bijective swizzle: xcd x gets duals [64x,64x+64) + Vs [512+32x, +32)
  const int d = blockIdx.x;
  const int xc = d & 7, c = d >> 3;  // c in 0..95
  const int u = (c < 64) ? (xc * 64 + c) : (512 + xc * 32 + (c - 64));
  int z, bx, by;
  if (u < 512) { z = u >> 8; int v = u & 255; bx = v & 7; by = v >> 3; }
  else         { z = 2;      int v = u - 512; bx = v & 7; by = v >> 3; }
  const int t = threadIdx.x;
  const int lane = t & 63;
  const int wave = t >> 6;
  const int wm = wave >> 1, wn = wave & 1;
  const int l15 = lane & 15, g = lane >> 4;
  const int mbase = by * 128, nbase = bx * 128;
  const int K = DM;
  const int srow = t >> 2;
  const int sx = (srow >> 1) & 3;            // inverse source swizzle
  const int scol = (((t & 3) ^ sx)) * 8;
  const int xr = (l15 >> 1) & 3;             // read-side swizzle
  const ushort* Ag = A + (size_t)(mbase + srow) * K + scol;
  const ushort* Wa = (z == 0) ? Wqa : (z == 1) ? Wka : Wv;
  const ushort* Wp = (z == 0) ? Wqp : Wkp;  // unused for z==2
  const ushort* Wag = Wa + (size_t)(nbase + srow) * K + scol;
  const ushort* Wpg = (z < 2) ? (Wp + (size_t)(nbase + srow) * K + scol) : Wag;

  const int nk = K / 32;                     // 32, compile-time
  f32x4 accA[4][4] = {};

  if (z < 2) {
    // ---------------- dual GEMM, 3-buffer ring ----------------
    f32x4 accP[4][4] = {};
    auto stage = [&](int buf, int kt) {
      gload16b(Ag + kt, &Alds[buf][t * 8]);
      gload16b(Ag + kt + (size_t)64 * K, &Alds[buf][t * 8 + 64 * 32]);
      gload16b(Wag + kt, &B0lds[buf][t * 8]);
      gload16b(Wag + kt + (size_t)64 * K, &B0lds[buf][t * 8 + 64 * 32]);
      gload16b(Wpg + kt, &B1lds[buf][t * 8]);
      gload16b(Wpg + kt + (size_t)64 * K, &B1lds[buf][t * 8 + 64 * 32]);
    };
    stage(0, 0);
    stage(1, 32);
    int cur = 0;
    for (int kt = 0; kt < nk; ++kt) {
      if (kt + 2 < nk) {
        int b2 = cur + 2; if (b2 >= 3) b2 -= 3;
        stage(b2, (kt + 2) * 32);
        asm volatile("s_waitcnt vmcnt(12)" ::: "memory");   // cur's 6 loads done
      } else if (kt + 1 < nk) {
        asm volatile("s_waitcnt vmcnt(6)" ::: "memory");
      } else {
        asm volatile("s_waitcnt vmcnt(0)" ::: "memory");
      }
      __builtin_amdgcn_s_barrier();
      bf16x8 af[4], ba[4], bp[4];
#pragma unroll
      for (int i = 0; i < 4; i++)
        af[i] = *reinterpret_cast<const bf16x8*>(
            &Alds[cur][(wm * 64 + i * 16 + l15) * 32 + (g ^ xr) * 8]);
#pragma unroll
      for (int j = 0; j < 4; j++) {
        ba[j] = *reinterpret_cast<const bf16x8*>(
            &B0lds[cur][(wn * 64 + j * 16 + l15) * 32 + (g ^ xr) * 8]);
        bp[j] = *reinterpret_cast<const bf16x8*>(
            &B1lds[cur][(wn * 64 + j * 16 + l15) * 32 + (g ^ xr) * 8]);
      }
      __builtin_amdgcn_s_setprio(1);
#pragma unroll
      for (int i = 0; i < 4; i++)
#pragma unroll
        for (int j = 0; j < 4; j++) {
          accA[i][j] = MFMA16(af[i], ba[j], accA[i][j]);
          accP[i][j] = MFMA16(af[i], bp[j], accP[i][j]);
        }
      __builtin_amdgcn_s_setprio(0);
      __builtin_amdgcn_s_barrier();
      cur = (cur + 1 == 3) ? 0 : cur + 1;
    }
    // ---------------- fused epilogue: softplus + RMS + pi*tanh -> sincos ----------------
    const int row0 = mbase + wm * 64;
    const int h = (nbase >> 6) + wn;              // head index
    const float scale = (z == 0) ? __expf(sls[h]) * 0.125f : 1.0f;
    ushort* ext = (z == 0) ? qext : kext;
#pragma unroll
    for (int i = 0; i < 4; i++) {
#pragma unroll
      for (int r = 0; r < 4; r++) {
        float sp[4];
        float ss = 0.0f;
#pragma unroll
        for (int j = 0; j < 4; j++) {
          float v = accA[i][j][r];
          sp[j] = fmaxf(v, 0.0f) + __logf(1.0f + __expf(-fabsf(v)));
          ss += sp[j] * sp[j];
        }
        ss += __shfl_xor(ss, 1);
        ss += __shfl_xor(ss, 2);
        ss += __shfl_xor(ss, 4);
        ss += __shfl_xor(ss, 8);
        float rn = rsqrtf(ss * (1.0f / 64.0f) + 1e-6f) * scale;
        const int token = row0 + i * 16 + g * 4 + r;
        const int bb = token >> 11, sidx = token & 2047;
        ushort* base = ext + (((size_t)(bb * NH + h) * S_LEN + sidx) << 7);
#pragma unroll
        for (int j = 0; j < 4; j++) {
          float e = __expf(2.0f * accP[i][j][r]);
          float th = 1.0f - 2.0f * __builtin_amdgcn_rcpf(e + 1.0f);
          float phi = 3.14159265358979f * th;
          float sn = __sinf(phi), cs = __cosf(phi);
          float a = sp[j] * rn;
          int dd = j * 16 + l15;
          base[dd] = f2b(a * cs);
          base[64 + dd] = f2b(a * sn);
        }
      }
    }
  } else {
    // ---------------- V GEMM -> vT[B,H,64,S] directly, 3-buffer ring ----------------
    auto stage = [&](int buf, int kt) {
      gload16b(Ag + kt, &Alds[buf][t * 8]);
      gload16b(Ag + kt + (size_t)64 * K, &Alds[buf][t * 8 + 64 * 32]);
      gload16b(Wag + kt, &B0lds[buf][t * 8]);
      gload16b(Wag + kt + (size_t)64 * K, &B0lds[buf][t * 8 + 64 * 32]);
    };
    stage(0, 0);
    stage(1, 32);
    int cur = 0;
    for (int kt = 0; kt < nk; ++kt) {
      if (kt + 2 < nk) {
        int b2 = cur + 2; if (b2 >= 3) b2 -= 3;
        stage(b2, (kt + 2) * 32);
        asm volatile("s_waitcnt vmcnt(8)" ::: "memory");
      } else if (kt + 1 < nk) {
        asm volatile("s_waitcnt vmcnt(4)" ::: "memory");
      } else {
        asm volatile("s_waitcnt vmcnt(0)" ::: "memory");
      }
      __builtin_amdgcn_s_barrier();
      bf16x8 af[4], ba[4];
#pragma unroll
      for (int i = 0; i < 4; i++)
        af[i] = *reinterpret_cast<const bf16x8*>(
            &Alds[cur][(wm * 64 + i * 16 + l15) * 32 + (g ^ xr) * 8]);
#pragma unroll
      for (int j = 0; j < 4; j++)
        ba[j] = *reinterpret_cast<const bf16x8*>(
            &B0lds[cur][(wn * 64 + j * 16 + l15) * 32 + (g ^ xr) * 8]);
      __builtin_amdgcn_s_setprio(1);
#pragma unroll
      for (int i = 0; i < 4; i++)
#pragma unroll
        for (int j = 0; j < 4; j++)
          accA[i][j] = MFMA16(af[i], ba[j], accA[i][j]);
      __builtin_amdgcn_s_setprio(0);
      __builtin_amdgcn_s_barrier();
      cur = (cur + 1 == 3) ? 0 : cur + 1;
    }
    const int row0 = mbase + wm * 64, col0 = nbase + wn * 64;
#pragma unroll
    for (int i = 0; i < 4; i++)
#pragma unroll
      for (int j = 0; j < 4; j++) {
        int col = col0 + j * 16 + l15;     // global value-dim
        int h = col >> 6, hd = col & 63;
        int t0 = row0 + i * 16 + g * 4;    // 4 consecutive tokens (r=0..3)
        int bb = t0 >> 11, s0 = t0 & 2047;
        ushort4v w;
#pragma unroll
        for (int r = 0; r < 4; r++) w[r] = f2b(accA[i][j][r]);
        *reinterpret_cast<ushort4v*>(
            &vT[(((size_t)(bb * NH + h) * HD + hd) << 11) + s0]) = w;
      }
  }
}

// ---------------------------------------------------------------- GEMM (Wo projection)
// Flat 256-block grid (1 block/CU), XCD swizzle, swizzled LDS slots, QUAD-buffered
// staging ring (prefetch 3 ahead, vmcnt(12/8/4/0)) — depth is the only latency cover
// at 1 block/CU.
__global__ __launch_bounds__(256) void gemm_bt(const ushort* __restrict__ A,
                                               const ushort* __restrict__ W,
                                               float* __restrict__ Cout,
                                               int M, int N, int K) {
  __shared__ __align__(16) ushort Alds[4][4096];
  __shared__ __align__(16) ushort Blds[4][4096];
  const int d = blockIdx.x;
  const int u = (d & 7) * 32 + (d >> 3);   // 256 = 8*32, bijective
  const int bx = u & 7, by = u >> 3;
  const int t = threadIdx.x;
  const int lane = t & 63;
  const int wave = t >> 6;
  const int wm = wave >> 1, wn = wave & 1;
  const int l15 = lane & 15, g = lane >> 4;
  const int mbase = by * 128, nbase = bx * 128;
  const int srow = t >> 2;
  const int sx = (srow >> 1) & 3;
  const int scol = (((t & 3) ^ sx)) * 8;
  const int xr = (l15 >> 1) & 3;
  const ushort* Ag = A + (size_t)(mbase + srow) * K + scol;
  const ushort* Wg = W + (size_t)(nbase + srow) * K + scol;
  auto stage = [&](int buf, int kt) {
    gload16b(Ag + kt, &Alds[buf][t * 8]);
    gload16b(Ag + kt + (size_t)64 * K, &Alds[buf][t * 8 + 64 * 32]);
    gload16b(Wg + kt, &Blds[buf][t * 8]);
    gload16b(Wg + kt + (size_t)64 * K, &Blds[buf][t * 8 + 64 * 32]);
  };
  const int nk = K / 32;
  stage(0, 0);
  stage(1, 32);
  stage(2, 64);
  f32x4 acc[4][4] = {};
  for (int kt = 0; kt < nk; ++kt) {
    const int cur = kt & 3;
    if (kt + 3 < nk) {
      stage((cur + 3) & 3, (kt + 3) * 32);
      asm volatile("s_waitcnt vmcnt(12)" ::: "memory");
    } else if (kt + 2 < nk) {
      asm volatile("s_waitcnt vmcnt(8)" ::: "memory");
    } else if (kt + 1 < nk) {
      asm volatile("s_waitcnt vmcnt(4)" ::: "memory");
    } else {
      asm volatile("s_waitcnt vmcnt(0)" ::: "memory");
    }
    __builtin_amdgcn_s_barrier();
    bf16x8 af[4], bfr[4];
#pragma unroll
    for (int i = 0; i < 4; i++)
      af[i] = *reinterpret_cast<const bf16x8*>(
          &Alds[cur][(wm * 64 + i * 16 + l15) * 32 + (g ^ xr) * 8]);
#pragma unroll
    for (int j = 0; j < 4; j++)
      bfr[j] = *reinterpret_cast<const bf16x8*>(
          &Blds[cur][(wn * 64 + j * 16 + l15) * 32 + (g ^ xr) * 8]);
    __builtin_amdgcn_s_setprio(1);
#pragma unroll
    for (int i = 0; i < 4; i++)
#pragma unroll
      for (int j = 0; j < 4; j++)
        acc[i][j] = MFMA16(af[i], bfr[j], acc[i][j]);
    __builtin_amdgcn_s_setprio(0);
    __builtin_amdgcn_s_barrier();
  }
  const int row0 = mbase + wm * 64, col0 = nbase + wn * 64;
#pragma unroll
  for (int i = 0; i < 4; i++)
#pragma unroll
    for (int j = 0; j < 4; j++)
#pragma unroll
      for (int r = 0; r < 4; r++) {
        int row = row0 + i * 16 + g * 4 + r;
        int col = col0 + j * 16 + l15;
        Cout[(size_t)row * N + col] = acc[i][j][r];
      }
}

// ---------------------------------------------------------------- causal flash attention
// Block = 128 q-rows (4 waves x 32-row swapped-QK). K/V staged in LDS (global_load_lds,
// XOR-swizzled src), double-buffered, counted vmcnt(6) + raw s_barrier.
__device__ __forceinline__ void stage_kv(const char* Kp, const char* Vp, int kb,
                                         char* buf, int wave, int lane) {
#pragma unroll
  for (int c = 0; c < 4; c++) {
    int i = wave * 4 + c;
    int kvl = i * 4 + (lane >> 4);
    int slot = (lane & 15) ^ (kvl & 7);
    gload16b(Kp + (size_t)(kb + kvl) * 256 + slot * 16, buf + i * 1024);
  }
#pragma unroll
  for (int c = 0; c < 2; c++) {
    int i = wave * 2 + c;
    int hd = i * 8 + (lane >> 3);
    int slot = (lane & 7) ^ (hd & 7);
    gload16b(Vp + (size_t)hd * (S_LEN * 2) + (size_t)kb * 2 + slot * 16,
             buf + 16384 + i * 1024);
  }
}

__global__ __launch_bounds__(256, 2) void attn_kernel(const ushort* __restrict__ qext,
                                                      const ushort* __restrict__ kext,
                                                      const ushort* __restrict__ vT,
                                                      ushort* __restrict__ attnout) {
  __shared__ __align__(16) char lds[2][24576];
  const int u = blockIdx.x;
  const int uh = u >> 8, v = u & 255;
  const int bh = v >> 3, j = v & 7;
  const int qt = uh ? (15 - j) : j;
  const int b = bh >> 4, h = bh & 15;
  const int wave = threadIdx.x >> 6, lane = threadIdx.x & 63;
  const int l31 = lane & 31, hi = lane >> 5;
  const int qb = qt * 128;
  const int qw = qb + wave * 32;
  const int qa = qw + l31;
  const char* Kp = (const char*)(kext + (size_t)bh * S_LEN * 128);
  const char* Vp = (const char*)(vT + (size_t)bh * HD * S_LEN);
  const ushort* Qp = qext + (size_t)bh * S_LEN * 128;
  const int nt = 2 * qt + 2;
  const int ksw = l31 & 7;

  stage_kv(Kp, Vp, 0, lds[0], wave, lane);
  bf16x8 qf[8];
#pragma unroll
  for (int s = 0; s < 8; s++)
    qf[s] = *reinterpret_cast<const bf16x8*>(&Qp[(size_t)qa * 128 + s * 16 + hi * 8]);

  f32x16 o0 = {}, o1 = {};
  float m = -1e30f, ls = 0.0f;

  for (int t = 0; t < nt; ++t) {
    const int cur = t & 1;
    const int kb = t << 6;
    if (t + 1 < nt) {
      stage_kv(Kp, Vp, (t + 1) << 6, lds[cur ^ 1], wave, lane);
      asm volatile("s_waitcnt vmcnt(6)" ::: "memory");
    } else {
      asm volatile("s_waitcnt vmcnt(0)" ::: "memory");
    }
    __builtin_amdgcn_s_barrier();

    const char* Kb = lds[cur];
    const char* Vb = lds[cur] + 16384;

    f32x16 st0 = {}, st1 = {};
    __builtin_amdgcn_s_setprio(1);
#pragma unroll
    for (int s = 0; s < 8; s++) {
      int sl = ((s * 2 + hi) ^ ksw) << 4;
      bf16x8 k0 = *(const bf16x8*)(Kb + l31 * 256 + sl);
      bf16x8 k1 = *(const bf16x8*)(Kb + (32 + l31) * 256 + sl);
      st0 = MFMA32(k0, qf[s], st0);
      st1 = MFMA32(k1, qf[s], st1);
    }
    __builtin_amdgcn_s_setprio(0);

    if (kb + 64 > qw) {
#pragma unroll
      for (int r = 0; r < 16; r++) {
        int kv = kb + (r & 3) + 8 * (r >> 2) + 4 * hi;
        if (kv > qa) st0[r] = -1e30f;
        if (kv + 32 > qa) st1[r] = -1e30f;
      }
    }
    float pm = -1e30f;
#pragma unroll
    for (int r = 0; r < 16; r++) pm = fmaxf(pm, fmaxf(st0[r], st1[r]));
    pm = fmaxf(pm, __shfl_xor(pm, 32));
    if (!__all(pm <= m + 8.0f)) {
      float mn = fmaxf(m, pm);
      float corr = __expf(m - mn);
      m = mn;
      ls *= corr;
#pragma unroll
      for (int r = 0; r < 16; r++) { o0[r] *= corr; o1[r] *= corr; }
    }
    float ssum = 0.0f;
#pragma unroll
    for (int r = 0; r < 16; r++) {
      st0[r] = __expf(st0[r] - m);
      st1[r] = __expf(st1[r] - m);
      ssum += st0[r] + st1[r];
    }
    ssum += __shfl_xor(ssum, 32);
    ls += ssum;

    u32x4 pb[4];
#pragma unroll
    for (int half = 0; half < 2; half++) {
      const f32x16& st = half ? st1 : st0;
      uint cA0 = pk2(st[0], st[1]),  cA1 = pk2(st[2], st[3]);
      uint cB0 = pk2(st[4], st[5]),  cB1 = pk2(st[6], st[7]);
      uint cC0 = pk2(st[8], st[9]),  cC1 = pk2(st[10], st[11]);
      uint cD0 = pk2(st[12], st[13]), cD1 = pk2(st[14], st[15]);
      uint xA0 = __shfl_xor(cA0, 32), xA1 = __shfl_xor(cA1, 32);
      uint xB0 = __shfl_xor(cB0, 32), xB1 = __shfl_xor(cB1, 32);
      uint xC0 = __shfl_xor(cC0, 32), xC1 = __shfl_xor(cC1, 32);
      uint xD0 = __shfl_xor(cD0, 32), xD1 = __shfl_xor(cD1, 32);
      u32x4 lo, hi4;
      lo[0] = cA0; lo[1] = cA1; lo[2] = xA0; lo[3] = xA1;
      hi4[0] = xB0; hi4[1] = xB1; hi4[2] = cB0; hi4[3] = cB1;
      pb[half * 2] = hi ? hi4 : lo;
      u32x4 lo2, hi2;
      lo2[0] = cC0; lo2[1] = cC1; lo2[2] = xC0; lo2[3] = xC1;
      hi2[0] = xD0; hi2[1] = xD1; hi2[2] = cD0; hi2[3] = cD1;
      pb[half * 2 + 1] = hi ? hi2 : lo2;
    }
    __builtin_amdgcn_s_setprio(1);
#pragma unroll
    for (int ks = 0; ks < 4; ks++) {
      int sl = ((ks * 2 + hi) ^ ksw) << 4;
      bf16x8 v0 = *(const bf16x8*)(Vb + l31 * 128 + sl);
      bf16x8 v1 = *(const bf16x8*)(Vb + (32 + l31) * 128 + sl);
      bf16x8 pbb = *reinterpret_cast<const bf16x8*>(&pb[ks]);
      o0 = MFMA32(v0, pbb, o0);
      o1 = MFMA32(v1, pbb, o1);
    }
    __builtin_amdgcn_s_setprio(0);
    __builtin_amdgcn_s_barrier();
  }

  float inv = 1.0f / ls;
  ushort* Op = attnout + ((size_t)b * S_LEN + qa) * DM + h * HD;
#pragma unroll
  for (int g4 = 0; g4 < 4; g4++) {
    ushort4v w0, w1;
#pragma unroll
    for (int jj = 0; jj < 4; jj++) {
      w0[jj] = f2b(o0[4 * g4 + jj] * inv);
      w1[jj] = f2b(o1[4 * g4 + jj] * inv);
    }
    *reinterpret_cast<ushort4v*>(Op + 8 * g4 + 4 * hi) = w0;
    *reinterpret_cast<ushort4v*>(Op + 32 + 8 * g4 + 4 * hi) = w1;
  }
}

// ----------------------------------------------------------------
extern "C" void kernel_launch(void* const* d_in, const int* in_sizes, int n_in,
                              void* d_out, int out_size, void* d_ws, size_t ws_size,
                              hipStream_t stream) {
  const float* x   = (const float*)d_in[0];
  const float* Wqa = (const float*)d_in[1];
  const float* Wka = (const float*)d_in[2];
  const float* Wqp = (const float*)d_in[3];
  const float* Wkp = (const float*)d_in[4];
  const float* Wv  = (const float*)d_in[5];
  const float* Wo  = (const float*)d_in[6];
  const float* sls = (const float*)d_in[7];

  char* ws = (char*)d_ws;
  ushort* x_bf = (ushort*)ws; ws += (size_t)NTOK * DM * 2;
  ushort* w_bf[6];
  for (int i = 0; i < 6; i++) { w_bf[i] = (ushort*)ws; ws += (size_t)DM * DM * 2; }
  ushort* qext = (ushort*)ws; ws += (size_t)NBH * S_LEN * 128 * 2;
  ushort* kext = (ushort*)ws; ws += (size_t)NBH * S_LEN * 128 * 2;
  ushort* vT   = (ushort*)ws; ws += (size_t)NBH * HD * S_LEN * 2;
  ushort* attn = (ushort*)ws; ws += (size_t)NTOK * DM * 2;

  // 1. fp32 -> bf16 conversions (x + 6 weights)
  CvtArgs ca;
  ca.src[0] = x; ca.dst[0] = x_bf; ca.n[0] = NTOK * DM;
  const float* wsrc[6] = {Wqa, Wka, Wqp, Wkp, Wv, Wo};
  for (int i = 0; i < 6; i++) { ca.src[i + 1] = wsrc[i]; ca.dst[i + 1] = w_bf[i]; ca.n[i + 1] = DM * DM; }
  dim3 cg((NTOK * DM / 8 + 255) / 256, 7);
  hipLaunchKernelGGL(cvt_kernel, cg, dim3(256), 0, stream, ca);

  // 2. fused projections, XCD-balanced swizzled flat grid (dual q/k + V->vT)
  hipLaunchKernelGGL(qkproj_kernel, dim3(768), dim3(256), 0, stream,
                     x_bf, w_bf[0], w_bf[2], w_bf[1], w_bf[3], w_bf[4], sls,
                     qext, kext, vT);

  // 3. causal flash attention (128-row blocks, LDS-staged K/V, 2-phase pipeline)
  hipLaunchKernelGGL(attn_kernel, dim3(512), dim3(256), 0, stream,
                     qext, kext, vT, attn);

  // 4. output projection -> fp32 d_out (XCD-swizzled flat grid, 4-buffer ring)
  hipLaunchKernelGGL(gemm_bt, dim3(256), dim3(256), 0, stream, attn, w_bf[5],
                     (float*)d_out, NTOK, DM, DM);
}

// Round 12
// 155.912 us; speedup vs baseline: 4.2635x; 1.0058x over previous
//
#include <hip/hip_runtime.h>
#include <hip/hip_bf16.h>
#include <math.h>

// Problem constants (fixed shapes from setup_inputs)
#define S_LEN 2048
#define NH 16
#define HD 64
#define DM 1024
#define NTOK 4096   // B*S
#define NBH 32      // B*NH

typedef __attribute__((ext_vector_type(8))) __bf16 bf16x8;
typedef __attribute__((ext_vector_type(8))) ushort ushort8;
typedef __attribute__((ext_vector_type(4))) ushort ushort4v;
typedef __attribute__((ext_vector_type(4))) float f32x4;
typedef __attribute__((ext_vector_type(16))) float f32x16;
typedef __attribute__((ext_vector_type(4))) uint u32x4;

__device__ __forceinline__ ushort f2b(float x) {
  __hip_bfloat16 h = __float2bfloat16(x);
  return *reinterpret_cast<ushort*>(&h);
}

__device__ __forceinline__ uint pk2(float lo, float hi) {
  return (uint)f2b(lo) | ((uint)f2b(hi) << 16);
}

__device__ __forceinline__ void gload16b(const void* g, void* l) {
  __builtin_amdgcn_global_load_lds((const __attribute__((address_space(1))) void*)g,
                                   (__attribute__((address_space(3))) void*)l, 16, 0, 0);
}

#define MFMA16(a, b, c) __builtin_amdgcn_mfma_f32_16x16x32_bf16((a), (b), (c), 0, 0, 0)
#define MFMA32(a, b, c) __builtin_amdgcn_mfma_f32_32x32x16_bf16((a), (b), (c), 0, 0, 0)

// ---------------------------------------------------------------- convert fp32 -> bf16
struct CvtArgs {
  const float* src[7];
  ushort* dst[7];
  int n[7];
};

__global__ void cvt_kernel(CvtArgs a) {
  int arr = blockIdx.y;
  long i = ((long)blockIdx.x * blockDim.x + threadIdx.x) * 8;
  if (i >= a.n[arr]) return;
  const float* s = a.src[arr];
  ushort* d = a.dst[arr];
  float4 v0 = *reinterpret_cast<const float4*>(s + i);
  float4 v1 = *reinterpret_cast<const float4*>(s + i + 4);
  ushort8 r;
  r[0] = f2b(v0.x); r[1] = f2b(v0.y); r[2] = f2b(v0.z); r[3] = f2b(v0.w);
  r[4] = f2b(v1.x); r[5] = f2b(v1.y); r[6] = f2b(v1.z); r[7] = f2b(v1.w);
  *reinterpret_cast<ushort8*>(d + i) = r;
}

// ---------------------------------------------------------------- fused QK/V projection
// XCD-swizzled flat grid (A-panels XCD-local); conflict-free LDS slot swizzle;
// triple-buffered staging ring (counted vmcnt).
__global__ __launch_bounds__(256, 2) void qkproj_kernel(
    const ushort* __restrict__ A,
    const ushort* __restrict__ Wqa, const ushort* __restrict__ Wqp,
    const ushort* __restrict__ Wka, const ushort* __restrict__ Wkp,
    const ushort* __restrict__ Wv, const float* __restrict__ sls,
    ushort* __restrict__ qext, ushort* __restrict__ kext, ushort* __restrict__ vT) {
  __shared__ __align__(16) ushort Alds[3][4096];
  __shared__ __align__(16) ushort B0lds[3][4096];
  __shared__ __align__(16) ushort B1lds[3][4096];
  const int d = blockIdx.x;
  const int xc = d & 7, c = d >> 3;  // c in 0..95
  const int u = (c < 64) ? (xc * 64 + c) : (512 + xc * 32 + (c - 64));
  int z, bx, by;
  if (u < 512) { z = u >> 8; int v = u & 255; bx = v & 7; by = v >> 3; }
  else         { z = 2;      int v = u - 512; bx = v & 7; by = v >> 3; }
  const int t = threadIdx.x;
  const int lane = t & 63;
  const int wave = t >> 6;
  const int wm = wave >> 1, wn = wave & 1;
  const int l15 = lane & 15, g = lane >> 4;
  const int mbase = by * 128, nbase = bx * 128;
  const int K = DM;
  const int srow = t >> 2;
  const int sx = (srow >> 1) & 3;            // inverse source swizzle
  const int scol = (((t & 3) ^ sx)) * 8;
  const int xr = (l15 >> 1) & 3;             // read-side swizzle
  const ushort* Ag = A + (size_t)(mbase + srow) * K + scol;
  const ushort* Wa = (z == 0) ? Wqa : (z == 1) ? Wka : Wv;
  const ushort* Wp = (z == 0) ? Wqp : Wkp;
  const ushort* Wag = Wa + (size_t)(nbase + srow) * K + scol;
  const ushort* Wpg = (z < 2) ? (Wp + (size_t)(nbase + srow) * K + scol) : Wag;

  const int nk = K / 32;
  f32x4 accA[4][4] = {};

  if (z < 2) {
    f32x4 accP[4][4] = {};
    auto stage = [&](int buf, int kt) {
      gload16b(Ag + kt, &Alds[buf][t * 8]);
      gload16b(Ag + kt + (size_t)64 * K, &Alds[buf][t * 8 + 64 * 32]);
      gload16b(Wag + kt, &B0lds[buf][t * 8]);
      gload16b(Wag + kt + (size_t)64 * K, &B0lds[buf][t * 8 + 64 * 32]);
      gload16b(Wpg + kt, &B1lds[buf][t * 8]);
      gload16b(Wpg + kt + (size_t)64 * K, &B1lds[buf][t * 8 + 64 * 32]);
    };
    stage(0, 0);
    stage(1, 32);
    int cur = 0;
    for (int kt = 0; kt < nk; ++kt) {
      if (kt + 2 < nk) {
        int b2 = cur + 2; if (b2 >= 3) b2 -= 3;
        stage(b2, (kt + 2) * 32);
        asm volatile("s_waitcnt vmcnt(12)" ::: "memory");
      } else if (kt + 1 < nk) {
        asm volatile("s_waitcnt vmcnt(6)" ::: "memory");
      } else {
        asm volatile("s_waitcnt vmcnt(0)" ::: "memory");
      }
      __builtin_amdgcn_s_barrier();
      bf16x8 af[4], ba[4], bp[4];
#pragma unroll
      for (int i = 0; i < 4; i++)
        af[i] = *reinterpret_cast<const bf16x8*>(
            &Alds[cur][(wm * 64 + i * 16 + l15) * 32 + (g ^ xr) * 8]);
#pragma unroll
      for (int j = 0; j < 4; j++) {
        ba[j] = *reinterpret_cast<const bf16x8*>(
            &B0lds[cur][(wn * 64 + j * 16 + l15) * 32 + (g ^ xr) * 8]);
        bp[j] = *reinterpret_cast<const bf16x8*>(
            &B1lds[cur][(wn * 64 + j * 16 + l15) * 32 + (g ^ xr) * 8]);
      }
      __builtin_amdgcn_s_setprio(1);
#pragma unroll
      for (int i = 0; i < 4; i++)
#pragma unroll
        for (int j = 0; j < 4; j++) {
          accA[i][j] = MFMA16(af[i], ba[j], accA[i][j]);
          accP[i][j] = MFMA16(af[i], bp[j], accP[i][j]);
        }
      __builtin_amdgcn_s_setprio(0);
      __builtin_amdgcn_s_barrier();
      cur = (cur + 1 == 3) ? 0 : cur + 1;
    }
    const int row0 = mbase + wm * 64;
    const int h = (nbase >> 6) + wn;
    const float scale = (z == 0) ? __expf(sls[h]) * 0.125f : 1.0f;
    ushort* ext = (z == 0) ? qext : kext;
#pragma unroll
    for (int i = 0; i < 4; i++) {
#pragma unroll
      for (int r = 0; r < 4; r++) {
        float sp[4];
        float ss = 0.0f;
#pragma unroll
        for (int j = 0; j < 4; j++) {
          float v = accA[i][j][r];
          sp[j] = fmaxf(v, 0.0f) + __logf(1.0f + __expf(-fabsf(v)));
          ss += sp[j] * sp[j];
        }
        ss += __shfl_xor(ss, 1);
        ss += __shfl_xor(ss, 2);
        ss += __shfl_xor(ss, 4);
        ss += __shfl_xor(ss, 8);
        float rn = rsqrtf(ss * (1.0f / 64.0f) + 1e-6f) * scale;
        const int token = row0 + i * 16 + g * 4 + r;
        const int bb = token >> 11, sidx = token & 2047;
        ushort* base = ext + (((size_t)(bb * NH + h) * S_LEN + sidx) << 7);
#pragma unroll
        for (int j = 0; j < 4; j++) {
          float e = __expf(2.0f * accP[i][j][r]);
          float th = 1.0f - 2.0f * __builtin_amdgcn_rcpf(e + 1.0f);
          float phi = 3.14159265358979f * th;
          float sn = __sinf(phi), cs = __cosf(phi);
          float a = sp[j] * rn;
          int dd = j * 16 + l15;
          base[dd] = f2b(a * cs);
          base[64 + dd] = f2b(a * sn);
        }
      }
    }
  } else {
    auto stage = [&](int buf, int kt) {
      gload16b(Ag + kt, &Alds[buf][t * 8]);
      gload16b(Ag + kt + (size_t)64 * K, &Alds[buf][t * 8 + 64 * 32]);
      gload16b(Wag + kt, &B0lds[buf][t * 8]);
      gload16b(Wag + kt + (size_t)64 * K, &B0lds[buf][t * 8 + 64 * 32]);
    };
    stage(0, 0);
    stage(1, 32);
    int cur = 0;
    for (int kt = 0; kt < nk; ++kt) {
      if (kt + 2 < nk) {
        int b2 = cur + 2; if (b2 >= 3) b2 -= 3;
        stage(b2, (kt + 2) * 32);
        asm volatile("s_waitcnt vmcnt(8)" ::: "memory");
      } else if (kt + 1 < nk) {
        asm volatile("s_waitcnt vmcnt(4)" ::: "memory");
      } else {
        asm volatile("s_waitcnt vmcnt(0)" ::: "memory");
      }
      __builtin_amdgcn_s_barrier();
      bf16x8 af[4], ba[4];
#pragma unroll
      for (int i = 0; i < 4; i++)
        af[i] = *reinterpret_cast<const bf16x8*>(
            &Alds[cur][(wm * 64 + i * 16 + l15) * 32 + (g ^ xr) * 8]);
#pragma unroll
      for (int j = 0; j < 4; j++)
        ba[j] = *reinterpret_cast<const bf16x8*>(
            &B0lds[cur][(wn * 64 + j * 16 + l15) * 32 + (g ^ xr) * 8]);
      __builtin_amdgcn_s_setprio(1);
#pragma unroll
      for (int i = 0; i < 4; i++)
#pragma unroll
        for (int j = 0; j < 4; j++)
          accA[i][j] = MFMA16(af[i], ba[j], accA[i][j]);
      __builtin_amdgcn_s_setprio(0);
      __builtin_amdgcn_s_barrier();
      cur = (cur + 1 == 3) ? 0 : cur + 1;
    }
    const int row0 = mbase + wm * 64, col0 = nbase + wn * 64;
#pragma unroll
    for (int i = 0; i < 4; i++)
#pragma unroll
      for (int j = 0; j < 4; j++) {
        int col = col0 + j * 16 + l15;
        int h = col >> 6, hd = col & 63;
        int t0 = row0 + i * 16 + g * 4;
        int bb = t0 >> 11, s0 = t0 & 2047;
        ushort4v w;
#pragma unroll
        for (int r = 0; r < 4; r++) w[r] = f2b(accA[i][j][r]);
        *reinterpret_cast<ushort4v*>(
            &vT[(((size_t)(bb * NH + h) * HD + hd) << 11) + s0]) = w;
      }
  }
}

// ---------------------------------------------------------------- GEMM (Wo projection)
__global__ __launch_bounds__(256) void gemm_bt(const ushort* __restrict__ A,
                                               const ushort* __restrict__ W,
                                               float* __restrict__ Cout,
                                               int M, int N, int K) {
  __shared__ __align__(16) ushort Alds[4][4096];
  __shared__ __align__(16) ushort Blds[4][4096];
  const int d = blockIdx.x;
  const int u = (d & 7) * 32 + (d >> 3);
  const int bx = u & 7, by = u >> 3;
  const int t = threadIdx.x;
  const int lane = t & 63;
  const int wave = t >> 6;
  const int wm = wave >> 1, wn = wave & 1;
  const int l15 = lane & 15, g = lane >> 4;
  const int mbase = by * 128, nbase = bx * 128;
  const int srow = t >> 2;
  const int sx = (srow >> 1) & 3;
  const int scol = (((t & 3) ^ sx)) * 8;
  const int xr = (l15 >> 1) & 3;
  const ushort* Ag = A + (size_t)(mbase + srow) * K + scol;
  const ushort* Wg = W + (size_t)(nbase + srow) * K + scol;
  auto stage = [&](int buf, int kt) {
    gload16b(Ag + kt, &Alds[buf][t * 8]);
    gload16b(Ag + kt + (size_t)64 * K, &Alds[buf][t * 8 + 64 * 32]);
    gload16b(Wg + kt, &Blds[buf][t * 8]);
    gload16b(Wg + kt + (size_t)64 * K, &Blds[buf][t * 8 + 64 * 32]);
  };
  const int nk = K / 32;
  stage(0, 0);
  stage(1, 32);
  stage(2, 64);
  f32x4 acc[4][4] = {};
  for (int kt = 0; kt < nk; ++kt) {
    const int cur = kt & 3;
    if (kt + 3 < nk) {
      stage((cur + 3) & 3, (kt + 3) * 32);
      asm volatile("s_waitcnt vmcnt(12)" ::: "memory");
    } else if (kt + 2 < nk) {
      asm volatile("s_waitcnt vmcnt(8)" ::: "memory");
    } else if (kt + 1 < nk) {
      asm volatile("s_waitcnt vmcnt(4)" ::: "memory");
    } else {
      asm volatile("s_waitcnt vmcnt(0)" ::: "memory");
    }
    __builtin_amdgcn_s_barrier();
    bf16x8 af[4], bfr[4];
#pragma unroll
    for (int i = 0; i < 4; i++)
      af[i] = *reinterpret_cast<const bf16x8*>(
          &Alds[cur][(wm * 64 + i * 16 + l15) * 32 + (g ^ xr) * 8]);
#pragma unroll
    for (int j = 0; j < 4; j++)
      bfr[j] = *reinterpret_cast<const bf16x8*>(
          &Blds[cur][(wn * 64 + j * 16 + l15) * 32 + (g ^ xr) * 8]);
    __builtin_amdgcn_s_setprio(1);
#pragma unroll
    for (int i = 0; i < 4; i++)
#pragma unroll
      for (int j = 0; j < 4; j++)
        acc[i][j] = MFMA16(af[i], bfr[j], acc[i][j]);
    __builtin_amdgcn_s_setprio(0);
    __builtin_amdgcn_s_barrier();
  }
  const int row0 = mbase + wm * 64, col0 = nbase + wn * 64;
#pragma unroll
  for (int i = 0; i < 4; i++)
#pragma unroll
    for (int j = 0; j < 4; j++)
#pragma unroll
      for (int r = 0; r < 4; r++) {
        int row = row0 + i * 16 + g * 4 + r;
        int col = col0 + j * 16 + l15;
        Cout[(size_t)row * N + col] = acc[i][j][r];
      }
}

// ---------------------------------------------------------------- causal flash attention
// 768 blocks, XCD-local: XCD x owns heads bh in {4x..4x+3} (K+V fit the 4MB L2).
// qt 0..7: one block (full kv). qt 8..15: TWO blocks (kv halves [0..qt], [qt+1..2qt+1],
// each qt+1 <= 16 tiles) writing fp32 partials; attn_merge combines. Kills the 32-tile
// straggler that set the makespan.
__device__ __forceinline__ void stage_kv(const char* Kp, const char* Vp, int kb,
                                         char* buf, int wave, int lane) {
#pragma unroll
  for (int c = 0; c < 4; c++) {
    int i = wave * 4 + c;
    int kvl = i * 4 + (lane >> 4);
    int slot = (lane & 15) ^ (kvl & 7);
    gload16b(Kp + (size_t)(kb + kvl) * 256 + slot * 16, buf + i * 1024);
  }
#pragma unroll
  for (int c = 0; c < 2; c++) {
    int i = wave * 2 + c;
    int hd = i * 8 + (lane >> 3);
    int slot = (lane & 7) ^ (hd & 7);
    gload16b(Vp + (size_t)hd * (S_LEN * 2) + (size_t)kb * 2 + slot * 16,
             buf + 16384 + i * 1024);
  }
}

__global__ __launch_bounds__(256, 3) void attn_kernel(const ushort* __restrict__ qext,
                                                      const ushort* __restrict__ kext,
                                                      const ushort* __restrict__ vT,
                                                      ushort* __restrict__ attnout,
                                                      float* __restrict__ part) {
  __shared__ __align__(16) char lds[2][24576];
  const int d = blockIdx.x;
  const int xcd = d & 7, c = d >> 3;          // c in 0..95
  const int bh = xcd * 4 + (c & 3);           // 4 heads per XCD
  const int w = c >> 2;                       // 0..23
  int qt, t0, t1, half;
  bool split;
  if (w < 8) { qt = w; t0 = 0; t1 = 2 * qt + 1; split = false; half = 0; }
  else {
    int ww = w - 8;                           // 0..15
    qt = 8 + (ww >> 1); half = ww & 1; split = true;
    if (half == 0) { t0 = 0; t1 = qt; } else { t0 = qt + 1; t1 = 2 * qt + 1; }
  }
  const int b = bh >> 4, h = bh & 15;
  const int wave = threadIdx.x >> 6, lane = threadIdx.x & 63;
  const int l31 = lane & 31, hi = lane >> 5;
  const int qb = qt * 128;
  const int qw = qb + wave * 32;
  const int qa = qw + l31;
  const char* Kp = (const char*)(kext + (size_t)bh * S_LEN * 128);
  const char* Vp = (const char*)(vT + (size_t)bh * HD * S_LEN);
  const ushort* Qp = qext + (size_t)bh * S_LEN * 128;
  const int ksw = l31 & 7;

  stage_kv(Kp, Vp, t0 << 6, lds[0], wave, lane);
  bf16x8 qf[8];
#pragma unroll
  for (int s = 0; s < 8; s++)
    qf[s] = *reinterpret_cast<const bf16x8*>(&Qp[(size_t)qa * 128 + s * 16 + hi * 8]);

  f32x16 o0 = {}, o1 = {};
  float m = -1e30f, ls = 0.0f;

  for (int t = t0; t <= t1; ++t) {
    const int cur = (t - t0) & 1;
    const int kb = t << 6;
    if (t < t1) {
      stage_kv(Kp, Vp, (t + 1) << 6, lds[cur ^ 1], wave, lane);
      asm volatile("s_waitcnt vmcnt(6)" ::: "memory");
    } else {
      asm volatile("s_waitcnt vmcnt(0)" ::: "memory");
    }
    __builtin_amdgcn_s_barrier();

    const char* Kb = lds[cur];
    const char* Vb = lds[cur] + 16384;

    f32x16 st0 = {}, st1 = {};
    __builtin_amdgcn_s_setprio(1);
#pragma unroll
    for (int s = 0; s < 8; s++) {
      int sl = ((s * 2 + hi) ^ ksw) << 4;
      bf16x8 k0 = *(const bf16x8*)(Kb + l31 * 256 + sl);
      bf16x8 k1 = *(const bf16x8*)(Kb + (32 + l31) * 256 + sl);
      st0 = MFMA32(k0, qf[s], st0);
      st1 = MFMA32(k1, qf[s], st1);
    }
    __builtin_amdgcn_s_setprio(0);

    if (kb + 64 > qw) {  // tile reaches past this wave's first row
#pragma unroll
      for (int r = 0; r < 16; r++) {
        int kv = kb + (r & 3) + 8 * (r >> 2) + 4 * hi;
        if (kv > qa) st0[r] = -1e30f;
        if (kv + 32 > qa) st1[r] = -1e30f;
      }
    }
    float pm = -1e30f;
#pragma unroll
    for (int r = 0; r < 16; r++) pm = fmaxf(pm, fmaxf(st0[r], st1[r]));
    pm = fmaxf(pm, __shfl_xor(pm, 32));
    if (!__all(pm <= m + 8.0f)) {
      float mn = fmaxf(m, pm);
      float corr = __expf(m - mn);
      m = mn;
      ls *= corr;
#pragma unroll
      for (int r = 0; r < 16; r++) { o0[r] *= corr; o1[r] *= corr; }
    }
    float ssum = 0.0f;
#pragma unroll
    for (int r = 0; r < 16; r++) {
      st0[r] = __expf(st0[r] - m);
      st1[r] = __expf(st1[r] - m);
      ssum += st0[r] + st1[r];
    }
    ssum += __shfl_xor(ssum, 32);
    ls += ssum;

    u32x4 pb[4];
#pragma unroll
    for (int hf = 0; hf < 2; hf++) {
      const f32x16& st = hf ? st1 : st0;
      uint cA0 = pk2(st[0], st[1]),  cA1 = pk2(st[2], st[3]);
      uint cB0 = pk2(st[4], st[5]),  cB1 = pk2(st[6], st[7]);
      uint cC0 = pk2(st[8], st[9]),  cC1 = pk2(st[10], st[11]);
      uint cD0 = pk2(st[12], st[13]), cD1 = pk2(st[14], st[15]);
      uint xA0 = __shfl_xor(cA0, 32), xA1 = __shfl_xor(cA1, 32);
      uint xB0 = __shfl_xor(cB0, 32), xB1 = __shfl_xor(cB1, 32);
      uint xC0 = __shfl_xor(cC0, 32), xC1 = __shfl_xor(cC1, 32);
      uint xD0 = __shfl_xor(cD0, 32), xD1 = __shfl_xor(cD1, 32);
      u32x4 lo, hi4;
      lo[0] = cA0; lo[1] = cA1; lo[2] = xA0; lo[3] = xA1;
      hi4[0] = xB0; hi4[1] = xB1; hi4[2] = cB0; hi4[3] = cB1;
      pb[hf * 2] = hi ? hi4 : lo;
      u32x4 lo2, hi2;
      lo2[0] = cC0; lo2[1] = cC1; lo2[2] = xC0; lo2[3] = xC1;
      hi2[0] = xD0; hi2[1] = xD1; hi2[2] = cD0; hi2[3] = cD1;
      pb[hf * 2 + 1] = hi ? hi2 : lo2;
    }
    __builtin_amdgcn_s_setprio(1);
#pragma unroll
    for (int ks = 0; ks < 4; ks++) {
      int sl = ((ks * 2 + hi) ^ ksw) << 4;
      bf16x8 v0 = *(const bf16x8*)(Vb + l31 * 128 + sl);
      bf16x8 v1 = *(const bf16x8*)(Vb + (32 + l31) * 128 + sl);
      bf16x8 pbb = *reinterpret_cast<const bf16x8*>(&pb[ks]);
      o0 = MFMA32(v0, pbb, o0);
      o1 = MFMA32(v1, pbb, o1);
    }
    __builtin_amdgcn_s_setprio(0);
    __builtin_amdgcn_s_barrier();
  }

  if (!split) {
    float inv = 1.0f / ls;
    ushort* Op = attnout + ((size_t)b * S_LEN + qa) * DM + h * HD;
#pragma unroll
    for (int g4 = 0; g4 < 4; g4++) {
      ushort4v w0, w1;
#pragma unroll
      for (int jj = 0; jj < 4; jj++) {
        w0[jj] = f2b(o0[4 * g4 + jj] * inv);
        w1[jj] = f2b(o1[4 * g4 + jj] * inv);
      }
      *reinterpret_cast<ushort4v*>(Op + 8 * g4 + 4 * hi) = w0;
      *reinterpret_cast<ushort4v*>(Op + 32 + 8 * g4 + 4 * hi) = w1;
    }
  } else {
    // partial state: [half][bh*8+(qt-8)][row 0..127][72 f32]  (64 dims + m + ls)
    float* P = part + ((size_t)(half * 256 + bh * 8 + (qt - 8)) * 128
                       + (wave * 32 + l31)) * 72;
#pragma unroll
    for (int g4 = 0; g4 < 4; g4++) {
      // o0[4g4+j] holds dim (j + 8*g4 + 4*hi); o1 -> +32
      float4 a0 = make_float4(o0[4 * g4], o0[4 * g4 + 1], o0[4 * g4 + 2], o0[4 * g4 + 3]);
      float4 a1 = make_float4(o1[4 * g4], o1[4 * g4 + 1], o1[4 * g4 + 2], o1[4 * g4 + 3]);
      *reinterpret_cast<float4*>(P + 8 * g4 + 4 * hi) = a0;
      *reinterpret_cast<float4*>(P + 32 + 8 * g4 + 4 * hi) = a1;
    }
    if (hi == 0) { P[64] = m; P[65] = ls; }
  }
}

// merge the two kv-halves of the heavy q-tiles (flash-decode combine)
__global__ void attn_merge(const float* __restrict__ part, ushort* __restrict__ attnout) {
  const int blk = blockIdx.x;        // 256 = bh*8 + (qt-8)
  const int row = threadIdx.x;       // 128
  const int bh = blk >> 3, qt = (blk & 7) + 8;
  const float* Pa = part + ((size_t)blk * 128 + row) * 72;
  const float* Pb = part + ((size_t)(256 + blk) * 128 + row) * 72;
  float mA = Pa[64], lsA = Pa[65], mB = Pb[64], lsB = Pb[65];
  float M = fmaxf(mA, mB);
  float ca = __expf(mA - M), cb = __expf(mB - M);
  float inv = 1.0f / (lsA * ca + lsB * cb);
  const int b = bh >> 4, h = bh & 15;
  const int q = qt * 128 + row;
  ushort* Op = attnout + ((size_t)b * S_LEN + q) * DM + h * HD;
#pragma unroll
  for (int dd = 0; dd < 64; dd += 4) {
    float4 va = *reinterpret_cast<const float4*>(Pa + dd);
    float4 vb = *reinterpret_cast<const float4*>(Pb + dd);
    ushort4v wv;
    wv[0] = f2b((va.x * ca + vb.x * cb) * inv);
    wv[1] = f2b((va.y * ca + vb.y * cb) * inv);
    wv[2] = f2b((va.z * ca + vb.z * cb) * inv);
    wv[3] = f2b((va.w * ca + vb.w * cb) * inv);
    *reinterpret_cast<ushort4v*>(Op + dd) = wv;
  }
}

// ----------------------------------------------------------------
extern "C" void kernel_launch(void* const* d_in, const int* in_sizes, int n_in,
                              void* d_out, int out_size, void* d_ws, size_t ws_size,
                              hipStream_t stream) {
  const float* x   = (const float*)d_in[0];
  const float* Wqa = (const float*)d_in[1];
  const float* Wka = (const float*)d_in[2];
  const float* Wqp = (const float*)d_in[3];
  const float* Wkp = (const float*)d_in[4];
  const float* Wv  = (const float*)d_in[5];
  const float* Wo  = (const float*)d_in[6];
  const float* sls = (const float*)d_in[7];

  char* ws = (char*)d_ws;
  ushort* x_bf = (ushort*)ws; ws += (size_t)NTOK * DM * 2;
  ushort* w_bf[6];
  for (int i = 0; i < 6; i++) { w_bf[i] = (ushort*)ws; ws += (size_t)DM * DM * 2; }
  ushort* qext = (ushort*)ws; ws += (size_t)NBH * S_LEN * 128 * 2;
  ushort* kext = (ushort*)ws; ws += (size_t)NBH * S_LEN * 128 * 2;
  ushort* vT   = (ushort*)ws; ws += (size_t)NBH * HD * S_LEN * 2;
  ushort* attn = (ushort*)ws; ws += (size_t)NTOK * DM * 2;
  float* part  = (float*)ws;  ws += (size_t)2 * 256 * 128 * 72 * 4;

  // 1. fp32 -> bf16 conversions (x + 6 weights)
  CvtArgs ca;
  ca.src[0] = x; ca.dst[0] = x_bf; ca.n[0] = NTOK * DM;
  const float* wsrc[6] = {Wqa, Wka, Wqp, Wkp, Wv, Wo};
  for (int i = 0; i < 6; i++) { ca.src[i + 1] = wsrc[i]; ca.dst[i + 1] = w_bf[i]; ca.n[i + 1] = DM * DM; }
  dim3 cg((NTOK * DM / 8 + 255) / 256, 7);
  hipLaunchKernelGGL(cvt_kernel, cg, dim3(256), 0, stream, ca);

  // 2. fused projections, XCD-balanced swizzled flat grid (dual q/k + V->vT)
  hipLaunchKernelGGL(qkproj_kernel, dim3(768), dim3(256), 0, stream,
                     x_bf, w_bf[0], w_bf[2], w_bf[1], w_bf[3], w_bf[4], sls,
                     qext, kext, vT);

  // 3. causal flash attention: XCD-local heads, heavy q-tiles kv-split
  hipLaunchKernelGGL(attn_kernel, dim3(768), dim3(256), 0, stream,
                     qext, kext, vT, attn, part);
  hipLaunchKernelGGL(attn_merge, dim3(256), dim3(128), 0, stream, part, attn);

  // 4. output projection -> fp32 d_out (XCD-swizzled flat grid, 4-buffer ring)
  hipLaunchKernelGGL(gemm_bt, dim3(256), dim3(256), 0, stream, attn, w_bf[5],
                     (float*)d_out, NTOK, DM, DM);
}